// Round 1
// baseline (747.803 us; speedup 1.0000x reference)
//
#include <hip/hip_runtime.h>

static constexpr int N_ = 8192;
static constexpr int B_ = 2;
static constexpr int K_ = 16;

// ---------------------------------------------------------------------------
// KNN: wave-per-query cooperative top-16 (squared L2, self excluded)
// Formula matches reference: d2 = sq_i + sq_j - 2*dot  (plain fp32, no fma)
// ---------------------------------------------------------------------------
__global__ __launch_bounds__(256) void knn_kernel(const float* __restrict__ coords,
                                                  int* __restrict__ oidx,
                                                  float* __restrict__ odist) {
  __shared__ float4 pts[2048];
  const int b = blockIdx.y;
  const int wv = threadIdx.x >> 6;
  const int lane = threadIdx.x & 63;
  const int q = blockIdx.x * 4 + wv;
  const float* cb = coords + (size_t)b * N_ * 3;
  const float qx = cb[q * 3 + 0], qy = cb[q * 3 + 1], qz = cb[q * 3 + 2];
  const float qsq = __fadd_rn(__fadd_rn(__fmul_rn(qx, qx), __fmul_rn(qy, qy)), __fmul_rn(qz, qz));
  float kd = INFINITY;  // sorted top-16 lives in lanes 0..15 (ascending)
  int ki = 0;
  for (int t0 = 0; t0 < N_; t0 += 2048) {
    __syncthreads();
    for (int i = threadIdx.x; i < 2048; i += 256) {
      const int p = t0 + i;
      const float x = cb[p * 3 + 0], y = cb[p * 3 + 1], z = cb[p * 3 + 2];
      const float sq = __fadd_rn(__fadd_rn(__fmul_rn(x, x), __fmul_rn(y, y)), __fmul_rn(z, z));
      pts[i] = make_float4(x, y, z, sq);
    }
    __syncthreads();
    for (int s = 0; s < 2048; s += 64) {
      const int j = t0 + s + lane;
      const float4 p = pts[s + lane];
      const float dot = __fadd_rn(__fadd_rn(__fmul_rn(qx, p.x), __fmul_rn(qy, p.y)), __fmul_rn(qz, p.z));
      float d2 = __fsub_rn(__fadd_rn(qsq, p.w), __fmul_rn(2.0f, dot));
      if (j == q) d2 = INFINITY;  // exclude self
      float tau = __shfl(kd, 15);
      unsigned long long m = __ballot(d2 < tau);
      while (m) {
        const int src = __builtin_ctzll(m);   // ascending index order -> tie stability
        const float dc = __shfl(d2, src);
        const int jc = t0 + s + src;
        const float sd = __shfl_up(kd, 1);
        const int si = __shfl_up(ki, 1);
        const bool c1 = kd > dc;              // strict: equals keep earlier entries first
        const bool c2 = (lane > 0) && (sd > dc);
        kd = c1 ? (c2 ? sd : dc) : kd;
        ki = c1 ? (c2 ? si : jc) : ki;
        m &= (m - 1);
        tau = __shfl(kd, 15);
        m &= __ballot(d2 < tau);
      }
    }
  }
  if (lane < 16) {
    oidx[((size_t)b * N_ + q) * K_ + lane] = ki;
    odist[((size_t)b * N_ + q) * K_ + lane] = fmaxf(kd, 0.0f);
  }
}

// ---------------------------------------------------------------------------
// Spatial feature moments: sum(s[10]) and sum(s s^T) over all (b,n,k)
// (shared by lse1 and lse2 BN stats; BN of z=W s+b is derivable from these)
// ---------------------------------------------------------------------------
__global__ __launch_bounds__(256) void moments_kernel(const float* __restrict__ coords,
                                                      const int* __restrict__ knn_i,
                                                      const float* __restrict__ knn_d,
                                                      double* __restrict__ mom) {
  const int t = blockIdx.x * 256 + threadIdx.x;  // point id 0..16383
  const int b = t >> 13, n = t & (N_ - 1);
  float acc[65];
#pragma unroll
  for (int e = 0; e < 65; ++e) acc[e] = 0.0f;
  const float* cb = coords + (size_t)b * N_ * 3;
  const float cx = cb[n * 3 + 0], cy = cb[n * 3 + 1], cz = cb[n * 3 + 2];
  for (int k = 0; k < K_; ++k) {
    const int id = knn_i[(size_t)t * K_ + k];
    const float dd = knn_d[(size_t)t * K_ + k];
    const float nx = cb[id * 3 + 0], ny = cb[id * 3 + 1], nz = cb[id * 3 + 2];
    const float s[10] = {cx, cy, cz, nx, ny, nz, cx - nx, cy - ny, cz - nz, dd};
    int e = 0;
#pragma unroll
    for (int i = 0; i < 10; ++i) acc[e++] += s[i];
#pragma unroll
    for (int i = 0; i < 10; ++i)
#pragma unroll
      for (int jj = i; jj < 10; ++jj) acc[e++] += s[i] * s[jj];
  }
#pragma unroll
  for (int e = 0; e < 65; ++e) {
    float v = acc[e];
#pragma unroll
    for (int off = 32; off > 0; off >>= 1) v += __shfl_xor(v, off);
    acc[e] = v;
  }
  __shared__ float buf[4][65];
  const int lane = threadIdx.x & 63, w = threadIdx.x >> 6;
  if (lane == 0) {
#pragma unroll
    for (int e = 0; e < 65; ++e) buf[w][e] = acc[e];
  }
  __syncthreads();
  if (threadIdx.x < 65) {
    const float tot = buf[0][threadIdx.x] + buf[1][threadIdx.x] + buf[2][threadIdx.x] + buf[3][threadIdx.x];
    atomicAdd(&mom[threadIdx.x], (double)tot);
  }
}

// ---------------------------------------------------------------------------
// lse BN affine from moments; folds affine into lse weights:
//   sf = relu(a*(w.s+b)+shift) = relu(w'.s + b')
// ---------------------------------------------------------------------------
__global__ void lse_affine_kernel(const double* __restrict__ mom,
                                  const float* __restrict__ w1, const float* __restrict__ b1,
                                  const float* __restrict__ g1, const float* __restrict__ t1,
                                  const float* __restrict__ w2, const float* __restrict__ b2,
                                  const float* __restrict__ g2, const float* __restrict__ t2,
                                  float* __restrict__ w1f, float* __restrict__ b1f,
                                  float* __restrict__ w2f, float* __restrict__ b2f) {
  __shared__ double mu[10];
  __shared__ double S[10][10];
  const double cnt = (double)B_ * N_ * K_;
  const int t = threadIdx.x;
  if (t < 10) mu[t] = mom[t] / cnt;
  if (t < 55) {
    int e = t, i = 0;
    while (e >= 10 - i) { e -= 10 - i; ++i; }
    const int j = i + e;
    const double v = mom[10 + t] / cnt;
    S[i][j] = v;
    S[j][i] = v;
  }
  __syncthreads();
  const float *w, *bias, *gg, *bt;
  float *wf, *bf;
  int c;
  if (t < 64) { w = w1; bias = b1; gg = g1; bt = t1; wf = w1f; bf = b1f; c = t; }
  else if (t < 96) { w = w2; bias = b2; gg = g2; bt = t2; wf = w2f; bf = b2f; c = t - 64; }
  else return;
  double wd[10];
#pragma unroll
  for (int d = 0; d < 10; ++d) wd[d] = (double)w[c * 10 + d];
  const double cbv = (double)bias[c];
  double mz = cbv;
  for (int d = 0; d < 10; ++d) mz += wd[d] * mu[d];
  double e2 = cbv * cbv;
  for (int d = 0; d < 10; ++d) e2 += 2.0 * cbv * wd[d] * mu[d];
  for (int d = 0; d < 10; ++d)
    for (int e = 0; e < 10; ++e) e2 += wd[d] * wd[e] * S[d][e];
  const double var = e2 - mz * mz;
  const double a = (double)gg[c] / sqrt(var + 1e-5);
  const double shift = (double)bt[c] - a * mz;
#pragma unroll
  for (int d = 0; d < 10; ++d) wf[c * 10 + d] = (float)(a * wd[d]);
  bf[c] = (float)(a * cbv + shift);
}

// ---------------------------------------------------------------------------
// Per-channel BN stats over (B*N) samples of a (B,N,C) fp32 buffer -> affine
// ---------------------------------------------------------------------------
__global__ __launch_bounds__(256) void stats_kernel(const float* __restrict__ act, int C,
                                                    const float* __restrict__ g,
                                                    const float* __restrict__ bt,
                                                    float* __restrict__ a, float* __restrict__ bb) {
  const int c = blockIdx.x;
  float s1 = 0.f, s2 = 0.f;
  for (int s = threadIdx.x; s < B_ * N_; s += 256) {
    const float v = act[(size_t)s * C + c];
    s1 += v;
    s2 += v * v;
  }
#pragma unroll
  for (int off = 32; off > 0; off >>= 1) {
    s1 += __shfl_xor(s1, off);
    s2 += __shfl_xor(s2, off);
  }
  __shared__ float r1[4], r2[4];
  const int w = threadIdx.x >> 6;
  if ((threadIdx.x & 63) == 0) { r1[w] = s1; r2[w] = s2; }
  __syncthreads();
  if (threadIdx.x == 0) {
    const double S1 = (double)r1[0] + r1[1] + r1[2] + r1[3];
    const double S2 = (double)r2[0] + r2[1] + r2[2] + r2[3];
    const double cnt = (double)B_ * N_;
    const double mean = S1 / cnt;
    const double var = S2 / cnt - mean * mean;
    const double av = (double)g[c] / sqrt(var + 1e-5);
    a[c] = (float)av;
    bb[c] = (float)((double)bt[c] - av * mean);
  }
}

// ---------------------------------------------------------------------------
// GEMM: per-thread point, input is a contiguous row (B,N,CI) fp32
// ---------------------------------------------------------------------------
template <int CI, int CO>
__global__ __launch_bounds__(256) void gemm_row_kernel(const float* __restrict__ in,
                                                       const float* __restrict__ w,
                                                       const float* __restrict__ bias,
                                                       float* __restrict__ out) {
  __shared__ float ws[CO * CI];
  __shared__ float bs[CO];
  for (int i = threadIdx.x; i < CO * CI; i += 256) ws[i] = w[i];
  for (int i = threadIdx.x; i < CO; i += 256) bs[i] = bias[i];
  __syncthreads();
  const int p = blockIdx.x * 256 + threadIdx.x;
  float f[CI];
  const float* ip = in + (size_t)p * CI;
#pragma unroll
  for (int c = 0; c < CI; c += 4) {
    const float4 v = *((const float4*)(ip + c));
    f[c] = v.x; f[c + 1] = v.y; f[c + 2] = v.z; f[c + 3] = v.w;
  }
  float* op = out + (size_t)p * CO;
  for (int o = 0; o < CO; ++o) {
    float acc = bs[o];
#pragma unroll
    for (int c = 0; c < CI; ++c) acc += ws[o * CI + c] * f[c];
    op[o] = acc;
  }
}

// GEMM: input is channel-major (B,CI,N) fp32 (coalesced across threads)
template <int CI, int CO>
__global__ __launch_bounds__(256) void gemm_col_kernel(const float* __restrict__ in,
                                                       const float* __restrict__ w,
                                                       const float* __restrict__ bias,
                                                       float* __restrict__ out) {
  __shared__ float ws[CO * CI];
  __shared__ float bs[CO];
  for (int i = threadIdx.x; i < CO * CI; i += 256) ws[i] = w[i];
  for (int i = threadIdx.x; i < CO; i += 256) bs[i] = bias[i];
  __syncthreads();
  const int p = blockIdx.x * 256 + threadIdx.x;
  const int b = p >> 13, n = p & (N_ - 1);
  float f[CI];
#pragma unroll
  for (int c = 0; c < CI; ++c) f[c] = in[((size_t)b * CI + c) * N_ + n];
  float* op = out + (size_t)p * CO;
  for (int o = 0; o < CO; ++o) {
    float acc = bs[o];
#pragma unroll
    for (int c = 0; c < CI; ++c) acc += ws[o * CI + c] * f[c];
    op[o] = acc;
  }
}

// ---------------------------------------------------------------------------
// Transpose pool weights to [c][o] for contiguous per-c rows
// ---------------------------------------------------------------------------
__global__ __launch_bounds__(256) void prep_kernel(const float* __restrict__ w1,
                                                   const float* __restrict__ w2,
                                                   float* __restrict__ wT1,
                                                   float* __restrict__ wT2) {
  const int t = blockIdx.x * 256 + threadIdx.x;
  if (t < 128 * 128) {
    const int o = t >> 7, c = t & 127;
    wT1[c * 128 + o] = w1[t];
  }
  const int t2 = t - 128 * 128;
  if (t2 >= 0 && t2 < 64 * 64) {
    const int o = t2 >> 6, c = t2 & 63;
    wT2[c * 64 + o] = w2[t2];
  }
}

// ---------------------------------------------------------------------------
// Fused LSE + attentive pool.
//   xcat[0:CSF]  = relu(w'.spatial + b')          (folded lse BN)
//   xcat[CSF:C]  = act(af*feat + bf)  broadcast over k
//   scores = wpT^T. xcat + pb ; softmax over k ; out = sum_k p*xcat
// 32 lanes per point; lane (og=l>>1, kg=l&1) owns OT o-rows x 8 k-cols.
// ---------------------------------------------------------------------------
template <int CSF, int CF, int OT>
__global__ __launch_bounds__(128) void pool_kernel(
    const float* __restrict__ coords, const int* __restrict__ knn_i, const float* __restrict__ knn_d,
    const float* __restrict__ wlse, const float* __restrict__ blse,
    const float* __restrict__ feat, const float* __restrict__ af, const float* __restrict__ bf,
    const float slope,
    const float* __restrict__ wpT, const float* __restrict__ pb,
    float* __restrict__ out) {
  constexpr int C = CSF + CF;
  __shared__ float xcat[4][C][16];
  __shared__ float sp[4][10][16];
  const int g = threadIdx.x >> 5;
  const int l = threadIdx.x & 31;
  const int pid = blockIdx.x * 4 + g;
  const int b = pid >> 13, n = pid & (N_ - 1);

  // Phase A: spatial rows (one k per lane 0..15)
  if (l < 16) {
    const int k = l;
    const int id = knn_i[(size_t)pid * K_ + k];
    const float dd = knn_d[(size_t)pid * K_ + k];
    const float* cb = coords + (size_t)b * N_ * 3;
    const float cx = cb[n * 3 + 0], cy = cb[n * 3 + 1], cz = cb[n * 3 + 2];
    const float nx = cb[id * 3 + 0], ny = cb[id * 3 + 1], nz = cb[id * 3 + 2];
    sp[g][0][k] = cx; sp[g][1][k] = cy; sp[g][2][k] = cz;
    sp[g][3][k] = nx; sp[g][4][k] = ny; sp[g][5][k] = nz;
    sp[g][6][k] = cx - nx; sp[g][7][k] = cy - ny; sp[g][8][k] = cz - nz;
    sp[g][9][k] = dd;
  }
  // Phase A2: feature rows (affine + leaky/relu), broadcast over k
#pragma unroll
  for (int r = 0; r < CF / 32; ++r) {
    const int c2 = r * 32 + l;
    float v = feat[(size_t)pid * CF + c2];
    v = af[c2] * v + bf[c2];
    v = (v >= 0.0f) ? v : slope * v;
    const float4 vv = make_float4(v, v, v, v);
    float4* row = (float4*)&xcat[g][CSF + c2][0];
    row[0] = vv; row[1] = vv; row[2] = vv; row[3] = vv;
  }
  __syncthreads();
  // Phase B: sf rows
#pragma unroll
  for (int r = 0; r < CSF / 32; ++r) {
    const int c = r * 32 + l;
    float z[16];
    const float bz = blse[c];
#pragma unroll
    for (int j = 0; j < 16; ++j) z[j] = bz;
#pragma unroll
    for (int d = 0; d < 10; ++d) {
      const float wv = wlse[c * 10 + d];
      float sv[16];
      const float4* sr = (const float4*)&sp[g][d][0];
      *((float4*)&sv[0]) = sr[0];
      *((float4*)&sv[4]) = sr[1];
      *((float4*)&sv[8]) = sr[2];
      *((float4*)&sv[12]) = sr[3];
#pragma unroll
      for (int j = 0; j < 16; ++j) z[j] += wv * sv[j];
    }
    float4* row = (float4*)&xcat[g][c][0];
    row[0] = make_float4(fmaxf(z[0], 0.f), fmaxf(z[1], 0.f), fmaxf(z[2], 0.f), fmaxf(z[3], 0.f));
    row[1] = make_float4(fmaxf(z[4], 0.f), fmaxf(z[5], 0.f), fmaxf(z[6], 0.f), fmaxf(z[7], 0.f));
    row[2] = make_float4(fmaxf(z[8], 0.f), fmaxf(z[9], 0.f), fmaxf(z[10], 0.f), fmaxf(z[11], 0.f));
    row[3] = make_float4(fmaxf(z[12], 0.f), fmaxf(z[13], 0.f), fmaxf(z[14], 0.f), fmaxf(z[15], 0.f));
  }
  __syncthreads();
  // Phase C: scores (OT o-rows x 8 k-cols per lane)
  const int kg = l & 1, og = l >> 1;
  float acc[OT][8];
#pragma unroll
  for (int i = 0; i < OT; ++i) {
    const float pbv = pb[og * OT + i];
#pragma unroll
    for (int j = 0; j < 8; ++j) acc[i][j] = pbv;
  }
  for (int c = 0; c < C; ++c) {
    float xv[8];
    const float* xr = &xcat[g][c][kg * 8];
    *((float4*)&xv[0]) = *((const float4*)(xr));
    *((float4*)&xv[4]) = *((const float4*)(xr + 4));
    float wv[OT];
    const float* wr = wpT + c * C + og * OT;
    *((float4*)&wv[0]) = *((const float4*)(wr));
    if constexpr (OT == 8) *((float4*)&wv[4]) = *((const float4*)(wr + 4));
#pragma unroll
    for (int i = 0; i < OT; ++i)
#pragma unroll
      for (int j = 0; j < 8; ++j) acc[i][j] += wv[i] * xv[j];
  }
  // Phase D: softmax over 16 k (pair exchange with lane^1) + weighted sum
  float res[OT];
#pragma unroll
  for (int i = 0; i < OT; ++i) {
    float mx = acc[i][0];
#pragma unroll
    for (int j = 1; j < 8; ++j) mx = fmaxf(mx, acc[i][j]);
    mx = fmaxf(mx, __shfl_xor(mx, 1));
    float ex[8];
    float sum = 0.f;
#pragma unroll
    for (int j = 0; j < 8; ++j) {
      ex[j] = __expf(acc[i][j] - mx);
      sum += ex[j];
    }
    sum += __shfl_xor(sum, 1);
    const int o = og * OT + i;
    float xv[8];
    const float* xr = &xcat[g][o][kg * 8];
    *((float4*)&xv[0]) = *((const float4*)(xr));
    *((float4*)&xv[4]) = *((const float4*)(xr + 4));
    float part = 0.f;
#pragma unroll
    for (int j = 0; j < 8; ++j) part += ex[j] * xv[j];
    part += __shfl_xor(part, 1);
    res[i] = part / sum;
  }
  if (kg == 0) {
    float* op = out + (size_t)pid * C + og * OT;
    *((float4*)op) = make_float4(res[0], res[1], res[2], res[3]);
    if constexpr (OT == 8) *((float4*)(op + 4)) = make_float4(res[4], res[5], res[6], res[7]);
  }
}

// ---------------------------------------------------------------------------
// Final: out[b, o, n] = relu(affine(y3 | yr))   (LeakyReLU(0.01) of relu == id)
// ---------------------------------------------------------------------------
__global__ __launch_bounds__(256) void final_kernel(const float* __restrict__ y3,
                                                    const float* __restrict__ yr,
                                                    const float* __restrict__ a3, const float* __restrict__ b3,
                                                    const float* __restrict__ ar, const float* __restrict__ br,
                                                    float* __restrict__ out) {
  const int blk = blockIdx.x;
  const int b = blk >> 9;
  const int n0 = (blk & 511) << 4;
  const int c = threadIdx.x;
  const float* src;
  float av, bv;
  int cc;
  if (c < 128) { src = y3; av = a3[c]; bv = b3[c]; cc = c; }
  else { src = yr; av = ar[c - 128]; bv = br[c - 128]; cc = c - 128; }
  float v[16];
#pragma unroll
  for (int nl = 0; nl < 16; ++nl) {
    const float x = av * src[((size_t)(b * N_ + n0 + nl)) * 128 + cc] + bv;
    v[nl] = fmaxf(x, 0.0f);
  }
  float* op = out + ((size_t)(b * 256 + c)) * N_ + n0;
#pragma unroll
  for (int j = 0; j < 4; ++j)
    *((float4*)(op + 4 * j)) = make_float4(v[4 * j], v[4 * j + 1], v[4 * j + 2], v[4 * j + 3]);
}

// ---------------------------------------------------------------------------
extern "C" void kernel_launch(void* const* d_in, const int* in_sizes, int n_in,
                              void* d_out, int out_size, void* d_ws, size_t ws_size,
                              hipStream_t stream) {
  (void)in_sizes; (void)n_in; (void)out_size; (void)ws_size;
  const float* coords   = (const float*)d_in[0];
  const float* features = (const float*)d_in[1];
  const float* mlp1_w = (const float*)d_in[2];
  const float* mlp1_b = (const float*)d_in[3];
  const float* mlp1_g = (const float*)d_in[4];
  const float* mlp1_t = (const float*)d_in[5];
  const float* lse1_w = (const float*)d_in[6];
  const float* lse1_b = (const float*)d_in[7];
  const float* lse1_g = (const float*)d_in[8];
  const float* lse1_t = (const float*)d_in[9];
  const float* mlpp1_w = (const float*)d_in[10];
  const float* mlpp1_b = (const float*)d_in[11];
  const float* mlpp1_g = (const float*)d_in[12];
  const float* mlpp1_t = (const float*)d_in[13];
  const float* lse2_w = (const float*)d_in[14];
  const float* lse2_b = (const float*)d_in[15];
  const float* lse2_g = (const float*)d_in[16];
  const float* lse2_t = (const float*)d_in[17];
  const float* mlp2_w = (const float*)d_in[18];
  const float* mlp2_b = (const float*)d_in[19];
  const float* mlp2_g = (const float*)d_in[20];
  const float* mlp2_t = (const float*)d_in[21];
  const float* res_w = (const float*)d_in[22];
  const float* res_b = (const float*)d_in[23];
  const float* res_g = (const float*)d_in[24];
  const float* res_t = (const float*)d_in[25];
  const float* pool1_w = (const float*)d_in[26];
  const float* pool1_b = (const float*)d_in[27];
  const float* pool2_w = (const float*)d_in[28];
  const float* pool2_b = (const float*)d_in[29];

  float* wsf = (float*)d_ws;
  int* knn_i = (int*)d_ws;                 // 262144 ints
  float* knn_d = wsf + 262144;             // 262144
  float* y1 = wsf + 524288;                // (B,N,64)  1048576
  float* pooled1 = wsf + 1572864;          // (B,N,128) 2097152
  float* y2 = wsf + 3670016;               // (B,N,32)  524288
  float* pooled2 = wsf + 4194304;          // (B,N,64)  1048576
  float* y3 = wsf + 5242880;               // (B,N,128) 2097152
  float* yr = wsf + 7340032;               // (B,N,128) 2097152
  double* mom = (double*)(wsf + 9437184);  // 65 doubles (pad to 192 floats)
  float* am1 = wsf + 9437376; float* ab1 = am1 + 64;
  float* am2 = ab1 + 64;      float* ab2 = am2 + 32;
  float* am3 = ab2 + 32;      float* ab3 = am3 + 128;
  float* amr = ab3 + 128;     float* abr = amr + 128;
  float* w1f = abr + 128;     // 640
  float* b1f = w1f + 640;     // 64
  float* w2f = b1f + 64;      // 320
  float* b2f = w2f + 320;     // 32
  float* wT1 = b2f + 32;      // 16384
  float* wT2 = wT1 + 16384;   // 4096

  hipMemsetAsync(mom, 0, 65 * sizeof(double), stream);
  knn_kernel<<<dim3(N_ / 4, B_), 256, 0, stream>>>(coords, knn_i, knn_d);
  moments_kernel<<<64, 256, 0, stream>>>(coords, knn_i, knn_d, mom);
  gemm_col_kernel<32, 64><<<64, 256, 0, stream>>>(features, mlp1_w, mlp1_b, y1);
  stats_kernel<<<64, 256, 0, stream>>>(y1, 64, mlp1_g, mlp1_t, am1, ab1);
  lse_affine_kernel<<<1, 128, 0, stream>>>(mom, lse1_w, lse1_b, lse1_g, lse1_t,
                                           lse2_w, lse2_b, lse2_g, lse2_t,
                                           w1f, b1f, w2f, b2f);
  prep_kernel<<<80, 256, 0, stream>>>(pool1_w, pool2_w, wT1, wT2);
  pool_kernel<64, 64, 8><<<B_ * N_ / 4, 128, 0, stream>>>(
      coords, knn_i, knn_d, w1f, b1f, y1, am1, ab1, 0.2f, wT1, pool1_b, pooled1);
  gemm_row_kernel<128, 32><<<64, 256, 0, stream>>>(pooled1, mlpp1_w, mlpp1_b, y2);
  stats_kernel<<<32, 256, 0, stream>>>(y2, 32, mlpp1_g, mlpp1_t, am2, ab2);
  pool_kernel<32, 32, 4><<<B_ * N_ / 4, 128, 0, stream>>>(
      coords, knn_i, knn_d, w2f, b2f, y2, am2, ab2, 0.0f, wT2, pool2_b, pooled2);
  gemm_row_kernel<64, 128><<<64, 256, 0, stream>>>(pooled2, mlp2_w, mlp2_b, y3);
  gemm_col_kernel<32, 128><<<64, 256, 0, stream>>>(features, res_w, res_b, yr);
  stats_kernel<<<128, 256, 0, stream>>>(y3, 128, mlp2_g, mlp2_t, am3, ab3);
  stats_kernel<<<128, 256, 0, stream>>>(yr, 128, res_g, res_t, amr, abr);
  final_kernel<<<B_ * 512, 256, 0, stream>>>(y3, yr, am3, ab3, amr, abr, (float*)d_out);
}

// Round 2
// 689.011 us; speedup vs baseline: 1.0853x; 1.0853x over previous
//
#include <hip/hip_runtime.h>

static constexpr int N_ = 8192;
static constexpr int B_ = 2;
static constexpr int K_ = 16;

// ---------------------------------------------------------------------------
// KNN: wave-per-query cooperative top-16 (squared L2, self excluded)
// ---------------------------------------------------------------------------
__global__ __launch_bounds__(256) void knn_kernel(const float* __restrict__ coords,
                                                  int* __restrict__ oidx,
                                                  float* __restrict__ odist) {
  __shared__ float4 pts[2048];
  const int b = blockIdx.y;
  const int wv = threadIdx.x >> 6;
  const int lane = threadIdx.x & 63;
  const int q = blockIdx.x * 4 + wv;
  const float* cb = coords + (size_t)b * N_ * 3;
  const float qx = cb[q * 3 + 0], qy = cb[q * 3 + 1], qz = cb[q * 3 + 2];
  const float qsq = __fadd_rn(__fadd_rn(__fmul_rn(qx, qx), __fmul_rn(qy, qy)), __fmul_rn(qz, qz));
  float kd = INFINITY;  // sorted top-16 lives in lanes 0..15 (ascending)
  int ki = 0;
  for (int t0 = 0; t0 < N_; t0 += 2048) {
    __syncthreads();
    for (int i = threadIdx.x; i < 2048; i += 256) {
      const int p = t0 + i;
      const float x = cb[p * 3 + 0], y = cb[p * 3 + 1], z = cb[p * 3 + 2];
      const float sq = __fadd_rn(__fadd_rn(__fmul_rn(x, x), __fmul_rn(y, y)), __fmul_rn(z, z));
      pts[i] = make_float4(x, y, z, sq);
    }
    __syncthreads();
    for (int s = 0; s < 2048; s += 64) {
      const int j = t0 + s + lane;
      const float4 p = pts[s + lane];
      const float dot = __fadd_rn(__fadd_rn(__fmul_rn(qx, p.x), __fmul_rn(qy, p.y)), __fmul_rn(qz, p.z));
      float d2 = __fsub_rn(__fadd_rn(qsq, p.w), __fmul_rn(2.0f, dot));
      if (j == q) d2 = INFINITY;
      float tau = __shfl(kd, 15);
      unsigned long long m = __ballot(d2 < tau);
      while (m) {
        const int src = __builtin_ctzll(m);
        const float dc = __shfl(d2, src);
        const int jc = t0 + s + src;
        const float sd = __shfl_up(kd, 1);
        const int si = __shfl_up(ki, 1);
        const bool c1 = kd > dc;
        const bool c2 = (lane > 0) && (sd > dc);
        kd = c1 ? (c2 ? sd : dc) : kd;
        ki = c1 ? (c2 ? si : jc) : ki;
        m &= (m - 1);
        tau = __shfl(kd, 15);
        m &= __ballot(d2 < tau);
      }
    }
  }
  if (lane < 16) {
    oidx[((size_t)b * N_ + q) * K_ + lane] = ki;
    odist[((size_t)b * N_ + q) * K_ + lane] = fmaxf(kd, 0.0f);
  }
}

// ---------------------------------------------------------------------------
// Spatial feature moments (shared by lse1/lse2 BN stats)
// ---------------------------------------------------------------------------
__global__ __launch_bounds__(256) void moments_kernel(const float* __restrict__ coords,
                                                      const int* __restrict__ knn_i,
                                                      const float* __restrict__ knn_d,
                                                      double* __restrict__ mom) {
  const int t = blockIdx.x * 256 + threadIdx.x;
  const int b = t >> 13, n = t & (N_ - 1);
  float acc[65];
#pragma unroll
  for (int e = 0; e < 65; ++e) acc[e] = 0.0f;
  const float* cb = coords + (size_t)b * N_ * 3;
  const float cx = cb[n * 3 + 0], cy = cb[n * 3 + 1], cz = cb[n * 3 + 2];
  for (int k = 0; k < K_; ++k) {
    const int id = knn_i[(size_t)t * K_ + k];
    const float dd = knn_d[(size_t)t * K_ + k];
    const float nx = cb[id * 3 + 0], ny = cb[id * 3 + 1], nz = cb[id * 3 + 2];
    const float s[10] = {cx, cy, cz, nx, ny, nz, cx - nx, cy - ny, cz - nz, dd};
    int e = 0;
#pragma unroll
    for (int i = 0; i < 10; ++i) acc[e++] += s[i];
#pragma unroll
    for (int i = 0; i < 10; ++i)
#pragma unroll
      for (int jj = i; jj < 10; ++jj) acc[e++] += s[i] * s[jj];
  }
#pragma unroll
  for (int e = 0; e < 65; ++e) {
    float v = acc[e];
#pragma unroll
    for (int off = 32; off > 0; off >>= 1) v += __shfl_xor(v, off);
    acc[e] = v;
  }
  __shared__ float buf[4][65];
  const int lane = threadIdx.x & 63, w = threadIdx.x >> 6;
  if (lane == 0) {
#pragma unroll
    for (int e = 0; e < 65; ++e) buf[w][e] = acc[e];
  }
  __syncthreads();
  if (threadIdx.x < 65) {
    const float tot = buf[0][threadIdx.x] + buf[1][threadIdx.x] + buf[2][threadIdx.x] + buf[3][threadIdx.x];
    atomicAdd(&mom[threadIdx.x], (double)tot);
  }
}

// ---------------------------------------------------------------------------
// lse BN affine from moments
// ---------------------------------------------------------------------------
__global__ void lse_affine_kernel(const double* __restrict__ mom,
                                  const float* __restrict__ w1, const float* __restrict__ b1,
                                  const float* __restrict__ g1, const float* __restrict__ t1,
                                  const float* __restrict__ w2, const float* __restrict__ b2,
                                  const float* __restrict__ g2, const float* __restrict__ t2,
                                  float* __restrict__ w1f, float* __restrict__ b1f,
                                  float* __restrict__ w2f, float* __restrict__ b2f) {
  __shared__ double mu[10];
  __shared__ double S[10][10];
  const double cnt = (double)B_ * N_ * K_;
  const int t = threadIdx.x;
  if (t < 10) mu[t] = mom[t] / cnt;
  if (t < 55) {
    int e = t, i = 0;
    while (e >= 10 - i) { e -= 10 - i; ++i; }
    const int j = i + e;
    const double v = mom[10 + t] / cnt;
    S[i][j] = v;
    S[j][i] = v;
  }
  __syncthreads();
  const float *w, *bias, *gg, *bt;
  float *wf, *bf;
  int c;
  if (t < 64) { w = w1; bias = b1; gg = g1; bt = t1; wf = w1f; bf = b1f; c = t; }
  else if (t < 96) { w = w2; bias = b2; gg = g2; bt = t2; wf = w2f; bf = b2f; c = t - 64; }
  else return;
  double wd[10];
#pragma unroll
  for (int d = 0; d < 10; ++d) wd[d] = (double)w[c * 10 + d];
  const double cbv = (double)bias[c];
  double mz = cbv;
  for (int d = 0; d < 10; ++d) mz += wd[d] * mu[d];
  double e2 = cbv * cbv;
  for (int d = 0; d < 10; ++d) e2 += 2.0 * cbv * wd[d] * mu[d];
  for (int d = 0; d < 10; ++d)
    for (int e = 0; e < 10; ++e) e2 += wd[d] * wd[e] * S[d][e];
  const double var = e2 - mz * mz;
  const double a = (double)gg[c] / sqrt(var + 1e-5);
  const double shift = (double)bt[c] - a * mz;
#pragma unroll
  for (int d = 0; d < 10; ++d) wf[c * 10 + d] = (float)(a * wd[d]);
  bf[c] = (float)(a * cbv + shift);
}

// ---------------------------------------------------------------------------
// GEMM + fused BN-stat partial sums (shuffle-reduce, double atomics)
// ---------------------------------------------------------------------------
template <int CI, int CO, bool ROWMAJ>
__global__ __launch_bounds__(256) void gemm_stats_kernel(const float* __restrict__ in,
                                                         const float* __restrict__ w,
                                                         const float* __restrict__ bias,
                                                         float* __restrict__ out,
                                                         double* __restrict__ sacc) {
  __shared__ float ws[CO * CI];
  __shared__ float bs[CO];
  __shared__ float part[4][CO][2];
  for (int i = threadIdx.x; i < CO * CI; i += 256) ws[i] = w[i];
  for (int i = threadIdx.x; i < CO; i += 256) bs[i] = bias[i];
  __syncthreads();
  const int p = blockIdx.x * 256 + threadIdx.x;
  float f[CI];
  if (ROWMAJ) {
    const float* ip = in + (size_t)p * CI;
#pragma unroll
    for (int c = 0; c < CI; c += 4) {
      const float4 v = *(const float4*)(ip + c);
      f[c] = v.x; f[c + 1] = v.y; f[c + 2] = v.z; f[c + 3] = v.w;
    }
  } else {
    const int b = p >> 13, n = p & (N_ - 1);
#pragma unroll
    for (int c = 0; c < CI; ++c) f[c] = in[((size_t)b * CI + c) * N_ + n];
  }
  const int lane = threadIdx.x & 63, wvid = threadIdx.x >> 6;
  float* op = out + (size_t)p * CO;
  for (int o4 = 0; o4 < CO; o4 += 4) {
    float a4[4];
#pragma unroll
    for (int u = 0; u < 4; ++u) {
      float a = bs[o4 + u];
#pragma unroll
      for (int c = 0; c < CI; ++c) a += ws[(o4 + u) * CI + c] * f[c];
      a4[u] = a;
    }
    *(float4*)(op + o4) = make_float4(a4[0], a4[1], a4[2], a4[3]);
#pragma unroll
    for (int u = 0; u < 4; ++u) {
      float s1 = a4[u], s2 = a4[u] * a4[u];
#pragma unroll
      for (int off = 32; off > 0; off >>= 1) {
        s1 += __shfl_xor(s1, off);
        s2 += __shfl_xor(s2, off);
      }
      if (lane == 0) { part[wvid][o4 + u][0] = s1; part[wvid][o4 + u][1] = s2; }
    }
  }
  __syncthreads();
  if (threadIdx.x < CO) {
    const int o = threadIdx.x;
    const double s1 = (double)part[0][o][0] + part[1][o][0] + part[2][o][0] + part[3][o][0];
    const double s2 = (double)part[0][o][1] + part[1][o][1] + part[2][o][1] + part[3][o][1];
    atomicAdd(&sacc[o], s1);
    atomicAdd(&sacc[CO + o], s2);
  }
}

__global__ void finalize_kernel(const double* __restrict__ sacc, int CO,
                                const float* __restrict__ g, const float* __restrict__ bt,
                                float* __restrict__ a, float* __restrict__ bb) {
  const int c = threadIdx.x;
  if (c >= CO) return;
  const double cnt = (double)(B_ * N_);
  const double mean = sacc[c] / cnt;
  const double var = sacc[CO + c] / cnt - mean * mean;
  const double av = (double)g[c] / sqrt(var + 1e-5);
  a[c] = (float)av;
  bb[c] = (float)((double)bt[c] - av * mean);
}

// ---------------------------------------------------------------------------
// Transpose pool weights to [c][o]
// ---------------------------------------------------------------------------
__global__ __launch_bounds__(256) void prep_kernel(const float* __restrict__ w1,
                                                   const float* __restrict__ w2,
                                                   float* __restrict__ wT1,
                                                   float* __restrict__ wT2) {
  const int t = blockIdx.x * 256 + threadIdx.x;
  if (t < 128 * 128) {
    const int o = t >> 7, c = t & 127;
    wT1[c * 128 + o] = w1[t];
  }
  const int t2 = t - 128 * 128;
  if (t2 >= 0 && t2 < 64 * 64) {
    const int o = t2 >> 6, c = t2 & 63;
    wT2[c * 64 + o] = w2[t2];
  }
}

// ---------------------------------------------------------------------------
// Fused LSE + attentive pool. ONE WAVE (64 lanes) per point; 4 points/block.
// xcat is k-major [16][C]: stride-C writes are 2-way bank aliased (free),
// Phase-C reads are contiguous float4 over c (broadcast, conflict-free).
// Lane l: og=l>>1 in [0,32), kg=l&1; lane owns OT o-rows x 8 k-cols.
// ---------------------------------------------------------------------------
template <int CSF, int CF, int OT>
__global__ __launch_bounds__(256, 4) void pool_kernel(
    const float* __restrict__ coords, const int* __restrict__ knn_i, const float* __restrict__ knn_d,
    const float* __restrict__ wlse, const float* __restrict__ blse,
    const float* __restrict__ feat, const float* __restrict__ af, const float* __restrict__ bf,
    const float slope,
    const float* __restrict__ wpT, const float* __restrict__ pb,
    float* __restrict__ out) {
  constexpr int C = CSF + CF;
  __shared__ float xcat[4][16][C];
  __shared__ float sp[4][10][16];
  const int g = threadIdx.x >> 6;
  const int l = threadIdx.x & 63;
  const int pid = blockIdx.x * 4 + g;
  const int b = pid >> 13, n = pid & (N_ - 1);
  const float* cb = coords + (size_t)b * N_ * 3;

  // Phase A: spatial columns (one k per lane 0..15)
  if (l < 16) {
    const int id = knn_i[(size_t)pid * K_ + l];
    const float dd = knn_d[(size_t)pid * K_ + l];
    const float cx = cb[n * 3 + 0], cy = cb[n * 3 + 1], cz = cb[n * 3 + 2];
    const float nx = cb[id * 3 + 0], ny = cb[id * 3 + 1], nz = cb[id * 3 + 2];
    sp[g][0][l] = cx; sp[g][1][l] = cy; sp[g][2][l] = cz;
    sp[g][3][l] = nx; sp[g][4][l] = ny; sp[g][5][l] = nz;
    sp[g][6][l] = cx - nx; sp[g][7][l] = cy - ny; sp[g][8][l] = cz - nz;
    sp[g][9][l] = dd;
  }
  // Phase A2: feature channels (affine + act), broadcast over k
  if (CF == 64 || l < CF) {
    float v = feat[(size_t)pid * CF + l];
    v = af[l] * v + bf[l];
    v = (v >= 0.0f) ? v : slope * v;
#pragma unroll
    for (int j = 0; j < 16; ++j) xcat[g][j][CSF + l] = v;
  }
  __syncthreads();
  // Phase B: sf channels (folded lse BN, relu)
  if (CSF == 64 || l < CSF) {
    float z[16];
    const float bz = blse[l];
#pragma unroll
    for (int j = 0; j < 16; ++j) z[j] = bz;
#pragma unroll
    for (int d = 0; d < 10; ++d) {
      const float wv = wlse[l * 10 + d];
      const float4* sr = (const float4*)&sp[g][d][0];
      const float4 s0 = sr[0], s1 = sr[1], s2 = sr[2], s3 = sr[3];
      z[0] += wv * s0.x; z[1] += wv * s0.y; z[2] += wv * s0.z; z[3] += wv * s0.w;
      z[4] += wv * s1.x; z[5] += wv * s1.y; z[6] += wv * s1.z; z[7] += wv * s1.w;
      z[8] += wv * s2.x; z[9] += wv * s2.y; z[10] += wv * s2.z; z[11] += wv * s2.w;
      z[12] += wv * s3.x; z[13] += wv * s3.y; z[14] += wv * s3.z; z[15] += wv * s3.w;
    }
#pragma unroll
    for (int j = 0; j < 16; ++j) xcat[g][j][l] = fmaxf(z[j], 0.0f);
  }
  __syncthreads();
  // Phase C: scores GEMM, c unrolled by 4 (float4 LDS reads over c)
  const int kg = l & 1, og = l >> 1;
  float acc[OT][8];
#pragma unroll
  for (int i = 0; i < OT; ++i) {
    const float pbv = pb[og * OT + i];
#pragma unroll
    for (int j = 0; j < 8; ++j) acc[i][j] = pbv;
  }
  for (int c0 = 0; c0 < C; c0 += 4) {
    float4 xv[8];
#pragma unroll
    for (int j = 0; j < 8; ++j) xv[j] = *(const float4*)&xcat[g][kg * 8 + j][c0];
#pragma unroll
    for (int cc = 0; cc < 4; ++cc) {
      float wv[OT];
      const float* wr = wpT + (size_t)(c0 + cc) * C + og * OT;
      if constexpr (OT == 4) {
        const float4 w4 = *(const float4*)wr;
        wv[0] = w4.x; wv[1] = w4.y; wv[2] = w4.z; wv[3] = w4.w;
      } else {
        const float2 w2 = *(const float2*)wr;
        wv[0] = w2.x; wv[1] = w2.y;
      }
#pragma unroll
      for (int i = 0; i < OT; ++i) {
#pragma unroll
        for (int j = 0; j < 8; ++j) {
          const float xc = (cc == 0) ? xv[j].x : (cc == 1) ? xv[j].y : (cc == 2) ? xv[j].z : xv[j].w;
          acc[i][j] += wv[i] * xc;
        }
      }
    }
  }
  // Phase D: softmax over 16 k (pair exchange with lane^1) + weighted sum
  float sum[OT];
#pragma unroll
  for (int i = 0; i < OT; ++i) {
    float mx = acc[i][0];
#pragma unroll
    for (int j = 1; j < 8; ++j) mx = fmaxf(mx, acc[i][j]);
    mx = fmaxf(mx, __shfl_xor(mx, 1));
    float s = 0.f;
#pragma unroll
    for (int j = 0; j < 8; ++j) {
      acc[i][j] = __expf(acc[i][j] - mx);
      s += acc[i][j];
    }
    sum[i] = s + __shfl_xor(s, 1);
  }
  float res[OT];
#pragma unroll
  for (int i = 0; i < OT; ++i) res[i] = 0.f;
#pragma unroll
  for (int j = 0; j < 8; ++j) {
    const float* xr = &xcat[g][kg * 8 + j][og * OT];
    if constexpr (OT == 4) {
      const float4 xq = *(const float4*)xr;
      res[0] += acc[0][j] * xq.x; res[1] += acc[1][j] * xq.y;
      res[2] += acc[2][j] * xq.z; res[3] += acc[3][j] * xq.w;
    } else {
      const float2 xq = *(const float2*)xr;
      res[0] += acc[0][j] * xq.x; res[1] += acc[1][j] * xq.y;
    }
  }
#pragma unroll
  for (int i = 0; i < OT; ++i) res[i] = (res[i] + __shfl_xor(res[i], 1)) / sum[i];
  if (kg == 0) {
    float* op = out + (size_t)pid * C + og * OT;
    if constexpr (OT == 4) *(float4*)op = make_float4(res[0], res[1], res[2], res[3]);
    else *(float2*)op = make_float2(res[0], res[1]);
  }
}

// ---------------------------------------------------------------------------
// Final: out[b, o, n] = relu(affine(y3 | yr))
// ---------------------------------------------------------------------------
__global__ __launch_bounds__(256) void final_kernel(const float* __restrict__ y3,
                                                    const float* __restrict__ yr,
                                                    const float* __restrict__ a3, const float* __restrict__ b3,
                                                    const float* __restrict__ ar, const float* __restrict__ br,
                                                    float* __restrict__ out) {
  const int blk = blockIdx.x;
  const int b = blk >> 9;
  const int n0 = (blk & 511) << 4;
  const int c = threadIdx.x;
  const float* src;
  float av, bv;
  int cc;
  if (c < 128) { src = y3; av = a3[c]; bv = b3[c]; cc = c; }
  else { src = yr; av = ar[c - 128]; bv = br[c - 128]; cc = c - 128; }
  float v[16];
#pragma unroll
  for (int nl = 0; nl < 16; ++nl) {
    const float x = av * src[((size_t)(b * N_ + n0 + nl)) * 128 + cc] + bv;
    v[nl] = fmaxf(x, 0.0f);
  }
  float* op = out + ((size_t)(b * 256 + c)) * N_ + n0;
#pragma unroll
  for (int j = 0; j < 4; ++j)
    *((float4*)(op + 4 * j)) = make_float4(v[4 * j], v[4 * j + 1], v[4 * j + 2], v[4 * j + 3]);
}

// ---------------------------------------------------------------------------
extern "C" void kernel_launch(void* const* d_in, const int* in_sizes, int n_in,
                              void* d_out, int out_size, void* d_ws, size_t ws_size,
                              hipStream_t stream) {
  (void)in_sizes; (void)n_in; (void)out_size; (void)ws_size;
  const float* coords   = (const float*)d_in[0];
  const float* features = (const float*)d_in[1];
  const float* mlp1_w = (const float*)d_in[2];
  const float* mlp1_b = (const float*)d_in[3];
  const float* mlp1_g = (const float*)d_in[4];
  const float* mlp1_t = (const float*)d_in[5];
  const float* lse1_w = (const float*)d_in[6];
  const float* lse1_b = (const float*)d_in[7];
  const float* lse1_g = (const float*)d_in[8];
  const float* lse1_t = (const float*)d_in[9];
  const float* mlpp1_w = (const float*)d_in[10];
  const float* mlpp1_b = (const float*)d_in[11];
  const float* mlpp1_g = (const float*)d_in[12];
  const float* mlpp1_t = (const float*)d_in[13];
  const float* lse2_w = (const float*)d_in[14];
  const float* lse2_b = (const float*)d_in[15];
  const float* lse2_g = (const float*)d_in[16];
  const float* lse2_t = (const float*)d_in[17];
  const float* mlp2_w = (const float*)d_in[18];
  const float* mlp2_b = (const float*)d_in[19];
  const float* mlp2_g = (const float*)d_in[20];
  const float* mlp2_t = (const float*)d_in[21];
  const float* res_w = (const float*)d_in[22];
  const float* res_b = (const float*)d_in[23];
  const float* res_g = (const float*)d_in[24];
  const float* res_t = (const float*)d_in[25];
  const float* pool1_w = (const float*)d_in[26];
  const float* pool1_b = (const float*)d_in[27];
  const float* pool2_w = (const float*)d_in[28];
  const float* pool2_b = (const float*)d_in[29];

  float* wsf = (float*)d_ws;
  int* knn_i = (int*)d_ws;                 // 262144 ints
  float* knn_d = wsf + 262144;             // 262144
  float* y1 = wsf + 524288;                // (B,N,64)
  float* pooled1 = wsf + 1572864;          // (B,N,128)
  float* y2 = wsf + 3670016;               // (B,N,32)
  float* pooled2 = wsf + 4194304;          // (B,N,64)
  float* y3 = wsf + 5242880;               // (B,N,128)
  float* yr = wsf + 7340032;               // (B,N,128)
  // double accumulators: mom[65] | mlp1[128] | mlpp1[64] | mlp2[256] | res[256]
  double* dacc = (double*)(wsf + 9437184);
  double* mom = dacc;
  double* sacc_mlp1 = dacc + 65;
  double* sacc_mlpp1 = dacc + 193;
  double* sacc_mlp2 = dacc + 257;
  double* sacc_res = dacc + 513;           // end at 769 doubles
  float* fpar = wsf + 9437184 + 1600;      // float param region
  float* am1 = fpar;          float* ab1 = am1 + 64;
  float* am2 = ab1 + 64;      float* ab2 = am2 + 32;
  float* am3 = ab2 + 32;      float* ab3 = am3 + 128;
  float* amr = ab3 + 128;     float* abr = amr + 128;
  float* w1f = abr + 128;     // 640
  float* b1f = w1f + 640;     // 64
  float* w2f = b1f + 64;      // 320
  float* b2f = w2f + 320;     // 32
  float* wT1 = b2f + 32;      // 16384
  float* wT2 = wT1 + 16384;   // 4096

  hipMemsetAsync(dacc, 0, 769 * sizeof(double), stream);
  knn_kernel<<<dim3(N_ / 4, B_), 256, 0, stream>>>(coords, knn_i, knn_d);
  moments_kernel<<<64, 256, 0, stream>>>(coords, knn_i, knn_d, mom);
  gemm_stats_kernel<32, 64, false><<<64, 256, 0, stream>>>(features, mlp1_w, mlp1_b, y1, sacc_mlp1);
  finalize_kernel<<<1, 64, 0, stream>>>(sacc_mlp1, 64, mlp1_g, mlp1_t, am1, ab1);
  lse_affine_kernel<<<1, 128, 0, stream>>>(mom, lse1_w, lse1_b, lse1_g, lse1_t,
                                           lse2_w, lse2_b, lse2_g, lse2_t,
                                           w1f, b1f, w2f, b2f);
  prep_kernel<<<80, 256, 0, stream>>>(pool1_w, pool2_w, wT1, wT2);
  pool_kernel<64, 64, 4><<<B_ * N_ / 4, 256, 0, stream>>>(
      coords, knn_i, knn_d, w1f, b1f, y1, am1, ab1, 0.2f, wT1, pool1_b, pooled1);
  gemm_stats_kernel<128, 32, true><<<64, 256, 0, stream>>>(pooled1, mlpp1_w, mlpp1_b, y2, sacc_mlpp1);
  finalize_kernel<<<1, 32, 0, stream>>>(sacc_mlpp1, 32, mlpp1_g, mlpp1_t, am2, ab2);
  pool_kernel<32, 32, 2><<<B_ * N_ / 4, 256, 0, stream>>>(
      coords, knn_i, knn_d, w2f, b2f, y2, am2, ab2, 0.0f, wT2, pool2_b, pooled2);
  gemm_stats_kernel<64, 128, true><<<64, 256, 0, stream>>>(pooled2, mlp2_w, mlp2_b, y3, sacc_mlp2);
  gemm_stats_kernel<32, 128, false><<<64, 256, 0, stream>>>(features, res_w, res_b, yr, sacc_res);
  finalize_kernel<<<1, 128, 0, stream>>>(sacc_mlp2, 128, mlp2_g, mlp2_t, am3, ab3);
  finalize_kernel<<<1, 128, 0, stream>>>(sacc_res, 128, res_g, res_t, amr, abr);
  final_kernel<<<B_ * 512, 256, 0, stream>>>(y3, yr, am3, ab3, amr, abr, (float*)d_out);
}

// Round 3
// 648.792 us; speedup vs baseline: 1.1526x; 1.0620x over previous
//
#include <hip/hip_runtime.h>

static constexpr int N_ = 8192;
static constexpr int B_ = 2;
static constexpr int K_ = 16;

// ---------------------------------------------------------------------------
// KNN: wave-per-query cooperative top-16 (squared L2, self excluded)
// 8 waves (8 queries) per block share one 2048-point LDS tile.
// tau (current 16th distance) is maintained across steps, not re-shuffled.
// ---------------------------------------------------------------------------
__global__ __launch_bounds__(512) void knn_kernel(const float* __restrict__ coords,
                                                  int* __restrict__ oidx,
                                                  float* __restrict__ odist) {
  __shared__ float4 pts[2048];
  const int b = blockIdx.y;
  const int wv = threadIdx.x >> 6;
  const int lane = threadIdx.x & 63;
  const int q = blockIdx.x * 8 + wv;
  const float* cb = coords + (size_t)b * N_ * 3;
  const float qx = cb[q * 3 + 0], qy = cb[q * 3 + 1], qz = cb[q * 3 + 2];
  const float qsq = __fadd_rn(__fadd_rn(__fmul_rn(qx, qx), __fmul_rn(qy, qy)), __fmul_rn(qz, qz));
  float kd = INFINITY;  // sorted top-16 lives in lanes 0..15 (ascending)
  int ki = 0;
  float tau = INFINITY;  // == __shfl(kd, 15), updated only on insert
  for (int t0 = 0; t0 < N_; t0 += 2048) {
    __syncthreads();
    for (int i = threadIdx.x; i < 2048; i += 512) {
      const int p = t0 + i;
      const float x = cb[p * 3 + 0], y = cb[p * 3 + 1], z = cb[p * 3 + 2];
      const float sq = __fadd_rn(__fadd_rn(__fmul_rn(x, x), __fmul_rn(y, y)), __fmul_rn(z, z));
      pts[i] = make_float4(x, y, z, sq);
    }
    __syncthreads();
    for (int s = 0; s < 2048; s += 64) {
      const int j = t0 + s + lane;
      const float4 p = pts[s + lane];
      const float dot = __fadd_rn(__fadd_rn(__fmul_rn(qx, p.x), __fmul_rn(qy, p.y)), __fmul_rn(qz, p.z));
      float d2 = __fsub_rn(__fadd_rn(qsq, p.w), __fmul_rn(2.0f, dot));
      if (j == q) d2 = INFINITY;
      unsigned long long m = __ballot(d2 < tau);
      while (m) {
        const int src = __builtin_ctzll(m);  // ascending index -> top_k tie stability
        const float dc = __shfl(d2, src);
        const int jc = t0 + s + src;
        const float sd = __shfl_up(kd, 1);
        const int si = __shfl_up(ki, 1);
        const bool c1 = kd > dc;             // strict: equals keep earlier entries
        const bool c2 = (lane > 0) && (sd > dc);
        kd = c1 ? (c2 ? sd : dc) : kd;
        ki = c1 ? (c2 ? si : jc) : ki;
        m &= (m - 1);
        tau = __shfl(kd, 15);
        m &= __ballot(d2 < tau);
      }
    }
  }
  if (lane < 16) {
    oidx[((size_t)b * N_ + q) * K_ + lane] = ki;
    odist[((size_t)b * N_ + q) * K_ + lane] = fmaxf(kd, 0.0f);
  }
}

// ---------------------------------------------------------------------------
// Spatial feature moments (shared by lse1/lse2 BN stats)
// ---------------------------------------------------------------------------
__global__ __launch_bounds__(256) void moments_kernel(const float* __restrict__ coords,
                                                      const int* __restrict__ knn_i,
                                                      const float* __restrict__ knn_d,
                                                      double* __restrict__ mom) {
  const int t = blockIdx.x * 256 + threadIdx.x;
  const int b = t >> 13, n = t & (N_ - 1);
  float acc[65];
#pragma unroll
  for (int e = 0; e < 65; ++e) acc[e] = 0.0f;
  const float* cb = coords + (size_t)b * N_ * 3;
  const float cx = cb[n * 3 + 0], cy = cb[n * 3 + 1], cz = cb[n * 3 + 2];
  for (int k = 0; k < K_; ++k) {
    const int id = knn_i[(size_t)t * K_ + k];
    const float dd = knn_d[(size_t)t * K_ + k];
    const float nx = cb[id * 3 + 0], ny = cb[id * 3 + 1], nz = cb[id * 3 + 2];
    const float s[10] = {cx, cy, cz, nx, ny, nz, cx - nx, cy - ny, cz - nz, dd};
    int e = 0;
#pragma unroll
    for (int i = 0; i < 10; ++i) acc[e++] += s[i];
#pragma unroll
    for (int i = 0; i < 10; ++i)
#pragma unroll
      for (int jj = i; jj < 10; ++jj) acc[e++] += s[i] * s[jj];
  }
#pragma unroll
  for (int e = 0; e < 65; ++e) {
    float v = acc[e];
#pragma unroll
    for (int off = 32; off > 0; off >>= 1) v += __shfl_xor(v, off);
    acc[e] = v;
  }
  __shared__ float buf[4][65];
  const int lane = threadIdx.x & 63, w = threadIdx.x >> 6;
  if (lane == 0) {
#pragma unroll
    for (int e = 0; e < 65; ++e) buf[w][e] = acc[e];
  }
  __syncthreads();
  if (threadIdx.x < 65) {
    const float tot = buf[0][threadIdx.x] + buf[1][threadIdx.x] + buf[2][threadIdx.x] + buf[3][threadIdx.x];
    atomicAdd(&mom[threadIdx.x], (double)tot);
  }
}

// ---------------------------------------------------------------------------
// lse BN affine from moments
// ---------------------------------------------------------------------------
__global__ void lse_affine_kernel(const double* __restrict__ mom,
                                  const float* __restrict__ w1, const float* __restrict__ b1,
                                  const float* __restrict__ g1, const float* __restrict__ t1,
                                  const float* __restrict__ w2, const float* __restrict__ b2,
                                  const float* __restrict__ g2, const float* __restrict__ t2,
                                  float* __restrict__ w1f, float* __restrict__ b1f,
                                  float* __restrict__ w2f, float* __restrict__ b2f) {
  __shared__ double mu[10];
  __shared__ double S[10][10];
  const double cnt = (double)B_ * N_ * K_;
  const int t = threadIdx.x;
  if (t < 10) mu[t] = mom[t] / cnt;
  if (t < 55) {
    int e = t, i = 0;
    while (e >= 10 - i) { e -= 10 - i; ++i; }
    const int j = i + e;
    const double v = mom[10 + t] / cnt;
    S[i][j] = v;
    S[j][i] = v;
  }
  __syncthreads();
  const float *w, *bias, *gg, *bt;
  float *wf, *bf;
  int c;
  if (t < 64) { w = w1; bias = b1; gg = g1; bt = t1; wf = w1f; bf = b1f; c = t; }
  else if (t < 96) { w = w2; bias = b2; gg = g2; bt = t2; wf = w2f; bf = b2f; c = t - 64; }
  else return;
  double wd[10];
#pragma unroll
  for (int d = 0; d < 10; ++d) wd[d] = (double)w[c * 10 + d];
  const double cbv = (double)bias[c];
  double mz = cbv;
  for (int d = 0; d < 10; ++d) mz += wd[d] * mu[d];
  double e2 = cbv * cbv;
  for (int d = 0; d < 10; ++d) e2 += 2.0 * cbv * wd[d] * mu[d];
  for (int d = 0; d < 10; ++d)
    for (int e = 0; e < 10; ++e) e2 += wd[d] * wd[e] * S[d][e];
  const double var = e2 - mz * mz;
  const double a = (double)gg[c] / sqrt(var + 1e-5);
  const double shift = (double)bt[c] - a * mz;
#pragma unroll
  for (int d = 0; d < 10; ++d) wf[c * 10 + d] = (float)(a * wd[d]);
  bf[c] = (float)(a * cbv + shift);
}

// ---------------------------------------------------------------------------
// GEMM + fused BN-stat partial sums.
//  ACCRES=true : accumulator-resident (CO regs), weights read wave-uniform
//                from global (scalarizes to s_load) — for large CI, small CO.
//  ACCRES=false: input-resident f[CI], weights staged in LDS.
// Block = 128 threads (2 waves), grid = 128 blocks, 1 point/thread.
// ---------------------------------------------------------------------------
template <int CI, int CO, bool ROWMAJ, bool ACCRES>
__global__ __launch_bounds__(128) void gemm_stats_kernel(const float* __restrict__ in,
                                                         const float* __restrict__ w,
                                                         const float* __restrict__ bias,
                                                         float* __restrict__ out,
                                                         double* __restrict__ sacc) {
  __shared__ float part[2][CO][2];
  const int p = blockIdx.x * 128 + threadIdx.x;
  const int lane = threadIdx.x & 63, wvid = threadIdx.x >> 6;
  float* op = out + (size_t)p * CO;

  if constexpr (ACCRES) {
    float acc[CO];
#pragma unroll
    for (int o = 0; o < CO; ++o) acc[o] = bias[o];
    const float* ip = in + (size_t)p * CI;
#pragma unroll 4
    for (int c0 = 0; c0 < CI; c0 += 4) {
      const float4 f4 = *(const float4*)(ip + c0);
#pragma unroll
      for (int u = 0; u < 4; ++u) {
        const float fv = (u == 0) ? f4.x : (u == 1) ? f4.y : (u == 2) ? f4.z : f4.w;
#pragma unroll
        for (int o = 0; o < CO; ++o) acc[o] += w[o * CI + c0 + u] * fv;
      }
    }
    for (int o4 = 0; o4 < CO; o4 += 4) {
      *(float4*)(op + o4) = make_float4(acc[o4], acc[o4 + 1], acc[o4 + 2], acc[o4 + 3]);
#pragma unroll
      for (int u = 0; u < 4; ++u) {
        float s1 = acc[o4 + u], s2 = acc[o4 + u] * acc[o4 + u];
#pragma unroll
        for (int off = 32; off > 0; off >>= 1) {
          s1 += __shfl_xor(s1, off);
          s2 += __shfl_xor(s2, off);
        }
        if (lane == 0) { part[wvid][o4 + u][0] = s1; part[wvid][o4 + u][1] = s2; }
      }
    }
  } else {
    __shared__ float ws[CO * CI];
    __shared__ float bs[CO];
    for (int i = threadIdx.x; i < CO * CI; i += 128) ws[i] = w[i];
    for (int i = threadIdx.x; i < CO; i += 128) bs[i] = bias[i];
    __syncthreads();
    float f[CI];
    if (ROWMAJ) {
      const float* ip = in + (size_t)p * CI;
#pragma unroll
      for (int c = 0; c < CI; c += 4) {
        const float4 v = *(const float4*)(ip + c);
        f[c] = v.x; f[c + 1] = v.y; f[c + 2] = v.z; f[c + 3] = v.w;
      }
    } else {
      const int b = p >> 13, n = p & (N_ - 1);
#pragma unroll
      for (int c = 0; c < CI; ++c) f[c] = in[((size_t)b * CI + c) * N_ + n];
    }
    for (int o4 = 0; o4 < CO; o4 += 4) {
      float a4[4];
#pragma unroll
      for (int u = 0; u < 4; ++u) {
        float a = bs[o4 + u];
#pragma unroll
        for (int c = 0; c < CI; ++c) a += ws[(o4 + u) * CI + c] * f[c];
        a4[u] = a;
      }
      *(float4*)(op + o4) = make_float4(a4[0], a4[1], a4[2], a4[3]);
#pragma unroll
      for (int u = 0; u < 4; ++u) {
        float s1 = a4[u], s2 = a4[u] * a4[u];
#pragma unroll
        for (int off = 32; off > 0; off >>= 1) {
          s1 += __shfl_xor(s1, off);
          s2 += __shfl_xor(s2, off);
        }
        if (lane == 0) { part[wvid][o4 + u][0] = s1; part[wvid][o4 + u][1] = s2; }
      }
    }
  }
  __syncthreads();
  if (threadIdx.x < CO) {
    const int o = threadIdx.x;
    const double s1 = (double)part[0][o][0] + part[1][o][0];
    const double s2 = (double)part[0][o][1] + part[1][o][1];
    atomicAdd(&sacc[o], s1);
    atomicAdd(&sacc[CO + o], s2);
  }
}

__global__ void finalize_kernel(const double* __restrict__ sacc, int CO,
                                const float* __restrict__ g, const float* __restrict__ bt,
                                float* __restrict__ a, float* __restrict__ bb) {
  const int c = threadIdx.x;
  if (c >= CO) return;
  const double cnt = (double)(B_ * N_);
  const double mean = sacc[c] / cnt;
  const double var = sacc[CO + c] / cnt - mean * mean;
  const double av = (double)g[c] / sqrt(var + 1e-5);
  a[c] = (float)av;
  bb[c] = (float)((double)bt[c] - av * mean);
}

// ---------------------------------------------------------------------------
// Transpose pool weights to [c][o]
// ---------------------------------------------------------------------------
__global__ __launch_bounds__(256) void prep_kernel(const float* __restrict__ w1,
                                                   const float* __restrict__ w2,
                                                   float* __restrict__ wT1,
                                                   float* __restrict__ wT2) {
  const int t = blockIdx.x * 256 + threadIdx.x;
  if (t < 128 * 128) {
    const int o = t >> 7, c = t & 127;
    wT1[c * 128 + o] = w1[t];
  }
  const int t2 = t - 128 * 128;
  if (t2 >= 0 && t2 < 64 * 64) {
    const int o = t2 >> 6, c = t2 & 63;
    wT2[c * 64 + o] = w2[t2];
  }
}

// ---------------------------------------------------------------------------
// Fused LSE + attentive pool. ONE WAVE per point; 4 points/block.
// ---------------------------------------------------------------------------
template <int CSF, int CF, int OT>
__global__ __launch_bounds__(256, 4) void pool_kernel(
    const float* __restrict__ coords, const int* __restrict__ knn_i, const float* __restrict__ knn_d,
    const float* __restrict__ wlse, const float* __restrict__ blse,
    const float* __restrict__ feat, const float* __restrict__ af, const float* __restrict__ bf,
    const float slope,
    const float* __restrict__ wpT, const float* __restrict__ pb,
    float* __restrict__ out) {
  constexpr int C = CSF + CF;
  __shared__ float xcat[4][16][C];
  __shared__ float sp[4][10][16];
  const int g = threadIdx.x >> 6;
  const int l = threadIdx.x & 63;
  const int pid = blockIdx.x * 4 + g;
  const int b = pid >> 13, n = pid & (N_ - 1);
  const float* cb = coords + (size_t)b * N_ * 3;

  if (l < 16) {
    const int id = knn_i[(size_t)pid * K_ + l];
    const float dd = knn_d[(size_t)pid * K_ + l];
    const float cx = cb[n * 3 + 0], cy = cb[n * 3 + 1], cz = cb[n * 3 + 2];
    const float nx = cb[id * 3 + 0], ny = cb[id * 3 + 1], nz = cb[id * 3 + 2];
    sp[g][0][l] = cx; sp[g][1][l] = cy; sp[g][2][l] = cz;
    sp[g][3][l] = nx; sp[g][4][l] = ny; sp[g][5][l] = nz;
    sp[g][6][l] = cx - nx; sp[g][7][l] = cy - ny; sp[g][8][l] = cz - nz;
    sp[g][9][l] = dd;
  }
  if (CF == 64 || l < CF) {
    float v = feat[(size_t)pid * CF + l];
    v = af[l] * v + bf[l];
    v = (v >= 0.0f) ? v : slope * v;
#pragma unroll
    for (int j = 0; j < 16; ++j) xcat[g][j][CSF + l] = v;
  }
  __syncthreads();
  if (CSF == 64 || l < CSF) {
    float z[16];
    const float bz = blse[l];
#pragma unroll
    for (int j = 0; j < 16; ++j) z[j] = bz;
#pragma unroll
    for (int d = 0; d < 10; ++d) {
      const float wv = wlse[l * 10 + d];
      const float4* sr = (const float4*)&sp[g][d][0];
      const float4 s0 = sr[0], s1 = sr[1], s2 = sr[2], s3 = sr[3];
      z[0] += wv * s0.x; z[1] += wv * s0.y; z[2] += wv * s0.z; z[3] += wv * s0.w;
      z[4] += wv * s1.x; z[5] += wv * s1.y; z[6] += wv * s1.z; z[7] += wv * s1.w;
      z[8] += wv * s2.x; z[9] += wv * s2.y; z[10] += wv * s2.z; z[11] += wv * s2.w;
      z[12] += wv * s3.x; z[13] += wv * s3.y; z[14] += wv * s3.z; z[15] += wv * s3.w;
    }
#pragma unroll
    for (int j = 0; j < 16; ++j) xcat[g][j][l] = fmaxf(z[j], 0.0f);
  }
  __syncthreads();
  const int kg = l & 1, og = l >> 1;
  float acc[OT][8];
#pragma unroll
  for (int i = 0; i < OT; ++i) {
    const float pbv = pb[og * OT + i];
#pragma unroll
    for (int j = 0; j < 8; ++j) acc[i][j] = pbv;
  }
  for (int c0 = 0; c0 < C; c0 += 4) {
    float4 xv[8];
#pragma unroll
    for (int j = 0; j < 8; ++j) xv[j] = *(const float4*)&xcat[g][kg * 8 + j][c0];
#pragma unroll
    for (int cc = 0; cc < 4; ++cc) {
      float wv[OT];
      const float* wr = wpT + (size_t)(c0 + cc) * C + og * OT;
      if constexpr (OT == 4) {
        const float4 w4 = *(const float4*)wr;
        wv[0] = w4.x; wv[1] = w4.y; wv[2] = w4.z; wv[3] = w4.w;
      } else {
        const float2 w2 = *(const float2*)wr;
        wv[0] = w2.x; wv[1] = w2.y;
      }
#pragma unroll
      for (int i = 0; i < OT; ++i) {
#pragma unroll
        for (int j = 0; j < 8; ++j) {
          const float xc = (cc == 0) ? xv[j].x : (cc == 1) ? xv[j].y : (cc == 2) ? xv[j].z : xv[j].w;
          acc[i][j] += wv[i] * xc;
        }
      }
    }
  }
  float sum[OT];
#pragma unroll
  for (int i = 0; i < OT; ++i) {
    float mx = acc[i][0];
#pragma unroll
    for (int j = 1; j < 8; ++j) mx = fmaxf(mx, acc[i][j]);
    mx = fmaxf(mx, __shfl_xor(mx, 1));
    float s = 0.f;
#pragma unroll
    for (int j = 0; j < 8; ++j) {
      acc[i][j] = __expf(acc[i][j] - mx);
      s += acc[i][j];
    }
    sum[i] = s + __shfl_xor(s, 1);
  }
  float res[OT];
#pragma unroll
  for (int i = 0; i < OT; ++i) res[i] = 0.f;
#pragma unroll
  for (int j = 0; j < 8; ++j) {
    const float* xr = &xcat[g][kg * 8 + j][og * OT];
    if constexpr (OT == 4) {
      const float4 xq = *(const float4*)xr;
      res[0] += acc[0][j] * xq.x; res[1] += acc[1][j] * xq.y;
      res[2] += acc[2][j] * xq.z; res[3] += acc[3][j] * xq.w;
    } else {
      const float2 xq = *(const float2*)xr;
      res[0] += acc[0][j] * xq.x; res[1] += acc[1][j] * xq.y;
    }
  }
#pragma unroll
  for (int i = 0; i < OT; ++i) res[i] = (res[i] + __shfl_xor(res[i], 1)) / sum[i];
  if (kg == 0) {
    float* op = out + (size_t)pid * C + og * OT;
    if constexpr (OT == 4) *(float4*)op = make_float4(res[0], res[1], res[2], res[3]);
    else *(float2*)op = make_float2(res[0], res[1]);
  }
}

// ---------------------------------------------------------------------------
// Final: out[b, o, n] = relu(affine(y3 | yr))
// ---------------------------------------------------------------------------
__global__ __launch_bounds__(256) void final_kernel(const float* __restrict__ y3,
                                                    const float* __restrict__ yr,
                                                    const float* __restrict__ a3, const float* __restrict__ b3,
                                                    const float* __restrict__ ar, const float* __restrict__ br,
                                                    float* __restrict__ out) {
  const int blk = blockIdx.x;
  const int b = blk >> 9;
  const int n0 = (blk & 511) << 4;
  const int c = threadIdx.x;
  const float* src;
  float av, bv;
  int cc;
  if (c < 128) { src = y3; av = a3[c]; bv = b3[c]; cc = c; }
  else { src = yr; av = ar[c - 128]; bv = br[c - 128]; cc = c - 128; }
  float v[16];
#pragma unroll
  for (int nl = 0; nl < 16; ++nl) {
    const float x = av * src[((size_t)(b * N_ + n0 + nl)) * 128 + cc] + bv;
    v[nl] = fmaxf(x, 0.0f);
  }
  float* op = out + ((size_t)(b * 256 + c)) * N_ + n0;
#pragma unroll
  for (int j = 0; j < 4; ++j)
    *((float4*)(op + 4 * j)) = make_float4(v[4 * j], v[4 * j + 1], v[4 * j + 2], v[4 * j + 3]);
}

// ---------------------------------------------------------------------------
extern "C" void kernel_launch(void* const* d_in, const int* in_sizes, int n_in,
                              void* d_out, int out_size, void* d_ws, size_t ws_size,
                              hipStream_t stream) {
  (void)in_sizes; (void)n_in; (void)out_size; (void)ws_size;
  const float* coords   = (const float*)d_in[0];
  const float* features = (const float*)d_in[1];
  const float* mlp1_w = (const float*)d_in[2];
  const float* mlp1_b = (const float*)d_in[3];
  const float* mlp1_g = (const float*)d_in[4];
  const float* mlp1_t = (const float*)d_in[5];
  const float* lse1_w = (const float*)d_in[6];
  const float* lse1_b = (const float*)d_in[7];
  const float* lse1_g = (const float*)d_in[8];
  const float* lse1_t = (const float*)d_in[9];
  const float* mlpp1_w = (const float*)d_in[10];
  const float* mlpp1_b = (const float*)d_in[11];
  const float* mlpp1_g = (const float*)d_in[12];
  const float* mlpp1_t = (const float*)d_in[13];
  const float* lse2_w = (const float*)d_in[14];
  const float* lse2_b = (const float*)d_in[15];
  const float* lse2_g = (const float*)d_in[16];
  const float* lse2_t = (const float*)d_in[17];
  const float* mlp2_w = (const float*)d_in[18];
  const float* mlp2_b = (const float*)d_in[19];
  const float* mlp2_g = (const float*)d_in[20];
  const float* mlp2_t = (const float*)d_in[21];
  const float* res_w = (const float*)d_in[22];
  const float* res_b = (const float*)d_in[23];
  const float* res_g = (const float*)d_in[24];
  const float* res_t = (const float*)d_in[25];
  const float* pool1_w = (const float*)d_in[26];
  const float* pool1_b = (const float*)d_in[27];
  const float* pool2_w = (const float*)d_in[28];
  const float* pool2_b = (const float*)d_in[29];

  float* wsf = (float*)d_ws;
  int* knn_i = (int*)d_ws;                 // 262144 ints
  float* knn_d = wsf + 262144;             // 262144
  float* y1 = wsf + 524288;                // (B,N,64)
  float* pooled1 = wsf + 1572864;          // (B,N,128)
  float* y2 = wsf + 3670016;               // (B,N,32)
  float* pooled2 = wsf + 4194304;          // (B,N,64)
  float* y3 = wsf + 5242880;               // (B,N,128)
  float* yr = wsf + 7340032;               // (B,N,128)
  double* dacc = (double*)(wsf + 9437184);
  double* mom = dacc;
  double* sacc_mlp1 = dacc + 65;
  double* sacc_mlpp1 = dacc + 193;
  double* sacc_mlp2 = dacc + 257;
  double* sacc_res = dacc + 513;
  float* fpar = wsf + 9437184 + 1600;
  float* am1 = fpar;          float* ab1 = am1 + 64;
  float* am2 = ab1 + 64;      float* ab2 = am2 + 32;
  float* am3 = ab2 + 32;      float* ab3 = am3 + 128;
  float* amr = ab3 + 128;     float* abr = amr + 128;
  float* w1f = abr + 128;
  float* b1f = w1f + 640;
  float* w2f = b1f + 64;
  float* b2f = w2f + 320;
  float* wT1 = b2f + 32;
  float* wT2 = wT1 + 16384;

  hipMemsetAsync(dacc, 0, 769 * sizeof(double), stream);
  knn_kernel<<<dim3(N_ / 8, B_), 512, 0, stream>>>(coords, knn_i, knn_d);
  moments_kernel<<<64, 256, 0, stream>>>(coords, knn_i, knn_d, mom);
  gemm_stats_kernel<32, 64, false, false><<<128, 128, 0, stream>>>(features, mlp1_w, mlp1_b, y1, sacc_mlp1);
  finalize_kernel<<<1, 64, 0, stream>>>(sacc_mlp1, 64, mlp1_g, mlp1_t, am1, ab1);
  lse_affine_kernel<<<1, 128, 0, stream>>>(mom, lse1_w, lse1_b, lse1_g, lse1_t,
                                           lse2_w, lse2_b, lse2_g, lse2_t,
                                           w1f, b1f, w2f, b2f);
  prep_kernel<<<80, 256, 0, stream>>>(pool1_w, pool2_w, wT1, wT2);
  pool_kernel<64, 64, 4><<<B_ * N_ / 4, 256, 0, stream>>>(
      coords, knn_i, knn_d, w1f, b1f, y1, am1, ab1, 0.2f, wT1, pool1_b, pooled1);
  gemm_stats_kernel<128, 32, true, true><<<128, 128, 0, stream>>>(pooled1, mlpp1_w, mlpp1_b, y2, sacc_mlpp1);
  finalize_kernel<<<1, 32, 0, stream>>>(sacc_mlpp1, 32, mlpp1_g, mlpp1_t, am2, ab2);
  pool_kernel<32, 32, 2><<<B_ * N_ / 4, 256, 0, stream>>>(
      coords, knn_i, knn_d, w2f, b2f, y2, am2, ab2, 0.0f, wT2, pool2_b, pooled2);
  gemm_stats_kernel<64, 128, true, false><<<128, 128, 0, stream>>>(pooled2, mlp2_w, mlp2_b, y3, sacc_mlp2);
  gemm_stats_kernel<32, 128, false, false><<<128, 128, 0, stream>>>(features, res_w, res_b, yr, sacc_res);
  finalize_kernel<<<1, 128, 0, stream>>>(sacc_mlp2, 128, mlp2_g, mlp2_t, am3, ab3);
  finalize_kernel<<<1, 128, 0, stream>>>(sacc_res, 128, res_g, res_t, amr, abr);
  final_kernel<<<B_ * 512, 256, 0, stream>>>(y3, yr, am3, ab3, amr, abr, (float*)d_out);
}

// Round 4
// 608.400 us; speedup vs baseline: 1.2291x; 1.0664x over previous
//
#include <hip/hip_runtime.h>

static constexpr int N_ = 8192;
static constexpr int B_ = 2;
static constexpr int K_ = 16;

typedef __attribute__((ext_vector_type(8))) short bf16x8;
typedef __attribute__((ext_vector_type(4))) float f32x4;

__device__ __forceinline__ short f2bf(float f) {
  unsigned int u = __float_as_uint(f);
  unsigned int r = (u + 0x7FFFu + ((u >> 16) & 1u)) >> 16;
  return (short)r;
}

// ---------------------------------------------------------------------------
// KNN: TWO queries per wave share each candidate ds_read_b128.
// Drain ballot mask fully (no in-loop tau refresh: extra inserts are harmless).
// ---------------------------------------------------------------------------
__global__ __launch_bounds__(512) void knn_kernel(const float* __restrict__ coords,
                                                  int* __restrict__ oidx,
                                                  float* __restrict__ odist) {
  __shared__ float4 pts[2048];
  const int b = blockIdx.y;
  const int wv = threadIdx.x >> 6;
  const int lane = threadIdx.x & 63;
  const int q0 = blockIdx.x * 16 + wv * 2;
  const int q1 = q0 + 1;
  const float* cb = coords + (size_t)b * N_ * 3;
  const float qx0 = cb[q0 * 3 + 0], qy0 = cb[q0 * 3 + 1], qz0 = cb[q0 * 3 + 2];
  const float qx1 = cb[q1 * 3 + 0], qy1 = cb[q1 * 3 + 1], qz1 = cb[q1 * 3 + 2];
  const float qsq0 = __fadd_rn(__fadd_rn(__fmul_rn(qx0, qx0), __fmul_rn(qy0, qy0)), __fmul_rn(qz0, qz0));
  const float qsq1 = __fadd_rn(__fadd_rn(__fmul_rn(qx1, qx1), __fmul_rn(qy1, qy1)), __fmul_rn(qz1, qz1));
  float kd0 = INFINITY, kd1 = INFINITY;
  int ki0 = 0, ki1 = 0;
  float tau0 = INFINITY, tau1 = INFINITY;
  for (int t0 = 0; t0 < N_; t0 += 2048) {
    __syncthreads();
    for (int i = threadIdx.x; i < 2048; i += 512) {
      const int p = t0 + i;
      const float x = cb[p * 3 + 0], y = cb[p * 3 + 1], z = cb[p * 3 + 2];
      const float sq = __fadd_rn(__fadd_rn(__fmul_rn(x, x), __fmul_rn(y, y)), __fmul_rn(z, z));
      pts[i] = make_float4(x, y, z, sq);
    }
    __syncthreads();
    for (int s = 0; s < 2048; s += 64) {
      const int j = t0 + s + lane;
      const float4 p = pts[s + lane];
      const float dot0 = __fadd_rn(__fadd_rn(__fmul_rn(qx0, p.x), __fmul_rn(qy0, p.y)), __fmul_rn(qz0, p.z));
      const float dot1 = __fadd_rn(__fadd_rn(__fmul_rn(qx1, p.x), __fmul_rn(qy1, p.y)), __fmul_rn(qz1, p.z));
      float d20 = __fsub_rn(__fadd_rn(qsq0, p.w), __fmul_rn(2.0f, dot0));
      float d21 = __fsub_rn(__fadd_rn(qsq1, p.w), __fmul_rn(2.0f, dot1));
      if (j == q0) d20 = INFINITY;
      if (j == q1) d21 = INFINITY;
      unsigned long long m0 = __ballot(d20 < tau0);
      if (m0) {
        do {
          const int src = __builtin_ctzll(m0);  // ascending index -> tie stability
          const float dc = __shfl(d20, src);
          const int jc = t0 + s + src;
          const float sd = __shfl_up(kd0, 1);
          const int si = __shfl_up(ki0, 1);
          const bool c1 = kd0 > dc;
          const bool c2 = (lane > 0) && (sd > dc);
          kd0 = c1 ? (c2 ? sd : dc) : kd0;
          ki0 = c1 ? (c2 ? si : jc) : ki0;
          m0 &= (m0 - 1);
        } while (m0);
        tau0 = __shfl(kd0, 15);
      }
      unsigned long long m1 = __ballot(d21 < tau1);
      if (m1) {
        do {
          const int src = __builtin_ctzll(m1);
          const float dc = __shfl(d21, src);
          const int jc = t0 + s + src;
          const float sd = __shfl_up(kd1, 1);
          const int si = __shfl_up(ki1, 1);
          const bool c1 = kd1 > dc;
          const bool c2 = (lane > 0) && (sd > dc);
          kd1 = c1 ? (c2 ? sd : dc) : kd1;
          ki1 = c1 ? (c2 ? si : jc) : ki1;
          m1 &= (m1 - 1);
        } while (m1);
        tau1 = __shfl(kd1, 15);
      }
    }
  }
  if (lane < 16) {
    oidx[((size_t)b * N_ + q0) * K_ + lane] = ki0;
    odist[((size_t)b * N_ + q0) * K_ + lane] = fmaxf(kd0, 0.0f);
    oidx[((size_t)b * N_ + q1) * K_ + lane] = ki1;
    odist[((size_t)b * N_ + q1) * K_ + lane] = fmaxf(kd1, 0.0f);
  }
}

// ---------------------------------------------------------------------------
// Spatial feature moments (shared by lse1/lse2 BN stats). 128 blocks x 128 thr.
// ---------------------------------------------------------------------------
__global__ __launch_bounds__(128) void moments_kernel(const float* __restrict__ coords,
                                                      const int* __restrict__ knn_i,
                                                      const float* __restrict__ knn_d,
                                                      double* __restrict__ mom) {
  const int t = blockIdx.x * 128 + threadIdx.x;
  const int b = t >> 13, n = t & (N_ - 1);
  float acc[65];
#pragma unroll
  for (int e = 0; e < 65; ++e) acc[e] = 0.0f;
  const float* cb = coords + (size_t)b * N_ * 3;
  const float cx = cb[n * 3 + 0], cy = cb[n * 3 + 1], cz = cb[n * 3 + 2];
  for (int k = 0; k < K_; ++k) {
    const int id = knn_i[(size_t)t * K_ + k];
    const float dd = knn_d[(size_t)t * K_ + k];
    const float nx = cb[id * 3 + 0], ny = cb[id * 3 + 1], nz = cb[id * 3 + 2];
    const float s[10] = {cx, cy, cz, nx, ny, nz, cx - nx, cy - ny, cz - nz, dd};
    int e = 0;
#pragma unroll
    for (int i = 0; i < 10; ++i) acc[e++] += s[i];
#pragma unroll
    for (int i = 0; i < 10; ++i)
#pragma unroll
      for (int jj = i; jj < 10; ++jj) acc[e++] += s[i] * s[jj];
  }
#pragma unroll
  for (int e = 0; e < 65; ++e) {
    float v = acc[e];
#pragma unroll
    for (int off = 32; off > 0; off >>= 1) v += __shfl_xor(v, off);
    acc[e] = v;
  }
  __shared__ float buf[2][65];
  const int lane = threadIdx.x & 63, w = threadIdx.x >> 6;
  if (lane == 0) {
#pragma unroll
    for (int e = 0; e < 65; ++e) buf[w][e] = acc[e];
  }
  __syncthreads();
  if (threadIdx.x < 65) {
    atomicAdd(&mom[threadIdx.x], (double)(buf[0][threadIdx.x] + buf[1][threadIdx.x]));
  }
}

// ---------------------------------------------------------------------------
// Setup: lse BN affines from moments + convert pool weights to bf16 [o][c]
// ---------------------------------------------------------------------------
__global__ void setup_kernel(const double* __restrict__ mom,
                             const float* __restrict__ w1, const float* __restrict__ b1,
                             const float* __restrict__ g1, const float* __restrict__ t1,
                             const float* __restrict__ w2, const float* __restrict__ b2,
                             const float* __restrict__ g2, const float* __restrict__ t2,
                             float* __restrict__ w1f, float* __restrict__ b1f,
                             float* __restrict__ w2f, float* __restrict__ b2f,
                             const float* __restrict__ pw1, const float* __restrict__ pw2,
                             short* __restrict__ wB1, short* __restrict__ wB2) {
  const int t = threadIdx.x;
  for (int i = t; i < 128 * 128; i += 256) wB1[i] = f2bf(pw1[i]);
  for (int i = t; i < 64 * 64; i += 256) wB2[i] = f2bf(pw2[i]);
  __shared__ double mu[10];
  __shared__ double S[10][10];
  const double cnt = (double)B_ * N_ * K_;
  if (t < 10) mu[t] = mom[t] / cnt;
  if (t < 55) {
    int e = t, i = 0;
    while (e >= 10 - i) { e -= 10 - i; ++i; }
    const int j = i + e;
    const double v = mom[10 + t] / cnt;
    S[i][j] = v;
    S[j][i] = v;
  }
  __syncthreads();
  const float *w, *bias, *gg, *bt;
  float *wf, *bf;
  int c;
  if (t < 64) { w = w1; bias = b1; gg = g1; bt = t1; wf = w1f; bf = b1f; c = t; }
  else if (t < 96) { w = w2; bias = b2; gg = g2; bt = t2; wf = w2f; bf = b2f; c = t - 64; }
  else return;
  double wd[10];
#pragma unroll
  for (int d = 0; d < 10; ++d) wd[d] = (double)w[c * 10 + d];
  const double cbv = (double)bias[c];
  double mz = cbv;
  for (int d = 0; d < 10; ++d) mz += wd[d] * mu[d];
  double e2 = cbv * cbv;
  for (int d = 0; d < 10; ++d) e2 += 2.0 * cbv * wd[d] * mu[d];
  for (int d = 0; d < 10; ++d)
    for (int e = 0; e < 10; ++e) e2 += wd[d] * wd[e] * S[d][e];
  const double var = e2 - mz * mz;
  const double a = (double)gg[c] / sqrt(var + 1e-5);
  const double shift = (double)bt[c] - a * mz;
#pragma unroll
  for (int d = 0; d < 10; ++d) wf[c * 10 + d] = (float)(a * wd[d]);
  bf[c] = (float)(a * cbv + shift);
}

// ---------------------------------------------------------------------------
// GEMM + fused BN-stat partial sums (unchanged from R3)
// ---------------------------------------------------------------------------
template <int CI, int CO, bool ROWMAJ, bool ACCRES>
__global__ __launch_bounds__(128) void gemm_stats_kernel(const float* __restrict__ in,
                                                         const float* __restrict__ w,
                                                         const float* __restrict__ bias,
                                                         float* __restrict__ out,
                                                         double* __restrict__ sacc) {
  __shared__ float part[2][CO][2];
  const int p = blockIdx.x * 128 + threadIdx.x;
  const int lane = threadIdx.x & 63, wvid = threadIdx.x >> 6;
  float* op = out + (size_t)p * CO;

  if constexpr (ACCRES) {
    float acc[CO];
#pragma unroll
    for (int o = 0; o < CO; ++o) acc[o] = bias[o];
    const float* ip = in + (size_t)p * CI;
#pragma unroll 4
    for (int c0 = 0; c0 < CI; c0 += 4) {
      const float4 f4 = *(const float4*)(ip + c0);
#pragma unroll
      for (int u = 0; u < 4; ++u) {
        const float fv = (u == 0) ? f4.x : (u == 1) ? f4.y : (u == 2) ? f4.z : f4.w;
#pragma unroll
        for (int o = 0; o < CO; ++o) acc[o] += w[o * CI + c0 + u] * fv;
      }
    }
    for (int o4 = 0; o4 < CO; o4 += 4) {
      *(float4*)(op + o4) = make_float4(acc[o4], acc[o4 + 1], acc[o4 + 2], acc[o4 + 3]);
#pragma unroll
      for (int u = 0; u < 4; ++u) {
        float s1 = acc[o4 + u], s2 = acc[o4 + u] * acc[o4 + u];
#pragma unroll
        for (int off = 32; off > 0; off >>= 1) {
          s1 += __shfl_xor(s1, off);
          s2 += __shfl_xor(s2, off);
        }
        if (lane == 0) { part[wvid][o4 + u][0] = s1; part[wvid][o4 + u][1] = s2; }
      }
    }
  } else {
    __shared__ float ws[CO * CI];
    __shared__ float bs[CO];
    for (int i = threadIdx.x; i < CO * CI; i += 128) ws[i] = w[i];
    for (int i = threadIdx.x; i < CO; i += 128) bs[i] = bias[i];
    __syncthreads();
    float f[CI];
    if (ROWMAJ) {
      const float* ip = in + (size_t)p * CI;
#pragma unroll
      for (int c = 0; c < CI; c += 4) {
        const float4 v = *(const float4*)(ip + c);
        f[c] = v.x; f[c + 1] = v.y; f[c + 2] = v.z; f[c + 3] = v.w;
      }
    } else {
      const int b = p >> 13, n = p & (N_ - 1);
#pragma unroll
      for (int c = 0; c < CI; ++c) f[c] = in[((size_t)b * CI + c) * N_ + n];
    }
    for (int o4 = 0; o4 < CO; o4 += 4) {
      float a4[4];
#pragma unroll
      for (int u = 0; u < 4; ++u) {
        float a = bs[o4 + u];
#pragma unroll
        for (int c = 0; c < CI; ++c) a += ws[(o4 + u) * CI + c] * f[c];
        a4[u] = a;
      }
      *(float4*)(op + o4) = make_float4(a4[0], a4[1], a4[2], a4[3]);
#pragma unroll
      for (int u = 0; u < 4; ++u) {
        float s1 = a4[u], s2 = a4[u] * a4[u];
#pragma unroll
        for (int off = 32; off > 0; off >>= 1) {
          s1 += __shfl_xor(s1, off);
          s2 += __shfl_xor(s2, off);
        }
        if (lane == 0) { part[wvid][o4 + u][0] = s1; part[wvid][o4 + u][1] = s2; }
      }
    }
  }
  __syncthreads();
  if (threadIdx.x < CO) {
    const int o = threadIdx.x;
    atomicAdd(&sacc[o], (double)(part[0][o][0] + part[1][o][0]));
    atomicAdd(&sacc[CO + o], (double)(part[0][o][1] + part[1][o][1]));
  }
}

// ---------------------------------------------------------------------------
// Fused LSE + attentive pool, MFMA scores.
// Scores computed transposed: D[kk][o] = sum_c X[c][kk]*W[o][c] via
// mfma_f32_16x16x32_bf16 with A = X^T (from fp32 LDS, cvt), B = W (bf16,
// global/L1). D-layout: kk = quad*4+reg, o = tile*16 + (lane&15).
// Softmax over kk = per-lane reg max/sum + shfl_xor(16,32).
// BN affine for feat channels computed inline from double accumulators.
// ---------------------------------------------------------------------------
template <int CSF, int CF>
__global__ __launch_bounds__(256) void pool_kernel(
    const float* __restrict__ coords, const int* __restrict__ knn_i, const float* __restrict__ knn_d,
    const float* __restrict__ wlse, const float* __restrict__ blse,
    const float* __restrict__ feat, const double* __restrict__ sfe,
    const float* __restrict__ gfe, const float* __restrict__ tfe,
    const float slope,
    const short* __restrict__ wB, const float* __restrict__ pb,
    float* __restrict__ out) {
  constexpr int C = CSF + CF;
  constexpr int CP = C + 4;    // fp32 row stride (pad: 16-lane row reads -> 2-way)
  constexpr int NT = C / 16;   // o tiles
  constexpr int NC = C / 32;   // c chunks
  __shared__ float xcat[4][16][CP];
  __shared__ float sp[4][10][16];
  const int g = threadIdx.x >> 6;
  const int l = threadIdx.x & 63;
  const int quad = l >> 4, col = l & 15;
  const int pid = blockIdx.x * 4 + g;
  const int b = pid >> 13, n = pid & (N_ - 1);
  const float* cb = coords + (size_t)b * N_ * 3;

  // Phase A: spatial columns (lanes 0..15, one k each)
  if (l < 16) {
    const int id = knn_i[(size_t)pid * K_ + l];
    const float dd = knn_d[(size_t)pid * K_ + l];
    const float cx = cb[n * 3 + 0], cy = cb[n * 3 + 1], cz = cb[n * 3 + 2];
    const float nx = cb[id * 3 + 0], ny = cb[id * 3 + 1], nz = cb[id * 3 + 2];
    sp[g][0][l] = cx; sp[g][1][l] = cy; sp[g][2][l] = cz;
    sp[g][3][l] = nx; sp[g][4][l] = ny; sp[g][5][l] = nz;
    sp[g][6][l] = cx - nx; sp[g][7][l] = cy - ny; sp[g][8][l] = cz - nz;
    sp[g][9][l] = dd;
  }
  // Phase A2: feature channels, BN affine computed inline, broadcast over k
  if (l < CF) {
    const double cnt = (double)(B_ * N_);
    const double mean = sfe[l] / cnt;
    const double var = sfe[CF + l] / cnt - mean * mean;
    const double av = (double)gfe[l] / sqrt(var + 1e-5);
    const float af = (float)av;
    const float bfv = (float)((double)tfe[l] - av * mean);
    float v = feat[(size_t)pid * CF + l];
    v = af * v + bfv;
    v = (v >= 0.0f) ? v : slope * v;
#pragma unroll
    for (int j = 0; j < 16; ++j) xcat[g][j][CSF + l] = v;
  }
  __syncthreads();
  // Phase B: sf channels (folded lse BN, relu)
  if (l < CSF) {
    float z[16];
    const float bz = blse[l];
#pragma unroll
    for (int j = 0; j < 16; ++j) z[j] = bz;
#pragma unroll
    for (int d = 0; d < 10; ++d) {
      const float wv = wlse[l * 10 + d];
      const float4* sr = (const float4*)&sp[g][d][0];
      const float4 s0 = sr[0], s1 = sr[1], s2 = sr[2], s3 = sr[3];
      z[0] += wv * s0.x; z[1] += wv * s0.y; z[2] += wv * s0.z; z[3] += wv * s0.w;
      z[4] += wv * s1.x; z[5] += wv * s1.y; z[6] += wv * s1.z; z[7] += wv * s1.w;
      z[8] += wv * s2.x; z[9] += wv * s2.y; z[10] += wv * s2.z; z[11] += wv * s2.w;
      z[12] += wv * s3.x; z[13] += wv * s3.y; z[14] += wv * s3.z; z[15] += wv * s3.w;
    }
#pragma unroll
    for (int j = 0; j < 16; ++j) xcat[g][j][l] = fmaxf(z[j], 0.0f);
  }
  __syncthreads();
  // Phase C: MFMA scores
  f32x4 d[NT];
#pragma unroll
  for (int t = 0; t < NT; ++t) {
    const float pbv = pb[t * 16 + col];
    d[t][0] = pbv; d[t][1] = pbv; d[t][2] = pbv; d[t][3] = pbv;
  }
#pragma unroll
  for (int cc = 0; cc < NC; ++cc) {
    // A frag: A[m=kk=col][k=c] = xcat[col][cc*32 + quad*8 + j]
    const float* xr = &xcat[g][col][cc * 32 + quad * 8];
    const float4 xa = *(const float4*)xr;
    const float4 xb = *(const float4*)(xr + 4);
    union { bf16x8 v; short u[8]; } A;
    A.u[0] = f2bf(xa.x); A.u[1] = f2bf(xa.y); A.u[2] = f2bf(xa.z); A.u[3] = f2bf(xa.w);
    A.u[4] = f2bf(xb.x); A.u[5] = f2bf(xb.y); A.u[6] = f2bf(xb.z); A.u[7] = f2bf(xb.w);
#pragma unroll
    for (int t = 0; t < NT; ++t) {
      // B frag: B[k=c][n=o=t*16+col] = wB[(t*16+col)*C + cc*32 + quad*8 + j]
      const bf16x8 Bv = *(const bf16x8*)(wB + (size_t)(t * 16 + col) * C + cc * 32 + quad * 8);
      d[t] = __builtin_amdgcn_mfma_f32_16x16x32_bf16(A.v, Bv, d[t], 0, 0, 0);
    }
  }
  // Phase D: softmax over kk (regs + quads) and weighted sum
#pragma unroll
  for (int t = 0; t < NT; ++t) {
    float mx = fmaxf(fmaxf(d[t][0], d[t][1]), fmaxf(d[t][2], d[t][3]));
    mx = fmaxf(mx, __shfl_xor(mx, 16));
    mx = fmaxf(mx, __shfl_xor(mx, 32));
    float e0 = __expf(d[t][0] - mx), e1 = __expf(d[t][1] - mx);
    float e2 = __expf(d[t][2] - mx), e3 = __expf(d[t][3] - mx);
    float s = e0 + e1 + e2 + e3;
    s += __shfl_xor(s, 16);
    s += __shfl_xor(s, 32);
    const int o = t * 16 + col;
    float part = e0 * xcat[g][quad * 4 + 0][o] + e1 * xcat[g][quad * 4 + 1][o] +
                 e2 * xcat[g][quad * 4 + 2][o] + e3 * xcat[g][quad * 4 + 3][o];
    part += __shfl_xor(part, 16);
    part += __shfl_xor(part, 32);
    if (quad == 0) out[(size_t)pid * C + o] = part / s;
  }
}

// ---------------------------------------------------------------------------
// Final: out[b, o, n] = relu(affine(y3 | yr)); affines computed inline
// ---------------------------------------------------------------------------
__global__ __launch_bounds__(256) void final_kernel(const float* __restrict__ y3,
                                                    const float* __restrict__ yr,
                                                    const double* __restrict__ s3,
                                                    const float* __restrict__ g3, const float* __restrict__ t3,
                                                    const double* __restrict__ sr,
                                                    const float* __restrict__ gr, const float* __restrict__ tr,
                                                    float* __restrict__ out) {
  const int blk = blockIdx.x;
  const int b = blk >> 9;
  const int n0 = (blk & 511) << 4;
  const int c = threadIdx.x;
  const float* src;
  const double* sa;
  const float *gp, *tp;
  int cc;
  if (c < 128) { src = y3; sa = s3; gp = g3; tp = t3; cc = c; }
  else { src = yr; sa = sr; gp = gr; tp = tr; cc = c - 128; }
  const double cnt = (double)(B_ * N_);
  const double mean = sa[cc] / cnt;
  const double var = sa[128 + cc] / cnt - mean * mean;
  const double avd = (double)gp[cc] / sqrt(var + 1e-5);
  const float av = (float)avd;
  const float bv = (float)((double)tp[cc] - avd * mean);
  float v[16];
#pragma unroll
  for (int nl = 0; nl < 16; ++nl) {
    const float x = av * src[((size_t)(b * N_ + n0 + nl)) * 128 + cc] + bv;
    v[nl] = fmaxf(x, 0.0f);
  }
  float* op = out + ((size_t)(b * 256 + c)) * N_ + n0;
#pragma unroll
  for (int j = 0; j < 4; ++j)
    *((float4*)(op + 4 * j)) = make_float4(v[4 * j], v[4 * j + 1], v[4 * j + 2], v[4 * j + 3]);
}

// ---------------------------------------------------------------------------
extern "C" void kernel_launch(void* const* d_in, const int* in_sizes, int n_in,
                              void* d_out, int out_size, void* d_ws, size_t ws_size,
                              hipStream_t stream) {
  (void)in_sizes; (void)n_in; (void)out_size; (void)ws_size;
  const float* coords   = (const float*)d_in[0];
  const float* features = (const float*)d_in[1];
  const float* mlp1_w = (const float*)d_in[2];
  const float* mlp1_b = (const float*)d_in[3];
  const float* mlp1_g = (const float*)d_in[4];
  const float* mlp1_t = (const float*)d_in[5];
  const float* lse1_w = (const float*)d_in[6];
  const float* lse1_b = (const float*)d_in[7];
  const float* lse1_g = (const float*)d_in[8];
  const float* lse1_t = (const float*)d_in[9];
  const float* mlpp1_w = (const float*)d_in[10];
  const float* mlpp1_b = (const float*)d_in[11];
  const float* mlpp1_g = (const float*)d_in[12];
  const float* mlpp1_t = (const float*)d_in[13];
  const float* lse2_w = (const float*)d_in[14];
  const float* lse2_b = (const float*)d_in[15];
  const float* lse2_g = (const float*)d_in[16];
  const float* lse2_t = (const float*)d_in[17];
  const float* mlp2_w = (const float*)d_in[18];
  const float* mlp2_b = (const float*)d_in[19];
  const float* mlp2_g = (const float*)d_in[20];
  const float* mlp2_t = (const float*)d_in[21];
  const float* res_w = (const float*)d_in[22];
  const float* res_b = (const float*)d_in[23];
  const float* res_g = (const float*)d_in[24];
  const float* res_t = (const float*)d_in[25];
  const float* pool1_w = (const float*)d_in[26];
  const float* pool1_b = (const float*)d_in[27];
  const float* pool2_w = (const float*)d_in[28];
  const float* pool2_b = (const float*)d_in[29];

  float* wsf = (float*)d_ws;
  int* knn_i = (int*)d_ws;                 // 262144 ints
  float* knn_d = wsf + 262144;             // 262144
  float* y1 = wsf + 524288;                // (B,N,64)
  float* pooled1 = wsf + 1572864;          // (B,N,128)
  float* y2 = wsf + 3670016;               // (B,N,32)
  float* pooled2 = wsf + 4194304;          // (B,N,64)
  float* y3 = wsf + 5242880;               // (B,N,128)
  float* yr = wsf + 7340032;               // (B,N,128)
  double* dacc = (double*)(wsf + 9437184);
  double* mom = dacc;
  double* sacc_mlp1 = dacc + 65;
  double* sacc_mlpp1 = dacc + 193;
  double* sacc_mlp2 = dacc + 257;
  double* sacc_res = dacc + 513;           // ends at 769 doubles
  float* fpar = wsf + 9437184 + 1600;
  float* w1f = fpar;          // 640
  float* b1f = w1f + 640;     // 64
  float* w2f = b1f + 64;      // 320
  float* b2f = w2f + 320;     // 32
  short* wB1 = (short*)(b2f + 32);   // 16384 shorts = 8192 floats
  short* wB2 = wB1 + 16384;          // 4096 shorts

  hipMemsetAsync(dacc, 0, 769 * sizeof(double), stream);
  knn_kernel<<<dim3(N_ / 16, B_), 512, 0, stream>>>(coords, knn_i, knn_d);
  moments_kernel<<<128, 128, 0, stream>>>(coords, knn_i, knn_d, mom);
  gemm_stats_kernel<32, 64, false, false><<<128, 128, 0, stream>>>(features, mlp1_w, mlp1_b, y1, sacc_mlp1);
  setup_kernel<<<1, 256, 0, stream>>>(mom, lse1_w, lse1_b, lse1_g, lse1_t,
                                      lse2_w, lse2_b, lse2_g, lse2_t,
                                      w1f, b1f, w2f, b2f, pool1_w, pool2_w, wB1, wB2);
  pool_kernel<64, 64><<<B_ * N_ / 4, 256, 0, stream>>>(
      coords, knn_i, knn_d, w1f, b1f, y1, sacc_mlp1, mlp1_g, mlp1_t, 0.2f, wB1, pool1_b, pooled1);
  gemm_stats_kernel<128, 32, true, true><<<128, 128, 0, stream>>>(pooled1, mlpp1_w, mlpp1_b, y2, sacc_mlpp1);
  pool_kernel<32, 32><<<B_ * N_ / 4, 256, 0, stream>>>(
      coords, knn_i, knn_d, w2f, b2f, y2, sacc_mlpp1, mlpp1_g, mlpp1_t, 0.0f, wB2, pool2_b, pooled2);
  gemm_stats_kernel<64, 128, true, false><<<128, 128, 0, stream>>>(pooled2, mlp2_w, mlp2_b, y3, sacc_mlp2);
  gemm_stats_kernel<32, 128, false, false><<<128, 128, 0, stream>>>(features, res_w, res_b, yr, sacc_res);
  final_kernel<<<B_ * 512, 256, 0, stream>>>(y3, yr, sacc_mlp2, mlp2_g, mlp2_t,
                                             sacc_res, res_g, res_t, (float*)d_out);
}

// Round 5
// 463.997 us; speedup vs baseline: 1.6117x; 1.3112x over previous
//
#include <hip/hip_runtime.h>

static constexpr int N_ = 8192;
static constexpr int B_ = 2;
static constexpr int K_ = 16;

typedef __attribute__((ext_vector_type(8))) short bf16x8;
typedef __attribute__((ext_vector_type(4))) float f32x4;

__device__ __forceinline__ short f2bf(float f) {
  unsigned int u = __float_as_uint(f);
  unsigned int r = (u + 0x7FFFu + ((u >> 16) & 1u)) >> 16;
  return (short)r;
}
__device__ __forceinline__ float bf2f(short h) {
  return __uint_as_float(((unsigned int)(unsigned short)h) << 16);
}

// ---------------------------------------------------------------------------
// KNN: two queries/wave, shared candidate reads, interleaved drain chains.
// In-drain tau refresh restored (prunes stale ballot). Self-exclusion is a
// scalar mask edit. Only the neighbor SET matters downstream (attentive pool
// is permutation-invariant over k), but tie semantics still match top_k.
// ---------------------------------------------------------------------------
__global__ __launch_bounds__(512) void knn_kernel(const float* __restrict__ coords,
                                                  int* __restrict__ oidx,
                                                  float* __restrict__ odist) {
  __shared__ float4 pts[2048];
  const int b = blockIdx.y;
  const int wv = threadIdx.x >> 6;
  const int lane = threadIdx.x & 63;
  const int q0 = blockIdx.x * 16 + wv * 2;
  const int q1 = q0 + 1;
  const float* cb = coords + (size_t)b * N_ * 3;
  const float qx0 = cb[q0 * 3 + 0], qy0 = cb[q0 * 3 + 1], qz0 = cb[q0 * 3 + 2];
  const float qx1 = cb[q1 * 3 + 0], qy1 = cb[q1 * 3 + 1], qz1 = cb[q1 * 3 + 2];
  const float qsq0 = __fadd_rn(__fadd_rn(__fmul_rn(qx0, qx0), __fmul_rn(qy0, qy0)), __fmul_rn(qz0, qz0));
  const float qsq1 = __fadd_rn(__fadd_rn(__fmul_rn(qx1, qx1), __fmul_rn(qy1, qy1)), __fmul_rn(qz1, qz1));
  const int up_addr = (lane > 0 ? lane - 1 : 0) << 2;
  float kd0 = INFINITY, kd1 = INFINITY;
  int ki0 = 0, ki1 = 0;
  float tau0 = INFINITY, tau1 = INFINITY;
  for (int t0 = 0; t0 < N_; t0 += 2048) {
    __syncthreads();
    for (int i = threadIdx.x; i < 2048; i += 512) {
      const int p = t0 + i;
      const float x = cb[p * 3 + 0], y = cb[p * 3 + 1], z = cb[p * 3 + 2];
      const float sq = __fadd_rn(__fadd_rn(__fmul_rn(x, x), __fmul_rn(y, y)), __fmul_rn(z, z));
      pts[i] = make_float4(x, y, z, sq);
    }
    __syncthreads();
    for (int s = 0; s < 2048; s += 64) {
      const float4 p = pts[s + lane];
      float d20, d21;
      {
        const float dot = __fadd_rn(__fadd_rn(__fmul_rn(qx0, p.x), __fmul_rn(qy0, p.y)), __fmul_rn(qz0, p.z));
        d20 = __fsub_rn(__fadd_rn(qsq0, p.w), __fmul_rn(2.0f, dot));
      }
      {
        const float dot = __fadd_rn(__fadd_rn(__fmul_rn(qx1, p.x), __fmul_rn(qy1, p.y)), __fmul_rn(qz1, p.z));
        d21 = __fsub_rn(__fadd_rn(qsq1, p.w), __fmul_rn(2.0f, dot));
      }
      unsigned long long m0 = __ballot(d20 < tau0);
      unsigned long long m1 = __ballot(d21 < tau1);
      const int base = t0 + s;
      if (base == (q0 & ~63)) m0 &= ~(1ull << (q0 & 63));  // self-exclude (scalar)
      if (base == (q1 & ~63)) m1 &= ~(1ull << (q1 & 63));
      while (m0 | m1) {
        if (m0) {
          const int src = __builtin_ctzll(m0);  // ascending index -> tie stability
          const float dc = __uint_as_float(__builtin_amdgcn_readlane(__float_as_uint(d20), src));
          const int jc = base + src;
          const float sd = __uint_as_float(__builtin_amdgcn_ds_bpermute(up_addr, __float_as_uint(kd0)));
          const int si = __builtin_amdgcn_ds_bpermute(up_addr, ki0);
          const bool c1 = kd0 > dc;
          const bool c2 = (lane > 0) && (sd > dc);
          kd0 = c1 ? (c2 ? sd : dc) : kd0;
          ki0 = c1 ? (c2 ? si : jc) : ki0;
          m0 &= (m0 - 1);
          tau0 = __uint_as_float(__builtin_amdgcn_readlane(__float_as_uint(kd0), 15));
          m0 &= __ballot(d20 < tau0);
        }
        if (m1) {
          const int src = __builtin_ctzll(m1);
          const float dc = __uint_as_float(__builtin_amdgcn_readlane(__float_as_uint(d21), src));
          const int jc = base + src;
          const float sd = __uint_as_float(__builtin_amdgcn_ds_bpermute(up_addr, __float_as_uint(kd1)));
          const int si = __builtin_amdgcn_ds_bpermute(up_addr, ki1);
          const bool c1 = kd1 > dc;
          const bool c2 = (lane > 0) && (sd > dc);
          kd1 = c1 ? (c2 ? sd : dc) : kd1;
          ki1 = c1 ? (c2 ? si : jc) : ki1;
          m1 &= (m1 - 1);
          tau1 = __uint_as_float(__builtin_amdgcn_readlane(__float_as_uint(kd1), 15));
          m1 &= __ballot(d21 < tau1);
        }
      }
    }
  }
  if (lane < 16) {
    oidx[((size_t)b * N_ + q0) * K_ + lane] = ki0;
    odist[((size_t)b * N_ + q0) * K_ + lane] = fmaxf(kd0, 0.0f);
    oidx[((size_t)b * N_ + q1) * K_ + lane] = ki1;
    odist[((size_t)b * N_ + q1) * K_ + lane] = fmaxf(kd1, 0.0f);
  }
}

// ---------------------------------------------------------------------------
// Spatial feature moments: 256 blocks x 64 threads (one wave per block)
// ---------------------------------------------------------------------------
__global__ __launch_bounds__(64) void moments_kernel(const float* __restrict__ coords,
                                                     const int* __restrict__ knn_i,
                                                     const float* __restrict__ knn_d,
                                                     double* __restrict__ mom) {
  const int t = blockIdx.x * 64 + threadIdx.x;
  const int b = t >> 13, n = t & (N_ - 1);
  float acc[65];
#pragma unroll
  for (int e = 0; e < 65; ++e) acc[e] = 0.0f;
  const float* cb = coords + (size_t)b * N_ * 3;
  const float cx = cb[n * 3 + 0], cy = cb[n * 3 + 1], cz = cb[n * 3 + 2];
  for (int k = 0; k < K_; ++k) {
    const int id = knn_i[(size_t)t * K_ + k];
    const float dd = knn_d[(size_t)t * K_ + k];
    const float nx = cb[id * 3 + 0], ny = cb[id * 3 + 1], nz = cb[id * 3 + 2];
    const float s[10] = {cx, cy, cz, nx, ny, nz, cx - nx, cy - ny, cz - nz, dd};
    int e = 0;
#pragma unroll
    for (int i = 0; i < 10; ++i) acc[e++] += s[i];
#pragma unroll
    for (int i = 0; i < 10; ++i)
#pragma unroll
      for (int jj = i; jj < 10; ++jj) acc[e++] += s[i] * s[jj];
  }
#pragma unroll
  for (int e = 0; e < 65; ++e) {
    float v = acc[e];
#pragma unroll
    for (int off = 32; off > 0; off >>= 1) v += __shfl_xor(v, off);
    acc[e] = v;
  }
  __shared__ float buf[65];
  if (threadIdx.x == 0) {
#pragma unroll
    for (int e = 0; e < 65; ++e) buf[e] = acc[e];
  }
  __syncthreads();
  if (threadIdx.x < 64) atomicAdd(&mom[threadIdx.x], (double)buf[threadIdx.x]);
  if (threadIdx.x == 0) atomicAdd(&mom[64], (double)buf[64]);
}

// ---------------------------------------------------------------------------
// Setup: lse BN affines + pool weights -> bf16 + gemm weights -> hi/lo bf16
// fragments in MFMA B-operand order.
// ---------------------------------------------------------------------------
__device__ __forceinline__ void convert_frags(const float* __restrict__ w, short* __restrict__ H,
                                              short* __restrict__ L, int CI, int CO, int tid) {
  const int NT = CO / 16;
  for (int i = tid; i < CI * CO; i += 256) {
    const int j = i & 7, l = (i >> 3) & 63, tmp = i >> 9;
    const int tt = tmp % NT, cc = tmp / NT;
    const int c = cc * 32 + (l >> 4) * 8 + j;
    const int o = tt * 16 + (l & 15);
    const float v = w[o * CI + c];
    const short h = f2bf(v);
    H[i] = h;
    L[i] = f2bf(v - bf2f(h));
  }
}

__global__ void setup_kernel(const double* __restrict__ mom,
                             const float* __restrict__ w1, const float* __restrict__ b1,
                             const float* __restrict__ g1, const float* __restrict__ t1,
                             const float* __restrict__ w2, const float* __restrict__ b2,
                             const float* __restrict__ g2, const float* __restrict__ t2,
                             float* __restrict__ w1f, float* __restrict__ b1f,
                             float* __restrict__ w2f, float* __restrict__ b2f,
                             const float* __restrict__ pw1, const float* __restrict__ pw2,
                             short* __restrict__ wB1, short* __restrict__ wB2,
                             const float* __restrict__ wm1, short* __restrict__ f1H, short* __restrict__ f1L,
                             const float* __restrict__ wmp, short* __restrict__ f2H, short* __restrict__ f2L,
                             const float* __restrict__ wm2, short* __restrict__ f3H, short* __restrict__ f3L,
                             const float* __restrict__ wrs, short* __restrict__ fRH, short* __restrict__ fRL) {
  const int t = threadIdx.x;
  for (int i = t; i < 128 * 128; i += 256) wB1[i] = f2bf(pw1[i]);
  for (int i = t; i < 64 * 64; i += 256) wB2[i] = f2bf(pw2[i]);
  convert_frags(wm1, f1H, f1L, 32, 64, t);
  convert_frags(wmp, f2H, f2L, 128, 32, t);
  convert_frags(wm2, f3H, f3L, 64, 128, t);
  convert_frags(wrs, fRH, fRL, 32, 128, t);
  __shared__ double mu[10];
  __shared__ double S[10][10];
  const double cnt = (double)B_ * N_ * K_;
  if (t < 10) mu[t] = mom[t] / cnt;
  if (t < 55) {
    int e = t, i = 0;
    while (e >= 10 - i) { e -= 10 - i; ++i; }
    const int j = i + e;
    const double v = mom[10 + t] / cnt;
    S[i][j] = v;
    S[j][i] = v;
  }
  __syncthreads();
  const float *w, *bias, *gg, *bt;
  float *wf, *bf;
  int c;
  if (t < 64) { w = w1; bias = b1; gg = g1; bt = t1; wf = w1f; bf = b1f; c = t; }
  else if (t < 96) { w = w2; bias = b2; gg = g2; bt = t2; wf = w2f; bf = b2f; c = t - 64; }
  else return;
  double wd[10];
#pragma unroll
  for (int d = 0; d < 10; ++d) wd[d] = (double)w[c * 10 + d];
  const double cbv = (double)bias[c];
  double mz = cbv;
  for (int d = 0; d < 10; ++d) mz += wd[d] * mu[d];
  double e2 = cbv * cbv;
  for (int d = 0; d < 10; ++d) e2 += 2.0 * cbv * wd[d] * mu[d];
  for (int d = 0; d < 10; ++d)
    for (int e = 0; e < 10; ++e) e2 += wd[d] * wd[e] * S[d][e];
  const double var = e2 - mz * mz;
  const double a = (double)gg[c] / sqrt(var + 1e-5);
  const double shift = (double)bt[c] - a * mz;
#pragma unroll
  for (int d = 0; d < 10; ++d) wf[c * 10 + d] = (float)(a * wd[d]);
  bf[c] = (float)(a * cbv + shift);
}

// ---------------------------------------------------------------------------
// MFMA GEMM + fused BN stats. hi/lo bf16 split => ~fp32 accuracy.
// 16 points per wave (A rows), CO outputs via NT 16-col tiles.
// D layout: row(m=point)=quad*4+r, col(n=o)=lane&15.
// ---------------------------------------------------------------------------
template <int CI, int CO, bool ROWMAJ>
__global__ __launch_bounds__(256) void gemm_mfma_kernel(const float* __restrict__ in,
                                                        const short* __restrict__ fragH,
                                                        const short* __restrict__ fragL,
                                                        const float* __restrict__ bias,
                                                        float* __restrict__ out,
                                                        double* __restrict__ sacc) {
  constexpr int NT = CO / 16;
  constexpr int NC = CI / 32;
  __shared__ float part[4][CO][2];
  const int wv = threadIdx.x >> 6, l = threadIdx.x & 63;
  const int col = l & 15, quad = l >> 4;
  const int p0 = blockIdx.x * 64 + wv * 16;
  const int pt = p0 + col;
  f32x4 d[NT];
#pragma unroll
  for (int t = 0; t < NT; ++t) {
    const float bv = bias[t * 16 + col];
    d[t][0] = bv; d[t][1] = bv; d[t][2] = bv; d[t][3] = bv;
  }
#pragma unroll
  for (int cc = 0; cc < NC; ++cc) {
    float xv[8];
    if (ROWMAJ) {
      const float* ip = in + (size_t)pt * CI + cc * 32 + quad * 8;
      *(float4*)&xv[0] = *(const float4*)ip;
      *(float4*)&xv[4] = *(const float4*)(ip + 4);
    } else {
      const int b = pt >> 13, n = pt & (N_ - 1);
      const float* ip = in + ((size_t)b * CI + cc * 32 + quad * 8) * N_ + n;
#pragma unroll
      for (int j = 0; j < 8; ++j) xv[j] = ip[(size_t)j * N_];
    }
    union { bf16x8 v; short u[8]; } AH, AL;
#pragma unroll
    for (int j = 0; j < 8; ++j) {
      const short h = f2bf(xv[j]);
      AH.u[j] = h;
      AL.u[j] = f2bf(xv[j] - bf2f(h));
    }
#pragma unroll
    for (int t = 0; t < NT; ++t) {
      const size_t fo = ((size_t)(cc * NT + t) * 64 + l) * 8;
      const bf16x8 BH = *(const bf16x8*)(fragH + fo);
      const bf16x8 BL = *(const bf16x8*)(fragL + fo);
      d[t] = __builtin_amdgcn_mfma_f32_16x16x32_bf16(AH.v, BH, d[t], 0, 0, 0);
      d[t] = __builtin_amdgcn_mfma_f32_16x16x32_bf16(AH.v, BL, d[t], 0, 0, 0);
      d[t] = __builtin_amdgcn_mfma_f32_16x16x32_bf16(AL.v, BH, d[t], 0, 0, 0);
    }
  }
#pragma unroll
  for (int t = 0; t < NT; ++t) {
#pragma unroll
    for (int r = 0; r < 4; ++r)
      out[(size_t)(p0 + quad * 4 + r) * CO + t * 16 + col] = d[t][r];
    float s1 = d[t][0] + d[t][1] + d[t][2] + d[t][3];
    float s2 = d[t][0] * d[t][0] + d[t][1] * d[t][1] + d[t][2] * d[t][2] + d[t][3] * d[t][3];
    s1 += __shfl_xor(s1, 16); s1 += __shfl_xor(s1, 32);
    s2 += __shfl_xor(s2, 16); s2 += __shfl_xor(s2, 32);
    if (quad == 0) { part[wv][t * 16 + col][0] = s1; part[wv][t * 16 + col][1] = s2; }
  }
  __syncthreads();
  if (threadIdx.x < CO) {
    const int o = threadIdx.x;
    atomicAdd(&sacc[o], (double)(part[0][o][0] + part[1][o][0] + part[2][o][0] + part[3][o][0]));
    atomicAdd(&sacc[CO + o], (double)(part[0][o][1] + part[1][o][1] + part[2][o][1] + part[3][o][1]));
  }
}

// ---------------------------------------------------------------------------
// Fused LSE + attentive pool, MFMA scores (unchanged from R4 — proven).
// ---------------------------------------------------------------------------
template <int CSF, int CF>
__global__ __launch_bounds__(256) void pool_kernel(
    const float* __restrict__ coords, const int* __restrict__ knn_i, const float* __restrict__ knn_d,
    const float* __restrict__ wlse, const float* __restrict__ blse,
    const float* __restrict__ feat, const double* __restrict__ sfe,
    const float* __restrict__ gfe, const float* __restrict__ tfe,
    const float slope,
    const short* __restrict__ wB, const float* __restrict__ pb,
    float* __restrict__ out) {
  constexpr int C = CSF + CF;
  constexpr int CP = C + 4;
  constexpr int NT = C / 16;
  constexpr int NC = C / 32;
  __shared__ float xcat[4][16][CP];
  __shared__ float sp[4][10][16];
  const int g = threadIdx.x >> 6;
  const int l = threadIdx.x & 63;
  const int quad = l >> 4, col = l & 15;
  const int pid = blockIdx.x * 4 + g;
  const int b = pid >> 13, n = pid & (N_ - 1);
  const float* cb = coords + (size_t)b * N_ * 3;

  if (l < 16) {
    const int id = knn_i[(size_t)pid * K_ + l];
    const float dd = knn_d[(size_t)pid * K_ + l];
    const float cx = cb[n * 3 + 0], cy = cb[n * 3 + 1], cz = cb[n * 3 + 2];
    const float nx = cb[id * 3 + 0], ny = cb[id * 3 + 1], nz = cb[id * 3 + 2];
    sp[g][0][l] = cx; sp[g][1][l] = cy; sp[g][2][l] = cz;
    sp[g][3][l] = nx; sp[g][4][l] = ny; sp[g][5][l] = nz;
    sp[g][6][l] = cx - nx; sp[g][7][l] = cy - ny; sp[g][8][l] = cz - nz;
    sp[g][9][l] = dd;
  }
  if (l < CF) {
    const double cnt = (double)(B_ * N_);
    const double mean = sfe[l] / cnt;
    const double var = sfe[CF + l] / cnt - mean * mean;
    const double av = (double)gfe[l] / sqrt(var + 1e-5);
    const float af = (float)av;
    const float bfv = (float)((double)tfe[l] - av * mean);
    float v = feat[(size_t)pid * CF + l];
    v = af * v + bfv;
    v = (v >= 0.0f) ? v : slope * v;
#pragma unroll
    for (int j = 0; j < 16; ++j) xcat[g][j][CSF + l] = v;
  }
  __syncthreads();
  if (l < CSF) {
    float z[16];
    const float bz = blse[l];
#pragma unroll
    for (int j = 0; j < 16; ++j) z[j] = bz;
#pragma unroll
    for (int d = 0; d < 10; ++d) {
      const float wv = wlse[l * 10 + d];
      const float4* sr = (const float4*)&sp[g][d][0];
      const float4 s0 = sr[0], s1 = sr[1], s2 = sr[2], s3 = sr[3];
      z[0] += wv * s0.x; z[1] += wv * s0.y; z[2] += wv * s0.z; z[3] += wv * s0.w;
      z[4] += wv * s1.x; z[5] += wv * s1.y; z[6] += wv * s1.z; z[7] += wv * s1.w;
      z[8] += wv * s2.x; z[9] += wv * s2.y; z[10] += wv * s2.z; z[11] += wv * s2.w;
      z[12] += wv * s3.x; z[13] += wv * s3.y; z[14] += wv * s3.z; z[15] += wv * s3.w;
    }
#pragma unroll
    for (int j = 0; j < 16; ++j) xcat[g][j][l] = fmaxf(z[j], 0.0f);
  }
  __syncthreads();
  f32x4 d[NT];
#pragma unroll
  for (int t = 0; t < NT; ++t) {
    const float pbv = pb[t * 16 + col];
    d[t][0] = pbv; d[t][1] = pbv; d[t][2] = pbv; d[t][3] = pbv;
  }
#pragma unroll
  for (int cc = 0; cc < NC; ++cc) {
    const float* xr = &xcat[g][col][cc * 32 + quad * 8];
    const float4 xa = *(const float4*)xr;
    const float4 xb = *(const float4*)(xr + 4);
    union { bf16x8 v; short u[8]; } A;
    A.u[0] = f2bf(xa.x); A.u[1] = f2bf(xa.y); A.u[2] = f2bf(xa.z); A.u[3] = f2bf(xa.w);
    A.u[4] = f2bf(xb.x); A.u[5] = f2bf(xb.y); A.u[6] = f2bf(xb.z); A.u[7] = f2bf(xb.w);
#pragma unroll
    for (int t = 0; t < NT; ++t) {
      const bf16x8 Bv = *(const bf16x8*)(wB + (size_t)(t * 16 + col) * C + cc * 32 + quad * 8);
      d[t] = __builtin_amdgcn_mfma_f32_16x16x32_bf16(A.v, Bv, d[t], 0, 0, 0);
    }
  }
#pragma unroll
  for (int t = 0; t < NT; ++t) {
    float mx = fmaxf(fmaxf(d[t][0], d[t][1]), fmaxf(d[t][2], d[t][3]));
    mx = fmaxf(mx, __shfl_xor(mx, 16));
    mx = fmaxf(mx, __shfl_xor(mx, 32));
    float e0 = __expf(d[t][0] - mx), e1 = __expf(d[t][1] - mx);
    float e2 = __expf(d[t][2] - mx), e3 = __expf(d[t][3] - mx);
    float s = e0 + e1 + e2 + e3;
    s += __shfl_xor(s, 16);
    s += __shfl_xor(s, 32);
    const int o = t * 16 + col;
    float part = e0 * xcat[g][quad * 4 + 0][o] + e1 * xcat[g][quad * 4 + 1][o] +
                 e2 * xcat[g][quad * 4 + 2][o] + e3 * xcat[g][quad * 4 + 3][o];
    part += __shfl_xor(part, 16);
    part += __shfl_xor(part, 32);
    if (quad == 0) out[(size_t)pid * C + o] = part / s;
  }
}

// ---------------------------------------------------------------------------
// Final: relu(affine(y3|yr)) with LDS transpose for coalesced writes
// ---------------------------------------------------------------------------
__global__ __launch_bounds__(256) void final_kernel(const float* __restrict__ y3,
                                                    const float* __restrict__ yr,
                                                    const double* __restrict__ s3,
                                                    const float* __restrict__ g3, const float* __restrict__ t3,
                                                    const double* __restrict__ sr,
                                                    const float* __restrict__ gr, const float* __restrict__ tr,
                                                    float* __restrict__ out) {
  __shared__ float tile[256 * 17];
  const int blk = blockIdx.x;
  const int b = blk >> 9;
  const int n0 = (blk & 511) << 4;
  const int c = threadIdx.x;
  const float* src;
  const double* sa;
  const float *gp, *tp;
  int cc;
  if (c < 128) { src = y3; sa = s3; gp = g3; tp = t3; cc = c; }
  else { src = yr; sa = sr; gp = gr; tp = tr; cc = c - 128; }
  const double cnt = (double)(B_ * N_);
  const double mean = sa[cc] / cnt;
  const double var = sa[128 + cc] / cnt - mean * mean;
  const double avd = (double)gp[cc] / sqrt(var + 1e-5);
  const float av = (float)avd;
  const float bv = (float)((double)tp[cc] - avd * mean);
#pragma unroll
  for (int nl = 0; nl < 16; ++nl) {
    const float x = av * src[((size_t)(b * N_ + n0 + nl)) * 128 + cc] + bv;
    tile[c * 17 + nl] = fmaxf(x, 0.0f);
  }
  __syncthreads();
  const int np = c & 15, grp = c >> 4;
#pragma unroll
  for (int j = 0; j < 16; ++j) {
    const int c2 = grp * 16 + j;
    out[((size_t)(b * 256 + c2)) * N_ + n0 + np] = tile[c2 * 17 + np];
  }
}

// ---------------------------------------------------------------------------
extern "C" void kernel_launch(void* const* d_in, const int* in_sizes, int n_in,
                              void* d_out, int out_size, void* d_ws, size_t ws_size,
                              hipStream_t stream) {
  (void)in_sizes; (void)n_in; (void)out_size; (void)ws_size;
  const float* coords   = (const float*)d_in[0];
  const float* features = (const float*)d_in[1];
  const float* mlp1_w = (const float*)d_in[2];
  const float* mlp1_b = (const float*)d_in[3];
  const float* mlp1_g = (const float*)d_in[4];
  const float* mlp1_t = (const float*)d_in[5];
  const float* lse1_w = (const float*)d_in[6];
  const float* lse1_b = (const float*)d_in[7];
  const float* lse1_g = (const float*)d_in[8];
  const float* lse1_t = (const float*)d_in[9];
  const float* mlpp1_w = (const float*)d_in[10];
  const float* mlpp1_b = (const float*)d_in[11];
  const float* mlpp1_g = (const float*)d_in[12];
  const float* mlpp1_t = (const float*)d_in[13];
  const float* lse2_w = (const float*)d_in[14];
  const float* lse2_b = (const float*)d_in[15];
  const float* lse2_g = (const float*)d_in[16];
  const float* lse2_t = (const float*)d_in[17];
  const float* mlp2_w = (const float*)d_in[18];
  const float* mlp2_b = (const float*)d_in[19];
  const float* mlp2_g = (const float*)d_in[20];
  const float* mlp2_t = (const float*)d_in[21];
  const float* res_w = (const float*)d_in[22];
  const float* res_b = (const float*)d_in[23];
  const float* res_g = (const float*)d_in[24];
  const float* res_t = (const float*)d_in[25];
  const float* pool1_w = (const float*)d_in[26];
  const float* pool1_b = (const float*)d_in[27];
  const float* pool2_w = (const float*)d_in[28];
  const float* pool2_b = (const float*)d_in[29];

  float* wsf = (float*)d_ws;
  int* knn_i = (int*)d_ws;                 // 262144 ints
  float* knn_d = wsf + 262144;             // 262144
  float* y1 = wsf + 524288;                // (B,N,64)
  float* pooled1 = wsf + 1572864;          // (B,N,128)
  float* y2 = wsf + 3670016;               // (B,N,32)
  float* pooled2 = wsf + 4194304;          // (B,N,64)
  float* y3 = wsf + 5242880;               // (B,N,128)
  float* yr = wsf + 7340032;               // (B,N,128)
  double* dacc = (double*)(wsf + 9437184);
  double* mom = dacc;                      // 65
  double* sacc_mlp1 = dacc + 65;           // 128
  double* sacc_mlpp1 = dacc + 193;         // 64
  double* sacc_mlp2 = dacc + 257;          // 256
  double* sacc_res = dacc + 513;           // 256 -> ends 769
  float* fpar = wsf + 9437184 + 1600;
  float* w1f = fpar;                 // 640
  float* b1f = w1f + 640;            // 64
  float* w2f = b1f + 64;             // 320
  float* b2f = w2f + 320;            // 32
  short* wB1 = (short*)(b2f + 32);   // 16384 shorts (8192 floats)
  short* wB2 = wB1 + 16384;          // 4096 shorts (2048 floats)
  short* f1H = wB2 + 4096;           // 2048
  short* f1L = f1H + 2048;           // 2048
  short* f2H = f1L + 2048;           // 4096
  short* f2L = f2H + 4096;           // 4096
  short* f3H = f2L + 4096;           // 8192
  short* f3L = f3H + 8192;           // 8192
  short* fRH = f3L + 8192;           // 4096
  short* fRL = fRH + 4096;           // 4096

  hipMemsetAsync(dacc, 0, 769 * sizeof(double), stream);
  knn_kernel<<<dim3(N_ / 16, B_), 512, 0, stream>>>(coords, knn_i, knn_d);
  moments_kernel<<<256, 64, 0, stream>>>(coords, knn_i, knn_d, mom);
  setup_kernel<<<1, 256, 0, stream>>>(mom, lse1_w, lse1_b, lse1_g, lse1_t,
                                      lse2_w, lse2_b, lse2_g, lse2_t,
                                      w1f, b1f, w2f, b2f, pool1_w, pool2_w, wB1, wB2,
                                      mlp1_w, f1H, f1L, mlpp1_w, f2H, f2L,
                                      mlp2_w, f3H, f3L, res_w, fRH, fRL);
  gemm_mfma_kernel<32, 64, false><<<256, 256, 0, stream>>>(features, f1H, f1L, mlp1_b, y1, sacc_mlp1);
  pool_kernel<64, 64><<<B_ * N_ / 4, 256, 0, stream>>>(
      coords, knn_i, knn_d, w1f, b1f, y1, sacc_mlp1, mlp1_g, mlp1_t, 0.2f, wB1, pool1_b, pooled1);
  gemm_mfma_kernel<128, 32, true><<<256, 256, 0, stream>>>(pooled1, f2H, f2L, mlpp1_b, y2, sacc_mlpp1);
  pool_kernel<32, 32><<<B_ * N_ / 4, 256, 0, stream>>>(
      coords, knn_i, knn_d, w2f, b2f, y2, sacc_mlpp1, mlpp1_g, mlpp1_t, 0.0f, wB2, pool2_b, pooled2);
  gemm_mfma_kernel<64, 128, true><<<256, 256, 0, stream>>>(pooled2, f3H, f3L, mlp2_b, y3, sacc_mlp2);
  gemm_mfma_kernel<32, 128, false><<<256, 256, 0, stream>>>(features, fRH, fRL, res_b, yr, sacc_res);
  final_kernel<<<B_ * 512, 256, 0, stream>>>(y3, yr, sacc_mlp2, mlp2_g, mlp2_t,
                                             sacc_res, res_g, res_t, (float*)d_out);
}

// Round 6
// 434.942 us; speedup vs baseline: 1.7193x; 1.0668x over previous
//
#include <hip/hip_runtime.h>

static constexpr int N_ = 8192;
static constexpr int B_ = 2;
static constexpr int K_ = 16;

typedef __attribute__((ext_vector_type(8))) short bf16x8;
typedef __attribute__((ext_vector_type(4))) float f32x4;

__device__ __forceinline__ short f2bf(float f) {
  unsigned int u = __float_as_uint(f);
  unsigned int r = (u + 0x7FFFu + ((u >> 16) & 1u)) >> 16;
  return (short)r;
}
__device__ __forceinline__ float bf2f(short h) {
  return __uint_as_float(((unsigned int)(unsigned short)h) << 16);
}
// DPP row_shr:1 — lane i <- lane i-1 within 16-lane rows (list lives in lanes 0..15)
__device__ __forceinline__ float dpp_shr1_f(float x) {
  return __uint_as_float((unsigned int)__builtin_amdgcn_update_dpp(
      0, (int)__float_as_uint(x), 0x111, 0xF, 0xF, true));
}
__device__ __forceinline__ int dpp_shr1_i(int x) {
  return __builtin_amdgcn_update_dpp(0, x, 0x111, 0xF, 0xF, true);
}
__device__ __forceinline__ float rdlane_f(float x, int l) {
  return __uint_as_float(__builtin_amdgcn_readlane(__float_as_uint(x), l));
}

// ---------------------------------------------------------------------------
// KNN: two queries/wave share each candidate ds_read_b128; separate drain
// loops per query (R3 semantics: tau refresh inside drain). Shift-up via DPP
// (pure VALU, no LDS crossbar).
// ---------------------------------------------------------------------------
__global__ __launch_bounds__(512) void knn_kernel(const float* __restrict__ coords,
                                                  int* __restrict__ oidx,
                                                  float* __restrict__ odist) {
  __shared__ float4 pts[2048];
  const int b = blockIdx.y;
  const int wv = threadIdx.x >> 6;
  const int lane = threadIdx.x & 63;
  const bool lpos = (lane != 0);
  const int q0 = blockIdx.x * 16 + wv * 2;
  const int q1 = q0 + 1;
  const float* cb = coords + (size_t)b * N_ * 3;
  const float qx0 = cb[q0 * 3 + 0], qy0 = cb[q0 * 3 + 1], qz0 = cb[q0 * 3 + 2];
  const float qx1 = cb[q1 * 3 + 0], qy1 = cb[q1 * 3 + 1], qz1 = cb[q1 * 3 + 2];
  const float qsq0 = __fadd_rn(__fadd_rn(__fmul_rn(qx0, qx0), __fmul_rn(qy0, qy0)), __fmul_rn(qz0, qz0));
  const float qsq1 = __fadd_rn(__fadd_rn(__fmul_rn(qx1, qx1), __fmul_rn(qy1, qy1)), __fmul_rn(qz1, qz1));
  float kd0 = INFINITY, kd1 = INFINITY;
  int ki0 = 0, ki1 = 0;
  float tau0 = INFINITY, tau1 = INFINITY;
  for (int t0 = 0; t0 < N_; t0 += 2048) {
    __syncthreads();
    for (int i = threadIdx.x; i < 2048; i += 512) {
      const int p = t0 + i;
      const float x = cb[p * 3 + 0], y = cb[p * 3 + 1], z = cb[p * 3 + 2];
      const float sq = __fadd_rn(__fadd_rn(__fmul_rn(x, x), __fmul_rn(y, y)), __fmul_rn(z, z));
      pts[i] = make_float4(x, y, z, sq);
    }
    __syncthreads();
    for (int s = 0; s < 2048; s += 64) {
      const float4 p = pts[s + lane];
      const int base = t0 + s;
      float d20, d21;
      {
        const float dot = __fadd_rn(__fadd_rn(__fmul_rn(qx0, p.x), __fmul_rn(qy0, p.y)), __fmul_rn(qz0, p.z));
        d20 = __fsub_rn(__fadd_rn(qsq0, p.w), __fmul_rn(2.0f, dot));
      }
      {
        const float dot = __fadd_rn(__fadd_rn(__fmul_rn(qx1, p.x), __fmul_rn(qy1, p.y)), __fmul_rn(qz1, p.z));
        d21 = __fsub_rn(__fadd_rn(qsq1, p.w), __fmul_rn(2.0f, dot));
      }
      unsigned long long m0 = __ballot(d20 < tau0);
      unsigned long long m1 = __ballot(d21 < tau1);
      if (base == (q0 & ~63)) m0 &= ~(1ull << (q0 & 63));  // self-exclude (scalar)
      if (base == (q1 & ~63)) m1 &= ~(1ull << (q1 & 63));
      while (m0) {
        const int src = __builtin_ctzll(m0);  // ascending index -> tie stability
        const float dc = rdlane_f(d20, src);
        const int jc = base + src;
        const float sd = dpp_shr1_f(kd0);
        const int si = dpp_shr1_i(ki0);
        const bool c1 = kd0 > dc;             // strict: equals keep earlier entries
        const bool c2 = lpos && (sd > dc);
        kd0 = c1 ? (c2 ? sd : dc) : kd0;
        ki0 = c1 ? (c2 ? si : jc) : ki0;
        m0 &= (m0 - 1);
        tau0 = rdlane_f(kd0, 15);
        m0 &= __ballot(d20 < tau0);
      }
      while (m1) {
        const int src = __builtin_ctzll(m1);
        const float dc = rdlane_f(d21, src);
        const int jc = base + src;
        const float sd = dpp_shr1_f(kd1);
        const int si = dpp_shr1_i(ki1);
        const bool c1 = kd1 > dc;
        const bool c2 = lpos && (sd > dc);
        kd1 = c1 ? (c2 ? sd : dc) : kd1;
        ki1 = c1 ? (c2 ? si : jc) : ki1;
        m1 &= (m1 - 1);
        tau1 = rdlane_f(kd1, 15);
        m1 &= __ballot(d21 < tau1);
      }
    }
  }
  if (lane < 16) {
    oidx[((size_t)b * N_ + q0) * K_ + lane] = ki0;
    odist[((size_t)b * N_ + q0) * K_ + lane] = fmaxf(kd0, 0.0f);
    oidx[((size_t)b * N_ + q1) * K_ + lane] = ki1;
    odist[((size_t)b * N_ + q1) * K_ + lane] = fmaxf(kd1, 0.0f);
  }
}

// ---------------------------------------------------------------------------
// Spatial moments, decomposed: per (point,k) only 14 accumulators
// (Sn[3], Snn[6], Sd, Sdd, Snd[3]); the 65 moments reconstructed per point.
// ---------------------------------------------------------------------------
__device__ __forceinline__ float snn_get(const float* SNN, int a, int b) {
  const int i = a < b ? a : b, j = a < b ? b : a;
  return SNN[i == 0 ? j : (i == 1 ? 2 + j : 3 + j)];
}
__device__ __forceinline__ float mom_mean(int i, const float* C, const float* SN, float Sd) {
  if (i < 3) return 16.0f * C[i];
  if (i < 6) return SN[i - 3];
  if (i < 9) return 16.0f * C[i - 6] - SN[i - 6];
  return Sd;
}
__device__ __forceinline__ float mom_prod(int i, int j, const float* C, const float* SN,
                                          const float* SNN, float Sd, float Sdd, const float* SND) {
  const int ti = i < 3 ? 0 : (i < 6 ? 1 : (i < 9 ? 2 : 3));
  const int tj = j < 3 ? 0 : (j < 6 ? 1 : (j < 9 ? 2 : 3));
  const int a = (ti == 3) ? 0 : (i - ti * 3);
  const int bb = (tj == 3) ? 0 : (j - tj * 3);
  if (ti == 0 && tj == 0) return 16.0f * C[a] * C[bb];
  if (ti == 0 && tj == 1) return C[a] * SN[bb];
  if (ti == 0 && tj == 2) return C[a] * (16.0f * C[bb] - SN[bb]);
  if (ti == 0 && tj == 3) return C[a] * Sd;
  if (ti == 1 && tj == 1) return snn_get(SNN, a, bb);
  if (ti == 1 && tj == 2) return C[bb] * SN[a] - snn_get(SNN, a, bb);
  if (ti == 1 && tj == 3) return SND[a];
  if (ti == 2 && tj == 2) return 16.0f * C[a] * C[bb] - C[a] * SN[bb] - C[bb] * SN[a] + snn_get(SNN, a, bb);
  if (ti == 2 && tj == 3) return C[a] * Sd - SND[a];
  return Sdd;
}

__global__ __launch_bounds__(64) void moments_kernel(const float* __restrict__ coords,
                                                     const int* __restrict__ knn_i,
                                                     const float* __restrict__ knn_d,
                                                     double* __restrict__ mom) {
  const int t = blockIdx.x * 64 + threadIdx.x;
  const int b = t >> 13, n = t & (N_ - 1);
  const float* cb = coords + (size_t)b * N_ * 3;
  float C[3] = {cb[n * 3 + 0], cb[n * 3 + 1], cb[n * 3 + 2]};
  float SN[3] = {0.f, 0.f, 0.f}, SNN[6] = {0.f, 0.f, 0.f, 0.f, 0.f, 0.f};
  float SND[3] = {0.f, 0.f, 0.f}, Sd = 0.f, Sdd = 0.f;
  for (int k = 0; k < K_; ++k) {
    const int id = knn_i[(size_t)t * K_ + k];
    const float dd = knn_d[(size_t)t * K_ + k];
    const float nx = cb[id * 3 + 0], ny = cb[id * 3 + 1], nz = cb[id * 3 + 2];
    SN[0] += nx; SN[1] += ny; SN[2] += nz;
    SNN[0] += nx * nx; SNN[1] += nx * ny; SNN[2] += nx * nz;
    SNN[3] += ny * ny; SNN[4] += ny * nz; SNN[5] += nz * nz;
    Sd += dd; Sdd += dd * dd;
    SND[0] += nx * dd; SND[1] += ny * dd; SND[2] += nz * dd;
  }
  float m65[65];
  int e = 0;
#pragma unroll
  for (int i = 0; i < 10; ++i) m65[e++] = mom_mean(i, C, SN, Sd);
#pragma unroll
  for (int i = 0; i < 10; ++i)
#pragma unroll
    for (int j = i; j < 10; ++j) m65[e++] = mom_prod(i, j, C, SN, SNN, Sd, Sdd, SND);
#pragma unroll
  for (int q = 0; q < 65; ++q) {
    float v = m65[q];
#pragma unroll
    for (int off = 32; off > 0; off >>= 1) v += __shfl_xor(v, off);
    m65[q] = v;
  }
  __shared__ float buf[65];
  if (threadIdx.x == 0) {
#pragma unroll
    for (int q = 0; q < 65; ++q) buf[q] = m65[q];
  }
  __syncthreads();
  if (threadIdx.x < 64) atomicAdd(&mom[threadIdx.x], (double)buf[threadIdx.x]);
  if (threadIdx.x == 0) atomicAdd(&mom[64], (double)buf[64]);
}

// ---------------------------------------------------------------------------
// Parallel weight conversion: pool weights -> bf16 [o][c]; gemm weights ->
// hi/lo bf16 fragments in MFMA B-operand order. Segmented by blockIdx.
// ---------------------------------------------------------------------------
template <int CI, int CO>
__device__ __forceinline__ void conv_frag_seg(const float* __restrict__ w, short* __restrict__ H,
                                              short* __restrict__ L, int tid, int nthr) {
  constexpr int NT = CO / 16;
  for (int i = tid; i < CI * CO; i += nthr) {
    const int j = i & 7, l = (i >> 3) & 63, tmp = i >> 9;
    const int tt = tmp % NT, cc = tmp / NT;
    const int c = cc * 32 + (l >> 4) * 8 + j;
    const int o = tt * 16 + (l & 15);
    const float v = w[o * CI + c];
    const short h = f2bf(v);
    H[i] = h;
    L[i] = f2bf(v - bf2f(h));
  }
}

__global__ __launch_bounds__(256) void convert_kernel(
    const float* __restrict__ pw1, const float* __restrict__ pw2,
    short* __restrict__ wB1, short* __restrict__ wB2,
    const float* __restrict__ wm1, short* __restrict__ f1H, short* __restrict__ f1L,
    const float* __restrict__ wmp, short* __restrict__ f2H, short* __restrict__ f2L,
    const float* __restrict__ wm2, short* __restrict__ f3H, short* __restrict__ f3L,
    const float* __restrict__ wrs, short* __restrict__ fRH, short* __restrict__ fRL) {
  const int blk = blockIdx.x;
  if (blk < 8) {
    const int tid = blk * 256 + threadIdx.x;
    for (int i = tid; i < 128 * 128; i += 2048) wB1[i] = f2bf(pw1[i]);
  } else if (blk < 10) {
    const int tid = (blk - 8) * 256 + threadIdx.x;
    for (int i = tid; i < 64 * 64; i += 512) wB2[i] = f2bf(pw2[i]);
  } else if (blk < 12) {
    conv_frag_seg<32, 64>(wm1, f1H, f1L, (blk - 10) * 256 + threadIdx.x, 512);
  } else if (blk < 16) {
    conv_frag_seg<128, 32>(wmp, f2H, f2L, (blk - 12) * 256 + threadIdx.x, 1024);
  } else if (blk < 24) {
    conv_frag_seg<64, 128>(wm2, f3H, f3L, (blk - 16) * 256 + threadIdx.x, 2048);
  } else {
    conv_frag_seg<32, 128>(wrs, fRH, fRL, (blk - 24) * 256 + threadIdx.x, 1024);
  }
}

// ---------------------------------------------------------------------------
// Setup: lse BN affines from moments (fold BN into lse weights)
// ---------------------------------------------------------------------------
__global__ void setup_kernel(const double* __restrict__ mom,
                             const float* __restrict__ w1, const float* __restrict__ b1,
                             const float* __restrict__ g1, const float* __restrict__ t1,
                             const float* __restrict__ w2, const float* __restrict__ b2,
                             const float* __restrict__ g2, const float* __restrict__ t2,
                             float* __restrict__ w1f, float* __restrict__ b1f,
                             float* __restrict__ w2f, float* __restrict__ b2f) {
  const int t = threadIdx.x;
  __shared__ double mu[10];
  __shared__ double S[10][10];
  const double cnt = (double)B_ * N_ * K_;
  if (t < 10) mu[t] = mom[t] / cnt;
  if (t < 55) {
    int e = t, i = 0;
    while (e >= 10 - i) { e -= 10 - i; ++i; }
    const int j = i + e;
    const double v = mom[10 + t] / cnt;
    S[i][j] = v;
    S[j][i] = v;
  }
  __syncthreads();
  const float *w, *bias, *gg, *bt;
  float *wf, *bf;
  int c;
  if (t < 64) { w = w1; bias = b1; gg = g1; bt = t1; wf = w1f; bf = b1f; c = t; }
  else if (t < 96) { w = w2; bias = b2; gg = g2; bt = t2; wf = w2f; bf = b2f; c = t - 64; }
  else return;
  double wd[10];
#pragma unroll
  for (int d = 0; d < 10; ++d) wd[d] = (double)w[c * 10 + d];
  const double cbv = (double)bias[c];
  double mz = cbv;
  for (int d = 0; d < 10; ++d) mz += wd[d] * mu[d];
  double e2 = cbv * cbv;
  for (int d = 0; d < 10; ++d) e2 += 2.0 * cbv * wd[d] * mu[d];
  for (int d = 0; d < 10; ++d)
    for (int e = 0; e < 10; ++e) e2 += wd[d] * wd[e] * S[d][e];
  const double var = e2 - mz * mz;
  const double a = (double)gg[c] / sqrt(var + 1e-5);
  const double shift = (double)bt[c] - a * mz;
#pragma unroll
  for (int d = 0; d < 10; ++d) wf[c * 10 + d] = (float)(a * wd[d]);
  bf[c] = (float)(a * cbv + shift);
}

// ---------------------------------------------------------------------------
// MFMA GEMM + fused BN stats (hi/lo bf16 split => ~fp32 accuracy)
// ---------------------------------------------------------------------------
template <int CI, int CO, bool ROWMAJ>
__global__ __launch_bounds__(256) void gemm_mfma_kernel(const float* __restrict__ in,
                                                        const short* __restrict__ fragH,
                                                        const short* __restrict__ fragL,
                                                        const float* __restrict__ bias,
                                                        float* __restrict__ out,
                                                        double* __restrict__ sacc) {
  constexpr int NT = CO / 16;
  constexpr int NC = CI / 32;
  __shared__ float part[4][CO][2];
  const int wv = threadIdx.x >> 6, l = threadIdx.x & 63;
  const int col = l & 15, quad = l >> 4;
  const int p0 = blockIdx.x * 64 + wv * 16;
  const int pt = p0 + col;
  f32x4 d[NT];
#pragma unroll
  for (int t = 0; t < NT; ++t) {
    const float bv = bias[t * 16 + col];
    d[t][0] = bv; d[t][1] = bv; d[t][2] = bv; d[t][3] = bv;
  }
#pragma unroll
  for (int cc = 0; cc < NC; ++cc) {
    float xv[8];
    if (ROWMAJ) {
      const float* ip = in + (size_t)pt * CI + cc * 32 + quad * 8;
      *(float4*)&xv[0] = *(const float4*)ip;
      *(float4*)&xv[4] = *(const float4*)(ip + 4);
    } else {
      const int b = pt >> 13, n = pt & (N_ - 1);
      const float* ip = in + ((size_t)b * CI + cc * 32 + quad * 8) * N_ + n;
#pragma unroll
      for (int j = 0; j < 8; ++j) xv[j] = ip[(size_t)j * N_];
    }
    union { bf16x8 v; short u[8]; } AH, AL;
#pragma unroll
    for (int j = 0; j < 8; ++j) {
      const short h = f2bf(xv[j]);
      AH.u[j] = h;
      AL.u[j] = f2bf(xv[j] - bf2f(h));
    }
#pragma unroll
    for (int t = 0; t < NT; ++t) {
      const size_t fo = ((size_t)(cc * NT + t) * 64 + l) * 8;
      const bf16x8 BH = *(const bf16x8*)(fragH + fo);
      const bf16x8 BL = *(const bf16x8*)(fragL + fo);
      d[t] = __builtin_amdgcn_mfma_f32_16x16x32_bf16(AH.v, BH, d[t], 0, 0, 0);
      d[t] = __builtin_amdgcn_mfma_f32_16x16x32_bf16(AH.v, BL, d[t], 0, 0, 0);
      d[t] = __builtin_amdgcn_mfma_f32_16x16x32_bf16(AL.v, BH, d[t], 0, 0, 0);
    }
  }
#pragma unroll
  for (int t = 0; t < NT; ++t) {
#pragma unroll
    for (int r = 0; r < 4; ++r)
      out[(size_t)(p0 + quad * 4 + r) * CO + t * 16 + col] = d[t][r];
    float s1 = d[t][0] + d[t][1] + d[t][2] + d[t][3];
    float s2 = d[t][0] * d[t][0] + d[t][1] * d[t][1] + d[t][2] * d[t][2] + d[t][3] * d[t][3];
    s1 += __shfl_xor(s1, 16); s1 += __shfl_xor(s1, 32);
    s2 += __shfl_xor(s2, 16); s2 += __shfl_xor(s2, 32);
    if (quad == 0) { part[wv][t * 16 + col][0] = s1; part[wv][t * 16 + col][1] = s2; }
  }
  __syncthreads();
  if (threadIdx.x < CO) {
    const int o = threadIdx.x;
    atomicAdd(&sacc[o], (double)(part[0][o][0] + part[1][o][0] + part[2][o][0] + part[3][o][0]));
    atomicAdd(&sacc[CO + o], (double)(part[0][o][1] + part[1][o][1] + part[2][o][1] + part[3][o][1]));
  }
}

// ---------------------------------------------------------------------------
// Fused LSE + attentive pool, MFMA scores (proven R4 version)
// ---------------------------------------------------------------------------
template <int CSF, int CF>
__global__ __launch_bounds__(256) void pool_kernel(
    const float* __restrict__ coords, const int* __restrict__ knn_i, const float* __restrict__ knn_d,
    const float* __restrict__ wlse, const float* __restrict__ blse,
    const float* __restrict__ feat, const double* __restrict__ sfe,
    const float* __restrict__ gfe, const float* __restrict__ tfe,
    const float slope,
    const short* __restrict__ wB, const float* __restrict__ pb,
    float* __restrict__ out) {
  constexpr int C = CSF + CF;
  constexpr int CP = C + 4;
  constexpr int NT = C / 16;
  constexpr int NC = C / 32;
  __shared__ float xcat[4][16][CP];
  __shared__ float sp[4][10][16];
  const int g = threadIdx.x >> 6;
  const int l = threadIdx.x & 63;
  const int quad = l >> 4, col = l & 15;
  const int pid = blockIdx.x * 4 + g;
  const int b = pid >> 13, n = pid & (N_ - 1);
  const float* cb = coords + (size_t)b * N_ * 3;

  if (l < 16) {
    const int id = knn_i[(size_t)pid * K_ + l];
    const float dd = knn_d[(size_t)pid * K_ + l];
    const float cx = cb[n * 3 + 0], cy = cb[n * 3 + 1], cz = cb[n * 3 + 2];
    const float nx = cb[id * 3 + 0], ny = cb[id * 3 + 1], nz = cb[id * 3 + 2];
    sp[g][0][l] = cx; sp[g][1][l] = cy; sp[g][2][l] = cz;
    sp[g][3][l] = nx; sp[g][4][l] = ny; sp[g][5][l] = nz;
    sp[g][6][l] = cx - nx; sp[g][7][l] = cy - ny; sp[g][8][l] = cz - nz;
    sp[g][9][l] = dd;
  }
  if (l < CF) {
    const double cnt = (double)(B_ * N_);
    const double mean = sfe[l] / cnt;
    const double var = sfe[CF + l] / cnt - mean * mean;
    const double av = (double)gfe[l] / sqrt(var + 1e-5);
    const float af = (float)av;
    const float bfv = (float)((double)tfe[l] - av * mean);
    float v = feat[(size_t)pid * CF + l];
    v = af * v + bfv;
    v = (v >= 0.0f) ? v : slope * v;
#pragma unroll
    for (int j = 0; j < 16; ++j) xcat[g][j][CSF + l] = v;
  }
  __syncthreads();
  if (l < CSF) {
    float z[16];
    const float bz = blse[l];
#pragma unroll
    for (int j = 0; j < 16; ++j) z[j] = bz;
#pragma unroll
    for (int d = 0; d < 10; ++d) {
      const float wv = wlse[l * 10 + d];
      const float4* sr = (const float4*)&sp[g][d][0];
      const float4 s0 = sr[0], s1 = sr[1], s2 = sr[2], s3 = sr[3];
      z[0] += wv * s0.x; z[1] += wv * s0.y; z[2] += wv * s0.z; z[3] += wv * s0.w;
      z[4] += wv * s1.x; z[5] += wv * s1.y; z[6] += wv * s1.z; z[7] += wv * s1.w;
      z[8] += wv * s2.x; z[9] += wv * s2.y; z[10] += wv * s2.z; z[11] += wv * s2.w;
      z[12] += wv * s3.x; z[13] += wv * s3.y; z[14] += wv * s3.z; z[15] += wv * s3.w;
    }
#pragma unroll
    for (int j = 0; j < 16; ++j) xcat[g][j][l] = fmaxf(z[j], 0.0f);
  }
  __syncthreads();
  f32x4 d[NT];
#pragma unroll
  for (int t = 0; t < NT; ++t) {
    const float pbv = pb[t * 16 + col];
    d[t][0] = pbv; d[t][1] = pbv; d[t][2] = pbv; d[t][3] = pbv;
  }
#pragma unroll
  for (int cc = 0; cc < NC; ++cc) {
    const float* xr = &xcat[g][col][cc * 32 + quad * 8];
    const float4 xa = *(const float4*)xr;
    const float4 xb = *(const float4*)(xr + 4);
    union { bf16x8 v; short u[8]; } A;
    A.u[0] = f2bf(xa.x); A.u[1] = f2bf(xa.y); A.u[2] = f2bf(xa.z); A.u[3] = f2bf(xa.w);
    A.u[4] = f2bf(xb.x); A.u[5] = f2bf(xb.y); A.u[6] = f2bf(xb.z); A.u[7] = f2bf(xb.w);
#pragma unroll
    for (int t = 0; t < NT; ++t) {
      const bf16x8 Bv = *(const bf16x8*)(wB + (size_t)(t * 16 + col) * C + cc * 32 + quad * 8);
      d[t] = __builtin_amdgcn_mfma_f32_16x16x32_bf16(A.v, Bv, d[t], 0, 0, 0);
    }
  }
#pragma unroll
  for (int t = 0; t < NT; ++t) {
    float mx = fmaxf(fmaxf(d[t][0], d[t][1]), fmaxf(d[t][2], d[t][3]));
    mx = fmaxf(mx, __shfl_xor(mx, 16));
    mx = fmaxf(mx, __shfl_xor(mx, 32));
    float e0 = __expf(d[t][0] - mx), e1 = __expf(d[t][1] - mx);
    float e2 = __expf(d[t][2] - mx), e3 = __expf(d[t][3] - mx);
    float s = e0 + e1 + e2 + e3;
    s += __shfl_xor(s, 16);
    s += __shfl_xor(s, 32);
    const int o = t * 16 + col;
    float part = e0 * xcat[g][quad * 4 + 0][o] + e1 * xcat[g][quad * 4 + 1][o] +
                 e2 * xcat[g][quad * 4 + 2][o] + e3 * xcat[g][quad * 4 + 3][o];
    part += __shfl_xor(part, 16);
    part += __shfl_xor(part, 32);
    if (quad == 0) out[(size_t)pid * C + o] = part / s;
  }
}

// ---------------------------------------------------------------------------
// Final: relu(affine(y3|yr)) with LDS transpose for coalesced writes
// ---------------------------------------------------------------------------
__global__ __launch_bounds__(256) void final_kernel(const float* __restrict__ y3,
                                                    const float* __restrict__ yr,
                                                    const double* __restrict__ s3,
                                                    const float* __restrict__ g3, const float* __restrict__ t3,
                                                    const double* __restrict__ sr,
                                                    const float* __restrict__ gr, const float* __restrict__ tr,
                                                    float* __restrict__ out) {
  __shared__ float tile[256 * 17];
  const int blk = blockIdx.x;
  const int b = blk >> 9;
  const int n0 = (blk & 511) << 4;
  const int c = threadIdx.x;
  const float* src;
  const double* sa;
  const float *gp, *tp;
  int cc;
  if (c < 128) { src = y3; sa = s3; gp = g3; tp = t3; cc = c; }
  else { src = yr; sa = sr; gp = gr; tp = tr; cc = c - 128; }
  const double cnt = (double)(B_ * N_);
  const double mean = sa[cc] / cnt;
  const double var = sa[128 + cc] / cnt - mean * mean;
  const double avd = (double)gp[cc] / sqrt(var + 1e-5);
  const float av = (float)avd;
  const float bv = (float)((double)tp[cc] - avd * mean);
#pragma unroll
  for (int nl = 0; nl < 16; ++nl) {
    const float x = av * src[((size_t)(b * N_ + n0 + nl)) * 128 + cc] + bv;
    tile[c * 17 + nl] = fmaxf(x, 0.0f);
  }
  __syncthreads();
  const int np = c & 15, grp = c >> 4;
#pragma unroll
  for (int j = 0; j < 16; ++j) {
    const int c2 = grp * 16 + j;
    out[((size_t)(b * 256 + c2)) * N_ + n0 + np] = tile[c2 * 17 + np];
  }
}

// ---------------------------------------------------------------------------
extern "C" void kernel_launch(void* const* d_in, const int* in_sizes, int n_in,
                              void* d_out, int out_size, void* d_ws, size_t ws_size,
                              hipStream_t stream) {
  (void)in_sizes; (void)n_in; (void)out_size; (void)ws_size;
  const float* coords   = (const float*)d_in[0];
  const float* features = (const float*)d_in[1];
  const float* mlp1_w = (const float*)d_in[2];
  const float* mlp1_b = (const float*)d_in[3];
  const float* mlp1_g = (const float*)d_in[4];
  const float* mlp1_t = (const float*)d_in[5];
  const float* lse1_w = (const float*)d_in[6];
  const float* lse1_b = (const float*)d_in[7];
  const float* lse1_g = (const float*)d_in[8];
  const float* lse1_t = (const float*)d_in[9];
  const float* mlpp1_w = (const float*)d_in[10];
  const float* mlpp1_b = (const float*)d_in[11];
  const float* mlpp1_g = (const float*)d_in[12];
  const float* mlpp1_t = (const float*)d_in[13];
  const float* lse2_w = (const float*)d_in[14];
  const float* lse2_b = (const float*)d_in[15];
  const float* lse2_g = (const float*)d_in[16];
  const float* lse2_t = (const float*)d_in[17];
  const float* mlp2_w = (const float*)d_in[18];
  const float* mlp2_b = (const float*)d_in[19];
  const float* mlp2_g = (const float*)d_in[20];
  const float* mlp2_t = (const float*)d_in[21];
  const float* res_w = (const float*)d_in[22];
  const float* res_b = (const float*)d_in[23];
  const float* res_g = (const float*)d_in[24];
  const float* res_t = (const float*)d_in[25];
  const float* pool1_w = (const float*)d_in[26];
  const float* pool1_b = (const float*)d_in[27];
  const float* pool2_w = (const float*)d_in[28];
  const float* pool2_b = (const float*)d_in[29];

  float* wsf = (float*)d_ws;
  int* knn_i = (int*)d_ws;                 // 262144 ints
  float* knn_d = wsf + 262144;             // 262144
  float* y1 = wsf + 524288;                // (B,N,64)
  float* pooled1 = wsf + 1572864;          // (B,N,128)
  float* y2 = wsf + 3670016;               // (B,N,32)
  float* pooled2 = wsf + 4194304;          // (B,N,64)
  float* y3 = wsf + 5242880;               // (B,N,128)
  float* yr = wsf + 7340032;               // (B,N,128)
  double* dacc = (double*)(wsf + 9437184);
  double* mom = dacc;                      // 65
  double* sacc_mlp1 = dacc + 65;           // 128
  double* sacc_mlpp1 = dacc + 193;         // 64
  double* sacc_mlp2 = dacc + 257;          // 256
  double* sacc_res = dacc + 513;           // 256 -> ends 769
  float* fpar = wsf + 9437184 + 1600;
  float* w1f = fpar;                 // 640
  float* b1f = w1f + 640;            // 64
  float* w2f = b1f + 64;             // 320
  float* b2f = w2f + 320;            // 32
  short* wB1 = (short*)(b2f + 32);   // 16384 shorts
  short* wB2 = wB1 + 16384;          // 4096
  short* f1H = wB2 + 4096;           // 2048
  short* f1L = f1H + 2048;           // 2048
  short* f2H = f1L + 2048;           // 4096
  short* f2L = f2H + 4096;           // 4096
  short* f3H = f2L + 4096;           // 8192
  short* f3L = f3H + 8192;           // 8192
  short* fRH = f3L + 8192;           // 4096
  short* fRL = fRH + 4096;           // 4096

  hipMemsetAsync(dacc, 0, 769 * sizeof(double), stream);
  knn_kernel<<<dim3(N_ / 16, B_), 512, 0, stream>>>(coords, knn_i, knn_d);
  convert_kernel<<<28, 256, 0, stream>>>(pool1_w, pool2_w, wB1, wB2,
                                         mlp1_w, f1H, f1L, mlpp1_w, f2H, f2L,
                                         mlp2_w, f3H, f3L, res_w, fRH, fRL);
  moments_kernel<<<256, 64, 0, stream>>>(coords, knn_i, knn_d, mom);
  setup_kernel<<<1, 128, 0, stream>>>(mom, lse1_w, lse1_b, lse1_g, lse1_t,
                                      lse2_w, lse2_b, lse2_g, lse2_t,
                                      w1f, b1f, w2f, b2f);
  gemm_mfma_kernel<32, 64, false><<<256, 256, 0, stream>>>(features, f1H, f1L, mlp1_b, y1, sacc_mlp1);
  pool_kernel<64, 64><<<B_ * N_ / 4, 256, 0, stream>>>(
      coords, knn_i, knn_d, w1f, b1f, y1, sacc_mlp1, mlp1_g, mlp1_t, 0.2f, wB1, pool1_b, pooled1);
  gemm_mfma_kernel<128, 32, true><<<256, 256, 0, stream>>>(pooled1, f2H, f2L, mlpp1_b, y2, sacc_mlpp1);
  pool_kernel<32, 32><<<B_ * N_ / 4, 256, 0, stream>>>(
      coords, knn_i, knn_d, w2f, b2f, y2, sacc_mlpp1, mlpp1_g, mlpp1_t, 0.0f, wB2, pool2_b, pooled2);
  gemm_mfma_kernel<64, 128, true><<<256, 256, 0, stream>>>(pooled2, f3H, f3L, mlp2_b, y3, sacc_mlp2);
  gemm_mfma_kernel<32, 128, false><<<256, 256, 0, stream>>>(features, fRH, fRL, res_b, yr, sacc_res);
  final_kernel<<<B_ * 512, 256, 0, stream>>>(y3, yr, sacc_mlp2, mlp2_g, mlp2_t,
                                             sacc_res, res_g, res_t, (float*)d_out);
}

// Round 7
// 433.449 us; speedup vs baseline: 1.7252x; 1.0034x over previous
//
#include <hip/hip_runtime.h>

static constexpr int N_ = 8192;
static constexpr int B_ = 2;
static constexpr int K_ = 16;

typedef __attribute__((ext_vector_type(8))) short bf16x8;
typedef __attribute__((ext_vector_type(4))) float f32x4;

__device__ __forceinline__ short f2bf(float f) {
  unsigned int u = __float_as_uint(f);
  unsigned int r = (u + 0x7FFFu + ((u >> 16) & 1u)) >> 16;
  return (short)r;
}
__device__ __forceinline__ float bf2f(short h) {
  return __uint_as_float(((unsigned int)(unsigned short)h) << 16);
}
// DPP row_shr:1 — lane i <- lane i-1 within 16-lane rows (list lives in lanes 0..15)
__device__ __forceinline__ float dpp_shr1_f(float x) {
  return __uint_as_float((unsigned int)__builtin_amdgcn_update_dpp(
      0, (int)__float_as_uint(x), 0x111, 0xF, 0xF, true));
}
__device__ __forceinline__ int dpp_shr1_i(int x) {
  return __builtin_amdgcn_update_dpp(0, x, 0x111, 0xF, 0xF, true);
}
__device__ __forceinline__ float rdlane_f(float x, int l) {
  return __uint_as_float(__builtin_amdgcn_readlane(__float_as_uint(x), l));
}

// ---------------------------------------------------------------------------
// KNN: two queries/wave share each candidate ds_read_b128. LEAN drain (R4
// semantics: no in-drain tau refresh — stale extra inserts are provably
// harmless, list invariant = 16 smallest inserted) + DPP shift-up + readlane
// (zero LDS-crossbar ops per insert). Vectorized float4 tile staging.
// ---------------------------------------------------------------------------
__global__ __launch_bounds__(512) void knn_kernel(const float* __restrict__ coords,
                                                  int* __restrict__ oidx,
                                                  float* __restrict__ odist) {
  __shared__ float4 pts[2048];
  const int b = blockIdx.y;
  const int wv = threadIdx.x >> 6;
  const int lane = threadIdx.x & 63;
  const bool lpos = (lane != 0);
  const int q0 = blockIdx.x * 16 + wv * 2;
  const int q1 = q0 + 1;
  const float* cb = coords + (size_t)b * N_ * 3;
  const float qx0 = cb[q0 * 3 + 0], qy0 = cb[q0 * 3 + 1], qz0 = cb[q0 * 3 + 2];
  const float qx1 = cb[q1 * 3 + 0], qy1 = cb[q1 * 3 + 1], qz1 = cb[q1 * 3 + 2];
  const float qsq0 = __fadd_rn(__fadd_rn(__fmul_rn(qx0, qx0), __fmul_rn(qy0, qy0)), __fmul_rn(qz0, qz0));
  const float qsq1 = __fadd_rn(__fadd_rn(__fmul_rn(qx1, qx1), __fmul_rn(qy1, qy1)), __fmul_rn(qz1, qz1));
  float kd0 = INFINITY, kd1 = INFINITY;
  int ki0 = 0, ki1 = 0;
  float tau0 = INFINITY, tau1 = INFINITY;
  for (int t0 = 0; t0 < N_; t0 += 2048) {
    __syncthreads();
    {
      // thread t stages points 4t..4t+3 via three float4 loads
      const float4* cb4 = (const float4*)(cb + (size_t)t0 * 3);
      const int t = threadIdx.x;
      const float4 a = cb4[3 * t + 0];
      const float4 bb = cb4[3 * t + 1];
      const float4 c = cb4[3 * t + 2];
      const float px[4] = {a.x, a.w, bb.z, c.y};
      const float py[4] = {a.y, bb.x, bb.w, c.z};
      const float pz[4] = {a.z, bb.y, c.x, c.w};
#pragma unroll
      for (int u = 0; u < 4; ++u) {
        const float sq = __fadd_rn(__fadd_rn(__fmul_rn(px[u], px[u]), __fmul_rn(py[u], py[u])),
                                   __fmul_rn(pz[u], pz[u]));
        pts[4 * t + u] = make_float4(px[u], py[u], pz[u], sq);
      }
    }
    __syncthreads();
    for (int s = 0; s < 2048; s += 64) {
      const float4 p = pts[s + lane];
      const int base = t0 + s;
      float d20, d21;
      {
        const float dot = __fadd_rn(__fadd_rn(__fmul_rn(qx0, p.x), __fmul_rn(qy0, p.y)), __fmul_rn(qz0, p.z));
        d20 = __fsub_rn(__fadd_rn(qsq0, p.w), __fmul_rn(2.0f, dot));
      }
      {
        const float dot = __fadd_rn(__fadd_rn(__fmul_rn(qx1, p.x), __fmul_rn(qy1, p.y)), __fmul_rn(qz1, p.z));
        d21 = __fsub_rn(__fadd_rn(qsq1, p.w), __fmul_rn(2.0f, dot));
      }
      unsigned long long m0 = __ballot(d20 < tau0);
      unsigned long long m1 = __ballot(d21 < tau1);
      if (base == (q0 & ~63)) m0 &= ~(1ull << (q0 & 63));  // self-exclude (scalar)
      if (base == (q1 & ~63)) m1 &= ~(1ull << (q1 & 63));
      if (m0) {
        do {
          const int src = __builtin_ctzll(m0);  // ascending index -> tie stability
          const float dc = rdlane_f(d20, src);
          const int jc = base + src;
          const float sd = dpp_shr1_f(kd0);
          const int si = dpp_shr1_i(ki0);
          const bool c1 = kd0 > dc;             // strict: equals keep earlier entries
          const bool c2 = lpos && (sd > dc);
          kd0 = c1 ? (c2 ? sd : dc) : kd0;
          ki0 = c1 ? (c2 ? si : jc) : ki0;
          m0 &= (m0 - 1);
        } while (m0);
        tau0 = rdlane_f(kd0, 15);
      }
      if (m1) {
        do {
          const int src = __builtin_ctzll(m1);
          const float dc = rdlane_f(d21, src);
          const int jc = base + src;
          const float sd = dpp_shr1_f(kd1);
          const int si = dpp_shr1_i(ki1);
          const bool c1 = kd1 > dc;
          const bool c2 = lpos && (sd > dc);
          kd1 = c1 ? (c2 ? sd : dc) : kd1;
          ki1 = c1 ? (c2 ? si : jc) : ki1;
          m1 &= (m1 - 1);
        } while (m1);
        tau1 = rdlane_f(kd1, 15);
      }
    }
  }
  if (lane < 16) {
    oidx[((size_t)b * N_ + q0) * K_ + lane] = ki0;
    odist[((size_t)b * N_ + q0) * K_ + lane] = fmaxf(kd0, 0.0f);
    oidx[((size_t)b * N_ + q1) * K_ + lane] = ki1;
    odist[((size_t)b * N_ + q1) * K_ + lane] = fmaxf(kd1, 0.0f);
  }
}

// ---------------------------------------------------------------------------
// Spatial moments, decomposed (14 accumulators per point)
// ---------------------------------------------------------------------------
__device__ __forceinline__ float snn_get(const float* SNN, int a, int b) {
  const int i = a < b ? a : b, j = a < b ? b : a;
  return SNN[i == 0 ? j : (i == 1 ? 2 + j : 3 + j)];
}
__device__ __forceinline__ float mom_mean(int i, const float* C, const float* SN, float Sd) {
  if (i < 3) return 16.0f * C[i];
  if (i < 6) return SN[i - 3];
  if (i < 9) return 16.0f * C[i - 6] - SN[i - 6];
  return Sd;
}
__device__ __forceinline__ float mom_prod(int i, int j, const float* C, const float* SN,
                                          const float* SNN, float Sd, float Sdd, const float* SND) {
  const int ti = i < 3 ? 0 : (i < 6 ? 1 : (i < 9 ? 2 : 3));
  const int tj = j < 3 ? 0 : (j < 6 ? 1 : (j < 9 ? 2 : 3));
  const int a = (ti == 3) ? 0 : (i - ti * 3);
  const int bb = (tj == 3) ? 0 : (j - tj * 3);
  if (ti == 0 && tj == 0) return 16.0f * C[a] * C[bb];
  if (ti == 0 && tj == 1) return C[a] * SN[bb];
  if (ti == 0 && tj == 2) return C[a] * (16.0f * C[bb] - SN[bb]);
  if (ti == 0 && tj == 3) return C[a] * Sd;
  if (ti == 1 && tj == 1) return snn_get(SNN, a, bb);
  if (ti == 1 && tj == 2) return C[bb] * SN[a] - snn_get(SNN, a, bb);
  if (ti == 1 && tj == 3) return SND[a];
  if (ti == 2 && tj == 2) return 16.0f * C[a] * C[bb] - C[a] * SN[bb] - C[bb] * SN[a] + snn_get(SNN, a, bb);
  if (ti == 2 && tj == 3) return C[a] * Sd - SND[a];
  return Sdd;
}

__global__ __launch_bounds__(64) void moments_kernel(const float* __restrict__ coords,
                                                     const int* __restrict__ knn_i,
                                                     const float* __restrict__ knn_d,
                                                     double* __restrict__ mom) {
  const int t = blockIdx.x * 64 + threadIdx.x;
  const int b = t >> 13, n = t & (N_ - 1);
  const float* cb = coords + (size_t)b * N_ * 3;
  float C[3] = {cb[n * 3 + 0], cb[n * 3 + 1], cb[n * 3 + 2]};
  float SN[3] = {0.f, 0.f, 0.f}, SNN[6] = {0.f, 0.f, 0.f, 0.f, 0.f, 0.f};
  float SND[3] = {0.f, 0.f, 0.f}, Sd = 0.f, Sdd = 0.f;
  for (int k = 0; k < K_; ++k) {
    const int id = knn_i[(size_t)t * K_ + k];
    const float dd = knn_d[(size_t)t * K_ + k];
    const float nx = cb[id * 3 + 0], ny = cb[id * 3 + 1], nz = cb[id * 3 + 2];
    SN[0] += nx; SN[1] += ny; SN[2] += nz;
    SNN[0] += nx * nx; SNN[1] += nx * ny; SNN[2] += nx * nz;
    SNN[3] += ny * ny; SNN[4] += ny * nz; SNN[5] += nz * nz;
    Sd += dd; Sdd += dd * dd;
    SND[0] += nx * dd; SND[1] += ny * dd; SND[2] += nz * dd;
  }
  float m65[65];
  int e = 0;
#pragma unroll
  for (int i = 0; i < 10; ++i) m65[e++] = mom_mean(i, C, SN, Sd);
#pragma unroll
  for (int i = 0; i < 10; ++i)
#pragma unroll
    for (int j = i; j < 10; ++j) m65[e++] = mom_prod(i, j, C, SN, SNN, Sd, Sdd, SND);
#pragma unroll
  for (int q = 0; q < 65; ++q) {
    float v = m65[q];
#pragma unroll
    for (int off = 32; off > 0; off >>= 1) v += __shfl_xor(v, off);
    m65[q] = v;
  }
  __shared__ float buf[65];
  if (threadIdx.x == 0) {
#pragma unroll
    for (int q = 0; q < 65; ++q) buf[q] = m65[q];
  }
  __syncthreads();
  if (threadIdx.x < 64) atomicAdd(&mom[threadIdx.x], (double)buf[threadIdx.x]);
  if (threadIdx.x == 0) atomicAdd(&mom[64], (double)buf[64]);
}

// ---------------------------------------------------------------------------
// Parallel weight conversion (bf16 pool weights + hi/lo gemm fragments)
// ---------------------------------------------------------------------------
template <int CI, int CO>
__device__ __forceinline__ void conv_frag_seg(const float* __restrict__ w, short* __restrict__ H,
                                              short* __restrict__ L, int tid, int nthr) {
  constexpr int NT = CO / 16;
  for (int i = tid; i < CI * CO; i += nthr) {
    const int j = i & 7, l = (i >> 3) & 63, tmp = i >> 9;
    const int tt = tmp % NT, cc = tmp / NT;
    const int c = cc * 32 + (l >> 4) * 8 + j;
    const int o = tt * 16 + (l & 15);
    const float v = w[o * CI + c];
    const short h = f2bf(v);
    H[i] = h;
    L[i] = f2bf(v - bf2f(h));
  }
}

__global__ __launch_bounds__(256) void convert_kernel(
    const float* __restrict__ pw1, const float* __restrict__ pw2,
    short* __restrict__ wB1, short* __restrict__ wB2,
    const float* __restrict__ wm1, short* __restrict__ f1H, short* __restrict__ f1L,
    const float* __restrict__ wmp, short* __restrict__ f2H, short* __restrict__ f2L,
    const float* __restrict__ wm2, short* __restrict__ f3H, short* __restrict__ f3L,
    const float* __restrict__ wrs, short* __restrict__ fRH, short* __restrict__ fRL) {
  const int blk = blockIdx.x;
  if (blk < 8) {
    const int tid = blk * 256 + threadIdx.x;
    for (int i = tid; i < 128 * 128; i += 2048) wB1[i] = f2bf(pw1[i]);
  } else if (blk < 10) {
    const int tid = (blk - 8) * 256 + threadIdx.x;
    for (int i = tid; i < 64 * 64; i += 512) wB2[i] = f2bf(pw2[i]);
  } else if (blk < 12) {
    conv_frag_seg<32, 64>(wm1, f1H, f1L, (blk - 10) * 256 + threadIdx.x, 512);
  } else if (blk < 16) {
    conv_frag_seg<128, 32>(wmp, f2H, f2L, (blk - 12) * 256 + threadIdx.x, 1024);
  } else if (blk < 24) {
    conv_frag_seg<64, 128>(wm2, f3H, f3L, (blk - 16) * 256 + threadIdx.x, 2048);
  } else {
    conv_frag_seg<32, 128>(wrs, fRH, fRL, (blk - 24) * 256 + threadIdx.x, 1024);
  }
}

// ---------------------------------------------------------------------------
// Setup: lse BN affines folded into compact per-channel vectors:
//   w8[c] = {P0,P1,P2, Q0,Q1,Q2, wd, b'} where z = P.c + Q.n + wd*d + b'
//   (P = a(w_c + w_rel), Q = a(w_n − w_rel); c-term is k-invariant)
// ---------------------------------------------------------------------------
__global__ void setup_kernel(const double* __restrict__ mom,
                             const float* __restrict__ w1, const float* __restrict__ b1,
                             const float* __restrict__ g1, const float* __restrict__ t1,
                             const float* __restrict__ w2, const float* __restrict__ b2,
                             const float* __restrict__ g2, const float* __restrict__ t2,
                             float* __restrict__ w1f8, float* __restrict__ w2f8) {
  const int t = threadIdx.x;
  __shared__ double mu[10];
  __shared__ double S[10][10];
  const double cnt = (double)B_ * N_ * K_;
  if (t < 10) mu[t] = mom[t] / cnt;
  if (t < 55) {
    int e = t, i = 0;
    while (e >= 10 - i) { e -= 10 - i; ++i; }
    const int j = i + e;
    const double v = mom[10 + t] / cnt;
    S[i][j] = v;
    S[j][i] = v;
  }
  __syncthreads();
  const float *w, *bias, *gg, *bt;
  float *wf;
  int c;
  if (t < 64) { w = w1; bias = b1; gg = g1; bt = t1; wf = w1f8; c = t; }
  else if (t < 96) { w = w2; bias = b2; gg = g2; bt = t2; wf = w2f8; c = t - 64; }
  else return;
  double wd[10];
#pragma unroll
  for (int d = 0; d < 10; ++d) wd[d] = (double)w[c * 10 + d];
  const double cbv = (double)bias[c];
  double mz = cbv;
  for (int d = 0; d < 10; ++d) mz += wd[d] * mu[d];
  double e2 = cbv * cbv;
  for (int d = 0; d < 10; ++d) e2 += 2.0 * cbv * wd[d] * mu[d];
  for (int d = 0; d < 10; ++d)
    for (int e = 0; e < 10; ++e) e2 += wd[d] * wd[e] * S[d][e];
  const double var = e2 - mz * mz;
  const double a = (double)gg[c] / sqrt(var + 1e-5);
  const double shift = (double)bt[c] - a * mz;
  wf[c * 8 + 0] = (float)(a * (wd[0] + wd[6]));
  wf[c * 8 + 1] = (float)(a * (wd[1] + wd[7]));
  wf[c * 8 + 2] = (float)(a * (wd[2] + wd[8]));
  wf[c * 8 + 3] = (float)(a * (wd[3] - wd[6]));
  wf[c * 8 + 4] = (float)(a * (wd[4] - wd[7]));
  wf[c * 8 + 5] = (float)(a * (wd[5] - wd[8]));
  wf[c * 8 + 6] = (float)(a * wd[9]);
  wf[c * 8 + 7] = (float)(a * cbv + shift);
}

// ---------------------------------------------------------------------------
// MFMA GEMM + fused BN stats (hi/lo bf16 split => ~fp32 accuracy)
// ---------------------------------------------------------------------------
template <int CI, int CO, bool ROWMAJ>
__global__ __launch_bounds__(256) void gemm_mfma_kernel(const float* __restrict__ in,
                                                        const short* __restrict__ fragH,
                                                        const short* __restrict__ fragL,
                                                        const float* __restrict__ bias,
                                                        float* __restrict__ out,
                                                        double* __restrict__ sacc) {
  constexpr int NT = CO / 16;
  constexpr int NC = CI / 32;
  __shared__ float part[4][CO][2];
  const int wv = threadIdx.x >> 6, l = threadIdx.x & 63;
  const int col = l & 15, quad = l >> 4;
  const int p0 = blockIdx.x * 64 + wv * 16;
  const int pt = p0 + col;
  f32x4 d[NT];
#pragma unroll
  for (int t = 0; t < NT; ++t) {
    const float bv = bias[t * 16 + col];
    d[t][0] = bv; d[t][1] = bv; d[t][2] = bv; d[t][3] = bv;
  }
#pragma unroll
  for (int cc = 0; cc < NC; ++cc) {
    float xv[8];
    if (ROWMAJ) {
      const float* ip = in + (size_t)pt * CI + cc * 32 + quad * 8;
      *(float4*)&xv[0] = *(const float4*)ip;
      *(float4*)&xv[4] = *(const float4*)(ip + 4);
    } else {
      const int b = pt >> 13, n = pt & (N_ - 1);
      const float* ip = in + ((size_t)b * CI + cc * 32 + quad * 8) * N_ + n;
#pragma unroll
      for (int j = 0; j < 8; ++j) xv[j] = ip[(size_t)j * N_];
    }
    union { bf16x8 v; short u[8]; } AH, AL;
#pragma unroll
    for (int j = 0; j < 8; ++j) {
      const short h = f2bf(xv[j]);
      AH.u[j] = h;
      AL.u[j] = f2bf(xv[j] - bf2f(h));
    }
#pragma unroll
    for (int t = 0; t < NT; ++t) {
      const size_t fo = ((size_t)(cc * NT + t) * 64 + l) * 8;
      const bf16x8 BH = *(const bf16x8*)(fragH + fo);
      const bf16x8 BL = *(const bf16x8*)(fragL + fo);
      d[t] = __builtin_amdgcn_mfma_f32_16x16x32_bf16(AH.v, BH, d[t], 0, 0, 0);
      d[t] = __builtin_amdgcn_mfma_f32_16x16x32_bf16(AH.v, BL, d[t], 0, 0, 0);
      d[t] = __builtin_amdgcn_mfma_f32_16x16x32_bf16(AL.v, BH, d[t], 0, 0, 0);
    }
  }
#pragma unroll
  for (int t = 0; t < NT; ++t) {
#pragma unroll
    for (int r = 0; r < 4; ++r)
      out[(size_t)(p0 + quad * 4 + r) * CO + t * 16 + col] = d[t][r];
    float s1 = d[t][0] + d[t][1] + d[t][2] + d[t][3];
    float s2 = d[t][0] * d[t][0] + d[t][1] * d[t][1] + d[t][2] * d[t][2] + d[t][3] * d[t][3];
    s1 += __shfl_xor(s1, 16); s1 += __shfl_xor(s1, 32);
    s2 += __shfl_xor(s2, 16); s2 += __shfl_xor(s2, 32);
    if (quad == 0) { part[wv][t * 16 + col][0] = s1; part[wv][t * 16 + col][1] = s2; }
  }
  __syncthreads();
  if (threadIdx.x < CO) {
    const int o = threadIdx.x;
    atomicAdd(&sacc[o], (double)(part[0][o][0] + part[1][o][0] + part[2][o][0] + part[3][o][0]));
    atomicAdd(&sacc[CO + o], (double)(part[0][o][1] + part[1][o][1] + part[2][o][1] + part[3][o][1]));
  }
}

// ---------------------------------------------------------------------------
// Fused LSE + attentive pool, MFMA scores. Phase A stages (n,dd) as one
// float4 per k; Phase B uses compact w8 vectors: z = (P.c+b') + Q.n + wd*d
// (k-invariant term hoisted) — 4 FMA + 1 LDS read per k.
// ---------------------------------------------------------------------------
template <int CSF, int CF>
__global__ __launch_bounds__(256) void pool_kernel(
    const float* __restrict__ coords, const int* __restrict__ knn_i, const float* __restrict__ knn_d,
    const float* __restrict__ w8,
    const float* __restrict__ feat, const double* __restrict__ sfe,
    const float* __restrict__ gfe, const float* __restrict__ tfe,
    const float slope,
    const short* __restrict__ wB, const float* __restrict__ pb,
    float* __restrict__ out) {
  constexpr int C = CSF + CF;
  constexpr int CP = C + 4;
  constexpr int NT = C / 16;
  constexpr int NC = C / 32;
  __shared__ float xcat[4][16][CP];
  __shared__ float4 sp4[4][16];
  __shared__ float4 spc[4];
  const int g = threadIdx.x >> 6;
  const int l = threadIdx.x & 63;
  const int quad = l >> 4, col = l & 15;
  const int pid = blockIdx.x * 4 + g;
  const int b = pid >> 13, n = pid & (N_ - 1);
  const float* cb = coords + (size_t)b * N_ * 3;

  // Phase A: lanes 0..15 stage (nx,ny,nz,dd); lane 0 stages center
  if (l < 16) {
    const int id = knn_i[(size_t)pid * K_ + l];
    const float dd = knn_d[(size_t)pid * K_ + l];
    const float nx = cb[id * 3 + 0], ny = cb[id * 3 + 1], nz = cb[id * 3 + 2];
    sp4[g][l] = make_float4(nx, ny, nz, dd);
    if (l == 0) spc[g] = make_float4(cb[n * 3 + 0], cb[n * 3 + 1], cb[n * 3 + 2], 0.0f);
  }
  // Phase A2: feature channels, BN affine inline, broadcast over k
  if (l < CF) {
    const double cnt = (double)(B_ * N_);
    const double mean = sfe[l] / cnt;
    const double var = sfe[CF + l] / cnt - mean * mean;
    const double av = (double)gfe[l] / sqrt(var + 1e-5);
    const float af = (float)av;
    const float bfv = (float)((double)tfe[l] - av * mean);
    float v = feat[(size_t)pid * CF + l];
    v = af * v + bfv;
    v = (v >= 0.0f) ? v : slope * v;
#pragma unroll
    for (int j = 0; j < 16; ++j) xcat[g][j][CSF + l] = v;
  }
  __syncthreads();
  // Phase B: sf channels
  if (l < CSF) {
    const float4 wA = *(const float4*)(w8 + l * 8);      // P0,P1,P2,Q0
    const float4 wBv = *(const float4*)(w8 + l * 8 + 4); // Q1,Q2,wd,b'
    const float4 C4 = spc[g];
    const float tterm = wBv.w + wA.x * C4.x + wA.y * C4.y + wA.z * C4.z;
#pragma unroll
    for (int k = 0; k < 16; ++k) {
      const float4 nk = sp4[g][k];
      const float z = tterm + wA.w * nk.x + wBv.x * nk.y + wBv.y * nk.z + wBv.z * nk.w;
      xcat[g][k][l] = fmaxf(z, 0.0f);
    }
  }
  __syncthreads();
  // Phase C: MFMA scores (D[k][o], k=quad*4+r, o=t*16+col)
  f32x4 d[NT];
#pragma unroll
  for (int t = 0; t < NT; ++t) {
    const float pbv = pb[t * 16 + col];
    d[t][0] = pbv; d[t][1] = pbv; d[t][2] = pbv; d[t][3] = pbv;
  }
#pragma unroll
  for (int cc = 0; cc < NC; ++cc) {
    const float* xr = &xcat[g][col][cc * 32 + quad * 8];
    const float4 xa = *(const float4*)xr;
    const float4 xb = *(const float4*)(xr + 4);
    union { bf16x8 v; short u[8]; } A;
    A.u[0] = f2bf(xa.x); A.u[1] = f2bf(xa.y); A.u[2] = f2bf(xa.z); A.u[3] = f2bf(xa.w);
    A.u[4] = f2bf(xb.x); A.u[5] = f2bf(xb.y); A.u[6] = f2bf(xb.z); A.u[7] = f2bf(xb.w);
#pragma unroll
    for (int t = 0; t < NT; ++t) {
      const bf16x8 Bv = *(const bf16x8*)(wB + (size_t)(t * 16 + col) * C + cc * 32 + quad * 8);
      d[t] = __builtin_amdgcn_mfma_f32_16x16x32_bf16(A.v, Bv, d[t], 0, 0, 0);
    }
  }
  // Phase D: softmax over k (regs + shfl 16/32) + weighted sum
#pragma unroll
  for (int t = 0; t < NT; ++t) {
    float mx = fmaxf(fmaxf(d[t][0], d[t][1]), fmaxf(d[t][2], d[t][3]));
    mx = fmaxf(mx, __shfl_xor(mx, 16));
    mx = fmaxf(mx, __shfl_xor(mx, 32));
    float e0 = __expf(d[t][0] - mx), e1 = __expf(d[t][1] - mx);
    float e2 = __expf(d[t][2] - mx), e3 = __expf(d[t][3] - mx);
    float s = e0 + e1 + e2 + e3;
    s += __shfl_xor(s, 16);
    s += __shfl_xor(s, 32);
    const int o = t * 16 + col;
    float part = e0 * xcat[g][quad * 4 + 0][o] + e1 * xcat[g][quad * 4 + 1][o] +
                 e2 * xcat[g][quad * 4 + 2][o] + e3 * xcat[g][quad * 4 + 3][o];
    part += __shfl_xor(part, 16);
    part += __shfl_xor(part, 32);
    if (quad == 0) out[(size_t)pid * C + o] = part / s;
  }
}

// ---------------------------------------------------------------------------
// Final: relu(affine(y3|yr)) with LDS transpose for coalesced writes
// ---------------------------------------------------------------------------
__global__ __launch_bounds__(256) void final_kernel(const float* __restrict__ y3,
                                                    const float* __restrict__ yr,
                                                    const double* __restrict__ s3,
                                                    const float* __restrict__ g3, const float* __restrict__ t3,
                                                    const double* __restrict__ sr,
                                                    const float* __restrict__ gr, const float* __restrict__ tr,
                                                    float* __restrict__ out) {
  __shared__ float tile[256 * 17];
  const int blk = blockIdx.x;
  const int b = blk >> 9;
  const int n0 = (blk & 511) << 4;
  const int c = threadIdx.x;
  const float* src;
  const double* sa;
  const float *gp, *tp;
  int cc;
  if (c < 128) { src = y3; sa = s3; gp = g3; tp = t3; cc = c; }
  else { src = yr; sa = sr; gp = gr; tp = tr; cc = c - 128; }
  const double cnt = (double)(B_ * N_);
  const double mean = sa[cc] / cnt;
  const double var = sa[128 + cc] / cnt - mean * mean;
  const double avd = (double)gp[cc] / sqrt(var + 1e-5);
  const float av = (float)avd;
  const float bv = (float)((double)tp[cc] - avd * mean);
#pragma unroll
  for (int nl = 0; nl < 16; ++nl) {
    const float x = av * src[((size_t)(b * N_ + n0 + nl)) * 128 + cc] + bv;
    tile[c * 17 + nl] = fmaxf(x, 0.0f);
  }
  __syncthreads();
  const int np = c & 15, grp = c >> 4;
#pragma unroll
  for (int j = 0; j < 16; ++j) {
    const int c2 = grp * 16 + j;
    out[((size_t)(b * 256 + c2)) * N_ + n0 + np] = tile[c2 * 17 + np];
  }
}

// ---------------------------------------------------------------------------
extern "C" void kernel_launch(void* const* d_in, const int* in_sizes, int n_in,
                              void* d_out, int out_size, void* d_ws, size_t ws_size,
                              hipStream_t stream) {
  (void)in_sizes; (void)n_in; (void)out_size; (void)ws_size;
  const float* coords   = (const float*)d_in[0];
  const float* features = (const float*)d_in[1];
  const float* mlp1_w = (const float*)d_in[2];
  const float* mlp1_b = (const float*)d_in[3];
  const float* mlp1_g = (const float*)d_in[4];
  const float* mlp1_t = (const float*)d_in[5];
  const float* lse1_w = (const float*)d_in[6];
  const float* lse1_b = (const float*)d_in[7];
  const float* lse1_g = (const float*)d_in[8];
  const float* lse1_t = (const float*)d_in[9];
  const float* mlpp1_w = (const float*)d_in[10];
  const float* mlpp1_b = (const float*)d_in[11];
  const float* mlpp1_g = (const float*)d_in[12];
  const float* mlpp1_t = (const float*)d_in[13];
  const float* lse2_w = (const float*)d_in[14];
  const float* lse2_b = (const float*)d_in[15];
  const float* lse2_g = (const float*)d_in[16];
  const float* lse2_t = (const float*)d_in[17];
  const float* mlp2_w = (const float*)d_in[18];
  const float* mlp2_b = (const float*)d_in[19];
  const float* mlp2_g = (const float*)d_in[20];
  const float* mlp2_t = (const float*)d_in[21];
  const float* res_w = (const float*)d_in[22];
  const float* res_b = (const float*)d_in[23];
  const float* res_g = (const float*)d_in[24];
  const float* res_t = (const float*)d_in[25];
  const float* pool1_w = (const float*)d_in[26];
  const float* pool1_b = (const float*)d_in[27];
  const float* pool2_w = (const float*)d_in[28];
  const float* pool2_b = (const float*)d_in[29];

  float* wsf = (float*)d_ws;
  int* knn_i = (int*)d_ws;                 // 262144 ints
  float* knn_d = wsf + 262144;             // 262144
  float* y1 = wsf + 524288;                // (B,N,64)
  float* pooled1 = wsf + 1572864;          // (B,N,128)
  float* y2 = wsf + 3670016;               // (B,N,32)
  float* pooled2 = wsf + 4194304;          // (B,N,64)
  float* y3 = wsf + 5242880;               // (B,N,128)
  float* yr = wsf + 7340032;               // (B,N,128)
  double* dacc = (double*)(wsf + 9437184);
  double* mom = dacc;                      // 65
  double* sacc_mlp1 = dacc + 65;           // 128
  double* sacc_mlpp1 = dacc + 193;         // 64
  double* sacc_mlp2 = dacc + 257;          // 256
  double* sacc_res = dacc + 513;           // 256 -> ends 769
  float* fpar = wsf + 9437184 + 1600;
  float* w1f8 = fpar;                // 512
  float* w2f8 = w1f8 + 512;          // 256
  short* wB1 = (short*)(w2f8 + 256); // 16384 shorts
  short* wB2 = wB1 + 16384;          // 4096
  short* f1H = wB2 + 4096;           // 2048
  short* f1L = f1H + 2048;           // 2048
  short* f2H = f1L + 2048;           // 4096
  short* f2L = f2H + 4096;           // 4096
  short* f3H = f2L + 4096;           // 8192
  short* f3L = f3H + 8192;           // 8192
  short* fRH = f3L + 8192;           // 4096
  short* fRL = fRH + 4096;           // 4096

  hipMemsetAsync(dacc, 0, 769 * sizeof(double), stream);
  knn_kernel<<<dim3(N_ / 16, B_), 512, 0, stream>>>(coords, knn_i, knn_d);
  convert_kernel<<<28, 256, 0, stream>>>(pool1_w, pool2_w, wB1, wB2,
                                         mlp1_w, f1H, f1L, mlpp1_w, f2H, f2L,
                                         mlp2_w, f3H, f3L, res_w, fRH, fRL);
  moments_kernel<<<256, 64, 0, stream>>>(coords, knn_i, knn_d, mom);
  setup_kernel<<<1, 128, 0, stream>>>(mom, lse1_w, lse1_b, lse1_g, lse1_t,
                                      lse2_w, lse2_b, lse2_g, lse2_t, w1f8, w2f8);
  gemm_mfma_kernel<32, 64, false><<<256, 256, 0, stream>>>(features, f1H, f1L, mlp1_b, y1, sacc_mlp1);
  pool_kernel<64, 64><<<B_ * N_ / 4, 256, 0, stream>>>(
      coords, knn_i, knn_d, w1f8, y1, sacc_mlp1, mlp1_g, mlp1_t, 0.2f, wB1, pool1_b, pooled1);
  gemm_mfma_kernel<128, 32, true><<<256, 256, 0, stream>>>(pooled1, f2H, f2L, mlpp1_b, y2, sacc_mlpp1);
  pool_kernel<32, 32><<<B_ * N_ / 4, 256, 0, stream>>>(
      coords, knn_i, knn_d, w2f8, y2, sacc_mlpp1, mlpp1_g, mlpp1_t, 0.0f, wB2, pool2_b, pooled2);
  gemm_mfma_kernel<64, 128, true><<<256, 256, 0, stream>>>(pooled2, f3H, f3L, mlp2_b, y3, sacc_mlp2);
  gemm_mfma_kernel<32, 128, false><<<256, 256, 0, stream>>>(features, fRH, fRL, res_b, yr, sacc_res);
  final_kernel<<<B_ * 512, 256, 0, stream>>>(y3, yr, sacc_mlp2, mlp2_g, mlp2_t,
                                             sacc_res, res_g, res_t, (float*)d_out);
}

// Round 8
// 422.692 us; speedup vs baseline: 1.7691x; 1.0254x over previous
//
#include <hip/hip_runtime.h>

static constexpr int N_ = 8192;
static constexpr int B_ = 2;
static constexpr int K_ = 16;

typedef __attribute__((ext_vector_type(8))) short bf16x8;
typedef __attribute__((ext_vector_type(4))) float f32x4;

__device__ __forceinline__ short f2bf(float f) {
  unsigned int u = __float_as_uint(f);
  unsigned int r = (u + 0x7FFFu + ((u >> 16) & 1u)) >> 16;
  return (short)r;
}
__device__ __forceinline__ float bf2f(short h) {
  return __uint_as_float(((unsigned int)(unsigned short)h) << 16);
}
// DPP row_shr:1 — lane i <- lane i-1 within 16-lane rows (list lives in lanes 0..15)
__device__ __forceinline__ float dpp_shr1_f(float x) {
  return __uint_as_float((unsigned int)__builtin_amdgcn_update_dpp(
      0, (int)__float_as_uint(x), 0x111, 0xF, 0xF, true));
}
__device__ __forceinline__ int dpp_shr1_i(int x) {
  return __builtin_amdgcn_update_dpp(0, x, 0x111, 0xF, 0xF, true);
}
__device__ __forceinline__ float rdlane_f(float x, int l) {
  return __uint_as_float(__builtin_amdgcn_readlane(__float_as_uint(x), l));
}

// ---------------------------------------------------------------------------
// KNN: two queries/wave share each candidate ds_read_b128. Lean drain (no
// in-drain tau refresh; stale extra inserts are harmless) + DPP shift-up +
// readlane. Staging = R6 pattern: lane-consecutive float4 writes (0 bank
// conflicts; R7's 64B-stride writes caused 32-way conflicts — reverted).
// Distances in fma form (numpy reference uses BLAS fma contraction anyway).
// ---------------------------------------------------------------------------
__global__ __launch_bounds__(512) void knn_kernel(const float* __restrict__ coords,
                                                  int* __restrict__ oidx,
                                                  float* __restrict__ odist) {
  __shared__ float4 pts[2048];
  const int b = blockIdx.y;
  const int wv = threadIdx.x >> 6;
  const int lane = threadIdx.x & 63;
  const bool lpos = (lane != 0);
  const int q0 = blockIdx.x * 16 + wv * 2;
  const int q1 = q0 + 1;
  const float* cb = coords + (size_t)b * N_ * 3;
  const float qx0 = cb[q0 * 3 + 0], qy0 = cb[q0 * 3 + 1], qz0 = cb[q0 * 3 + 2];
  const float qx1 = cb[q1 * 3 + 0], qy1 = cb[q1 * 3 + 1], qz1 = cb[q1 * 3 + 2];
  const float qsq0 = fmaf(qx0, qx0, fmaf(qy0, qy0, qz0 * qz0));
  const float qsq1 = fmaf(qx1, qx1, fmaf(qy1, qy1, qz1 * qz1));
  const int qblk0 = q0 & ~63, qblk1 = q1 & ~63;
  const unsigned long long qbit0 = ~(1ull << (q0 & 63));
  const unsigned long long qbit1 = ~(1ull << (q1 & 63));
  float kd0 = INFINITY, kd1 = INFINITY;
  int ki0 = 0, ki1 = 0;
  float tau0 = INFINITY, tau1 = INFINITY;
  for (int t0 = 0; t0 < N_; t0 += 2048) {
    __syncthreads();
    for (int i = threadIdx.x; i < 2048; i += 512) {
      const int p = t0 + i;
      const float x = cb[p * 3 + 0], y = cb[p * 3 + 1], z = cb[p * 3 + 2];
      const float sq = fmaf(x, x, fmaf(y, y, z * z));
      pts[i] = make_float4(x, y, z, sq);
    }
    __syncthreads();
    for (int s = 0; s < 2048; s += 64) {
      const float4 p = pts[s + lane];
      const int base = t0 + s;
      const float dot0 = fmaf(qx0, p.x, fmaf(qy0, p.y, qz0 * p.z));
      const float dot1 = fmaf(qx1, p.x, fmaf(qy1, p.y, qz1 * p.z));
      const float d20 = fmaf(-2.0f, dot0, qsq0 + p.w);
      const float d21 = fmaf(-2.0f, dot1, qsq1 + p.w);
      unsigned long long m0 = __ballot(d20 < tau0);
      unsigned long long m1 = __ballot(d21 < tau1);
      if (base == qblk0) m0 &= qbit0;  // self-exclude (scalar)
      if (base == qblk1) m1 &= qbit1;
      if (m0) {
        do {
          const int src = __builtin_ctzll(m0);  // ascending index order
          const float dc = rdlane_f(d20, src);
          const int jc = base + src;
          const float sd = dpp_shr1_f(kd0);
          const int si = dpp_shr1_i(ki0);
          const bool c1 = kd0 > dc;             // strict: equals keep earlier entries
          const bool c2 = lpos && (sd > dc);
          kd0 = c1 ? (c2 ? sd : dc) : kd0;
          ki0 = c1 ? (c2 ? si : jc) : ki0;
          m0 &= (m0 - 1);
        } while (m0);
        tau0 = rdlane_f(kd0, 15);
      }
      if (m1) {
        do {
          const int src = __builtin_ctzll(m1);
          const float dc = rdlane_f(d21, src);
          const int jc = base + src;
          const float sd = dpp_shr1_f(kd1);
          const int si = dpp_shr1_i(ki1);
          const bool c1 = kd1 > dc;
          const bool c2 = lpos && (sd > dc);
          kd1 = c1 ? (c2 ? sd : dc) : kd1;
          ki1 = c1 ? (c2 ? si : jc) : ki1;
          m1 &= (m1 - 1);
        } while (m1);
        tau1 = rdlane_f(kd1, 15);
      }
    }
  }
  if (lane < 16) {
    oidx[((size_t)b * N_ + q0) * K_ + lane] = ki0;
    odist[((size_t)b * N_ + q0) * K_ + lane] = fmaxf(kd0, 0.0f);
    oidx[((size_t)b * N_ + q1) * K_ + lane] = ki1;
    odist[((size_t)b * N_ + q1) * K_ + lane] = fmaxf(kd1, 0.0f);
  }
}

// ---------------------------------------------------------------------------
// Spatial moments, decomposed (14 accumulators per point)
// ---------------------------------------------------------------------------
__device__ __forceinline__ float snn_get(const float* SNN, int a, int b) {
  const int i = a < b ? a : b, j = a < b ? b : a;
  return SNN[i == 0 ? j : (i == 1 ? 2 + j : 3 + j)];
}
__device__ __forceinline__ float mom_mean(int i, const float* C, const float* SN, float Sd) {
  if (i < 3) return 16.0f * C[i];
  if (i < 6) return SN[i - 3];
  if (i < 9) return 16.0f * C[i - 6] - SN[i - 6];
  return Sd;
}
__device__ __forceinline__ float mom_prod(int i, int j, const float* C, const float* SN,
                                          const float* SNN, float Sd, float Sdd, const float* SND) {
  const int ti = i < 3 ? 0 : (i < 6 ? 1 : (i < 9 ? 2 : 3));
  const int tj = j < 3 ? 0 : (j < 6 ? 1 : (j < 9 ? 2 : 3));
  const int a = (ti == 3) ? 0 : (i - ti * 3);
  const int bb = (tj == 3) ? 0 : (j - tj * 3);
  if (ti == 0 && tj == 0) return 16.0f * C[a] * C[bb];
  if (ti == 0 && tj == 1) return C[a] * SN[bb];
  if (ti == 0 && tj == 2) return C[a] * (16.0f * C[bb] - SN[bb]);
  if (ti == 0 && tj == 3) return C[a] * Sd;
  if (ti == 1 && tj == 1) return snn_get(SNN, a, bb);
  if (ti == 1 && tj == 2) return C[bb] * SN[a] - snn_get(SNN, a, bb);
  if (ti == 1 && tj == 3) return SND[a];
  if (ti == 2 && tj == 2) return 16.0f * C[a] * C[bb] - C[a] * SN[bb] - C[bb] * SN[a] + snn_get(SNN, a, bb);
  if (ti == 2 && tj == 3) return C[a] * Sd - SND[a];
  return Sdd;
}

__global__ __launch_bounds__(64) void moments_kernel(const float* __restrict__ coords,
                                                     const int* __restrict__ knn_i,
                                                     const float* __restrict__ knn_d,
                                                     double* __restrict__ mom) {
  const int t = blockIdx.x * 64 + threadIdx.x;
  const int b = t >> 13, n = t & (N_ - 1);
  const float* cb = coords + (size_t)b * N_ * 3;
  float C[3] = {cb[n * 3 + 0], cb[n * 3 + 1], cb[n * 3 + 2]};
  float SN[3] = {0.f, 0.f, 0.f}, SNN[6] = {0.f, 0.f, 0.f, 0.f, 0.f, 0.f};
  float SND[3] = {0.f, 0.f, 0.f}, Sd = 0.f, Sdd = 0.f;
  for (int k = 0; k < K_; ++k) {
    const int id = knn_i[(size_t)t * K_ + k];
    const float dd = knn_d[(size_t)t * K_ + k];
    const float nx = cb[id * 3 + 0], ny = cb[id * 3 + 1], nz = cb[id * 3 + 2];
    SN[0] += nx; SN[1] += ny; SN[2] += nz;
    SNN[0] += nx * nx; SNN[1] += nx * ny; SNN[2] += nx * nz;
    SNN[3] += ny * ny; SNN[4] += ny * nz; SNN[5] += nz * nz;
    Sd += dd; Sdd += dd * dd;
    SND[0] += nx * dd; SND[1] += ny * dd; SND[2] += nz * dd;
  }
  float m65[65];
  int e = 0;
#pragma unroll
  for (int i = 0; i < 10; ++i) m65[e++] = mom_mean(i, C, SN, Sd);
#pragma unroll
  for (int i = 0; i < 10; ++i)
#pragma unroll
    for (int j = i; j < 10; ++j) m65[e++] = mom_prod(i, j, C, SN, SNN, Sd, Sdd, SND);
#pragma unroll
  for (int q = 0; q < 65; ++q) {
    float v = m65[q];
#pragma unroll
    for (int off = 32; off > 0; off >>= 1) v += __shfl_xor(v, off);
    m65[q] = v;
  }
  __shared__ float buf[65];
  if (threadIdx.x == 0) {
#pragma unroll
    for (int q = 0; q < 65; ++q) buf[q] = m65[q];
  }
  __syncthreads();
  if (threadIdx.x < 64) atomicAdd(&mom[threadIdx.x], (double)buf[threadIdx.x]);
  if (threadIdx.x == 0) atomicAdd(&mom[64], (double)buf[64]);
}

// ---------------------------------------------------------------------------
// Parallel weight conversion (bf16 pool weights + hi/lo gemm fragments)
// ---------------------------------------------------------------------------
template <int CI, int CO>
__device__ __forceinline__ void conv_frag_seg(const float* __restrict__ w, short* __restrict__ H,
                                              short* __restrict__ L, int tid, int nthr) {
  constexpr int NT = CO / 16;
  for (int i = tid; i < CI * CO; i += nthr) {
    const int j = i & 7, l = (i >> 3) & 63, tmp = i >> 9;
    const int tt = tmp % NT, cc = tmp / NT;
    const int c = cc * 32 + (l >> 4) * 8 + j;
    const int o = tt * 16 + (l & 15);
    const float v = w[o * CI + c];
    const short h = f2bf(v);
    H[i] = h;
    L[i] = f2bf(v - bf2f(h));
  }
}

__global__ __launch_bounds__(256) void convert_kernel(
    const float* __restrict__ pw1, const float* __restrict__ pw2,
    short* __restrict__ wB1, short* __restrict__ wB2,
    const float* __restrict__ wm1, short* __restrict__ f1H, short* __restrict__ f1L,
    const float* __restrict__ wmp, short* __restrict__ f2H, short* __restrict__ f2L,
    const float* __restrict__ wm2, short* __restrict__ f3H, short* __restrict__ f3L,
    const float* __restrict__ wrs, short* __restrict__ fRH, short* __restrict__ fRL) {
  const int blk = blockIdx.x;
  if (blk < 8) {
    const int tid = blk * 256 + threadIdx.x;
    for (int i = tid; i < 128 * 128; i += 2048) wB1[i] = f2bf(pw1[i]);
  } else if (blk < 10) {
    const int tid = (blk - 8) * 256 + threadIdx.x;
    for (int i = tid; i < 64 * 64; i += 512) wB2[i] = f2bf(pw2[i]);
  } else if (blk < 12) {
    conv_frag_seg<32, 64>(wm1, f1H, f1L, (blk - 10) * 256 + threadIdx.x, 512);
  } else if (blk < 16) {
    conv_frag_seg<128, 32>(wmp, f2H, f2L, (blk - 12) * 256 + threadIdx.x, 1024);
  } else if (blk < 24) {
    conv_frag_seg<64, 128>(wm2, f3H, f3L, (blk - 16) * 256 + threadIdx.x, 2048);
  } else {
    conv_frag_seg<32, 128>(wrs, fRH, fRL, (blk - 24) * 256 + threadIdx.x, 1024);
  }
}

// ---------------------------------------------------------------------------
// Setup: lse BN affines folded into compact per-channel vectors:
//   w8[c] = {P0,P1,P2, Q0,Q1,Q2, wd, b'} where z = P.c + Q.n + wd*d + b'
// ---------------------------------------------------------------------------
__global__ void setup_kernel(const double* __restrict__ mom,
                             const float* __restrict__ w1, const float* __restrict__ b1,
                             const float* __restrict__ g1, const float* __restrict__ t1,
                             const float* __restrict__ w2, const float* __restrict__ b2,
                             const float* __restrict__ g2, const float* __restrict__ t2,
                             float* __restrict__ w1f8, float* __restrict__ w2f8) {
  const int t = threadIdx.x;
  __shared__ double mu[10];
  __shared__ double S[10][10];
  const double cnt = (double)B_ * N_ * K_;
  if (t < 10) mu[t] = mom[t] / cnt;
  if (t < 55) {
    int e = t, i = 0;
    while (e >= 10 - i) { e -= 10 - i; ++i; }
    const int j = i + e;
    const double v = mom[10 + t] / cnt;
    S[i][j] = v;
    S[j][i] = v;
  }
  __syncthreads();
  const float *w, *bias, *gg, *bt;
  float *wf;
  int c;
  if (t < 64) { w = w1; bias = b1; gg = g1; bt = t1; wf = w1f8; c = t; }
  else if (t < 96) { w = w2; bias = b2; gg = g2; bt = t2; wf = w2f8; c = t - 64; }
  else return;
  double wd[10];
#pragma unroll
  for (int d = 0; d < 10; ++d) wd[d] = (double)w[c * 10 + d];
  const double cbv = (double)bias[c];
  double mz = cbv;
  for (int d = 0; d < 10; ++d) mz += wd[d] * mu[d];
  double e2 = cbv * cbv;
  for (int d = 0; d < 10; ++d) e2 += 2.0 * cbv * wd[d] * mu[d];
  for (int d = 0; d < 10; ++d)
    for (int e = 0; e < 10; ++e) e2 += wd[d] * wd[e] * S[d][e];
  const double var = e2 - mz * mz;
  const double a = (double)gg[c] / sqrt(var + 1e-5);
  const double shift = (double)bt[c] - a * mz;
  wf[c * 8 + 0] = (float)(a * (wd[0] + wd[6]));
  wf[c * 8 + 1] = (float)(a * (wd[1] + wd[7]));
  wf[c * 8 + 2] = (float)(a * (wd[2] + wd[8]));
  wf[c * 8 + 3] = (float)(a * (wd[3] - wd[6]));
  wf[c * 8 + 4] = (float)(a * (wd[4] - wd[7]));
  wf[c * 8 + 5] = (float)(a * (wd[5] - wd[8]));
  wf[c * 8 + 6] = (float)(a * wd[9]);
  wf[c * 8 + 7] = (float)(a * cbv + shift);
}

// ---------------------------------------------------------------------------
// MFMA GEMM + fused BN stats (hi/lo bf16 split => ~fp32 accuracy)
// ---------------------------------------------------------------------------
template <int CI, int CO, bool ROWMAJ>
__global__ __launch_bounds__(256) void gemm_mfma_kernel(const float* __restrict__ in,
                                                        const short* __restrict__ fragH,
                                                        const short* __restrict__ fragL,
                                                        const float* __restrict__ bias,
                                                        float* __restrict__ out,
                                                        double* __restrict__ sacc) {
  constexpr int NT = CO / 16;
  constexpr int NC = CI / 32;
  __shared__ float part[4][CO][2];
  const int wv = threadIdx.x >> 6, l = threadIdx.x & 63;
  const int col = l & 15, quad = l >> 4;
  const int p0 = blockIdx.x * 64 + wv * 16;
  const int pt = p0 + col;
  f32x4 d[NT];
#pragma unroll
  for (int t = 0; t < NT; ++t) {
    const float bv = bias[t * 16 + col];
    d[t][0] = bv; d[t][1] = bv; d[t][2] = bv; d[t][3] = bv;
  }
#pragma unroll
  for (int cc = 0; cc < NC; ++cc) {
    float xv[8];
    if (ROWMAJ) {
      const float* ip = in + (size_t)pt * CI + cc * 32 + quad * 8;
      *(float4*)&xv[0] = *(const float4*)ip;
      *(float4*)&xv[4] = *(const float4*)(ip + 4);
    } else {
      const int b = pt >> 13, n = pt & (N_ - 1);
      const float* ip = in + ((size_t)b * CI + cc * 32 + quad * 8) * N_ + n;
#pragma unroll
      for (int j = 0; j < 8; ++j) xv[j] = ip[(size_t)j * N_];
    }
    union { bf16x8 v; short u[8]; } AH, AL;
#pragma unroll
    for (int j = 0; j < 8; ++j) {
      const short h = f2bf(xv[j]);
      AH.u[j] = h;
      AL.u[j] = f2bf(xv[j] - bf2f(h));
    }
#pragma unroll
    for (int t = 0; t < NT; ++t) {
      const size_t fo = ((size_t)(cc * NT + t) * 64 + l) * 8;
      const bf16x8 BH = *(const bf16x8*)(fragH + fo);
      const bf16x8 BL = *(const bf16x8*)(fragL + fo);
      d[t] = __builtin_amdgcn_mfma_f32_16x16x32_bf16(AH.v, BH, d[t], 0, 0, 0);
      d[t] = __builtin_amdgcn_mfma_f32_16x16x32_bf16(AH.v, BL, d[t], 0, 0, 0);
      d[t] = __builtin_amdgcn_mfma_f32_16x16x32_bf16(AL.v, BH, d[t], 0, 0, 0);
    }
  }
#pragma unroll
  for (int t = 0; t < NT; ++t) {
#pragma unroll
    for (int r = 0; r < 4; ++r)
      out[(size_t)(p0 + quad * 4 + r) * CO + t * 16 + col] = d[t][r];
    float s1 = d[t][0] + d[t][1] + d[t][2] + d[t][3];
    float s2 = d[t][0] * d[t][0] + d[t][1] * d[t][1] + d[t][2] * d[t][2] + d[t][3] * d[t][3];
    s1 += __shfl_xor(s1, 16); s1 += __shfl_xor(s1, 32);
    s2 += __shfl_xor(s2, 16); s2 += __shfl_xor(s2, 32);
    if (quad == 0) { part[wv][t * 16 + col][0] = s1; part[wv][t * 16 + col][1] = s2; }
  }
  __syncthreads();
  if (threadIdx.x < CO) {
    const int o = threadIdx.x;
    atomicAdd(&sacc[o], (double)(part[0][o][0] + part[1][o][0] + part[2][o][0] + part[3][o][0]));
    atomicAdd(&sacc[CO + o], (double)(part[0][o][1] + part[1][o][1] + part[2][o][1] + part[3][o][1]));
  }
}

// ---------------------------------------------------------------------------
// Fused LSE + attentive pool, MFMA scores (R7 version — stable)
// ---------------------------------------------------------------------------
template <int CSF, int CF>
__global__ __launch_bounds__(256) void pool_kernel(
    const float* __restrict__ coords, const int* __restrict__ knn_i, const float* __restrict__ knn_d,
    const float* __restrict__ w8,
    const float* __restrict__ feat, const double* __restrict__ sfe,
    const float* __restrict__ gfe, const float* __restrict__ tfe,
    const float slope,
    const short* __restrict__ wB, const float* __restrict__ pb,
    float* __restrict__ out) {
  constexpr int C = CSF + CF;
  constexpr int CP = C + 4;
  constexpr int NT = C / 16;
  constexpr int NC = C / 32;
  __shared__ float xcat[4][16][CP];
  __shared__ float4 sp4[4][16];
  __shared__ float4 spc[4];
  const int g = threadIdx.x >> 6;
  const int l = threadIdx.x & 63;
  const int quad = l >> 4, col = l & 15;
  const int pid = blockIdx.x * 4 + g;
  const int b = pid >> 13, n = pid & (N_ - 1);
  const float* cb = coords + (size_t)b * N_ * 3;

  if (l < 16) {
    const int id = knn_i[(size_t)pid * K_ + l];
    const float dd = knn_d[(size_t)pid * K_ + l];
    const float nx = cb[id * 3 + 0], ny = cb[id * 3 + 1], nz = cb[id * 3 + 2];
    sp4[g][l] = make_float4(nx, ny, nz, dd);
    if (l == 0) spc[g] = make_float4(cb[n * 3 + 0], cb[n * 3 + 1], cb[n * 3 + 2], 0.0f);
  }
  if (l < CF) {
    const double cnt = (double)(B_ * N_);
    const double mean = sfe[l] / cnt;
    const double var = sfe[CF + l] / cnt - mean * mean;
    const double av = (double)gfe[l] / sqrt(var + 1e-5);
    const float af = (float)av;
    const float bfv = (float)((double)tfe[l] - av * mean);
    float v = feat[(size_t)pid * CF + l];
    v = af * v + bfv;
    v = (v >= 0.0f) ? v : slope * v;
#pragma unroll
    for (int j = 0; j < 16; ++j) xcat[g][j][CSF + l] = v;
  }
  __syncthreads();
  if (l < CSF) {
    const float4 wA = *(const float4*)(w8 + l * 8);      // P0,P1,P2,Q0
    const float4 wBv = *(const float4*)(w8 + l * 8 + 4); // Q1,Q2,wd,b'
    const float4 C4 = spc[g];
    const float tterm = wBv.w + wA.x * C4.x + wA.y * C4.y + wA.z * C4.z;
#pragma unroll
    for (int k = 0; k < 16; ++k) {
      const float4 nk = sp4[g][k];
      const float z = tterm + wA.w * nk.x + wBv.x * nk.y + wBv.y * nk.z + wBv.z * nk.w;
      xcat[g][k][l] = fmaxf(z, 0.0f);
    }
  }
  __syncthreads();
  f32x4 d[NT];
#pragma unroll
  for (int t = 0; t < NT; ++t) {
    const float pbv = pb[t * 16 + col];
    d[t][0] = pbv; d[t][1] = pbv; d[t][2] = pbv; d[t][3] = pbv;
  }
#pragma unroll
  for (int cc = 0; cc < NC; ++cc) {
    const float* xr = &xcat[g][col][cc * 32 + quad * 8];
    const float4 xa = *(const float4*)xr;
    const float4 xb = *(const float4*)(xr + 4);
    union { bf16x8 v; short u[8]; } A;
    A.u[0] = f2bf(xa.x); A.u[1] = f2bf(xa.y); A.u[2] = f2bf(xa.z); A.u[3] = f2bf(xa.w);
    A.u[4] = f2bf(xb.x); A.u[5] = f2bf(xb.y); A.u[6] = f2bf(xb.z); A.u[7] = f2bf(xb.w);
#pragma unroll
    for (int t = 0; t < NT; ++t) {
      const bf16x8 Bv = *(const bf16x8*)(wB + (size_t)(t * 16 + col) * C + cc * 32 + quad * 8);
      d[t] = __builtin_amdgcn_mfma_f32_16x16x32_bf16(A.v, Bv, d[t], 0, 0, 0);
    }
  }
#pragma unroll
  for (int t = 0; t < NT; ++t) {
    float mx = fmaxf(fmaxf(d[t][0], d[t][1]), fmaxf(d[t][2], d[t][3]));
    mx = fmaxf(mx, __shfl_xor(mx, 16));
    mx = fmaxf(mx, __shfl_xor(mx, 32));
    float e0 = __expf(d[t][0] - mx), e1 = __expf(d[t][1] - mx);
    float e2 = __expf(d[t][2] - mx), e3 = __expf(d[t][3] - mx);
    float s = e0 + e1 + e2 + e3;
    s += __shfl_xor(s, 16);
    s += __shfl_xor(s, 32);
    const int o = t * 16 + col;
    float part = e0 * xcat[g][quad * 4 + 0][o] + e1 * xcat[g][quad * 4 + 1][o] +
                 e2 * xcat[g][quad * 4 + 2][o] + e3 * xcat[g][quad * 4 + 3][o];
    part += __shfl_xor(part, 16);
    part += __shfl_xor(part, 32);
    if (quad == 0) out[(size_t)pid * C + o] = part / s;
  }
}

// ---------------------------------------------------------------------------
// Final: relu(affine(y3|yr)) with LDS transpose for coalesced writes
// ---------------------------------------------------------------------------
__global__ __launch_bounds__(256) void final_kernel(const float* __restrict__ y3,
                                                    const float* __restrict__ yr,
                                                    const double* __restrict__ s3,
                                                    const float* __restrict__ g3, const float* __restrict__ t3,
                                                    const double* __restrict__ sr,
                                                    const float* __restrict__ gr, const float* __restrict__ tr,
                                                    float* __restrict__ out) {
  __shared__ float tile[256 * 17];
  const int blk = blockIdx.x;
  const int b = blk >> 9;
  const int n0 = (blk & 511) << 4;
  const int c = threadIdx.x;
  const float* src;
  const double* sa;
  const float *gp, *tp;
  int cc;
  if (c < 128) { src = y3; sa = s3; gp = g3; tp = t3; cc = c; }
  else { src = yr; sa = sr; gp = gr; tp = tr; cc = c - 128; }
  const double cnt = (double)(B_ * N_);
  const double mean = sa[cc] / cnt;
  const double var = sa[128 + cc] / cnt - mean * mean;
  const double avd = (double)gp[cc] / sqrt(var + 1e-5);
  const float av = (float)avd;
  const float bv = (float)((double)tp[cc] - avd * mean);
#pragma unroll
  for (int nl = 0; nl < 16; ++nl) {
    const float x = av * src[((size_t)(b * N_ + n0 + nl)) * 128 + cc] + bv;
    tile[c * 17 + nl] = fmaxf(x, 0.0f);
  }
  __syncthreads();
  const int np = c & 15, grp = c >> 4;
#pragma unroll
  for (int j = 0; j < 16; ++j) {
    const int c2 = grp * 16 + j;
    out[((size_t)(b * 256 + c2)) * N_ + n0 + np] = tile[c2 * 17 + np];
  }
}

// ---------------------------------------------------------------------------
extern "C" void kernel_launch(void* const* d_in, const int* in_sizes, int n_in,
                              void* d_out, int out_size, void* d_ws, size_t ws_size,
                              hipStream_t stream) {
  (void)in_sizes; (void)n_in; (void)out_size; (void)ws_size;
  const float* coords   = (const float*)d_in[0];
  const float* features = (const float*)d_in[1];
  const float* mlp1_w = (const float*)d_in[2];
  const float* mlp1_b = (const float*)d_in[3];
  const float* mlp1_g = (const float*)d_in[4];
  const float* mlp1_t = (const float*)d_in[5];
  const float* lse1_w = (const float*)d_in[6];
  const float* lse1_b = (const float*)d_in[7];
  const float* lse1_g = (const float*)d_in[8];
  const float* lse1_t = (const float*)d_in[9];
  const float* mlpp1_w = (const float*)d_in[10];
  const float* mlpp1_b = (const float*)d_in[11];
  const float* mlpp1_g = (const float*)d_in[12];
  const float* mlpp1_t = (const float*)d_in[13];
  const float* lse2_w = (const float*)d_in[14];
  const float* lse2_b = (const float*)d_in[15];
  const float* lse2_g = (const float*)d_in[16];
  const float* lse2_t = (const float*)d_in[17];
  const float* mlp2_w = (const float*)d_in[18];
  const float* mlp2_b = (const float*)d_in[19];
  const float* mlp2_g = (const float*)d_in[20];
  const float* mlp2_t = (const float*)d_in[21];
  const float* res_w = (const float*)d_in[22];
  const float* res_b = (const float*)d_in[23];
  const float* res_g = (const float*)d_in[24];
  const float* res_t = (const float*)d_in[25];
  const float* pool1_w = (const float*)d_in[26];
  const float* pool1_b = (const float*)d_in[27];
  const float* pool2_w = (const float*)d_in[28];
  const float* pool2_b = (const float*)d_in[29];

  float* wsf = (float*)d_ws;
  int* knn_i = (int*)d_ws;                 // 262144 ints
  float* knn_d = wsf + 262144;             // 262144
  float* y1 = wsf + 524288;                // (B,N,64)
  float* pooled1 = wsf + 1572864;          // (B,N,128)
  float* y2 = wsf + 3670016;               // (B,N,32)
  float* pooled2 = wsf + 4194304;          // (B,N,64)
  float* y3 = wsf + 5242880;               // (B,N,128)
  float* yr = wsf + 7340032;               // (B,N,128)
  double* dacc = (double*)(wsf + 9437184);
  double* mom = dacc;                      // 65
  double* sacc_mlp1 = dacc + 65;           // 128
  double* sacc_mlpp1 = dacc + 193;         // 64
  double* sacc_mlp2 = dacc + 257;          // 256
  double* sacc_res = dacc + 513;           // 256 -> ends 769
  float* fpar = wsf + 9437184 + 1600;
  float* w1f8 = fpar;                // 512
  float* w2f8 = w1f8 + 512;          // 256
  short* wB1 = (short*)(w2f8 + 256); // 16384 shorts
  short* wB2 = wB1 + 16384;          // 4096
  short* f1H = wB2 + 4096;           // 2048
  short* f1L = f1H + 2048;           // 2048
  short* f2H = f1L + 2048;           // 4096
  short* f2L = f2H + 4096;           // 4096
  short* f3H = f2L + 4096;           // 8192
  short* f3L = f3H + 8192;           // 8192
  short* fRH = f3L + 8192;           // 4096
  short* fRL = fRH + 4096;           // 4096

  hipMemsetAsync(dacc, 0, 769 * sizeof(double), stream);
  knn_kernel<<<dim3(N_ / 16, B_), 512, 0, stream>>>(coords, knn_i, knn_d);
  convert_kernel<<<28, 256, 0, stream>>>(pool1_w, pool2_w, wB1, wB2,
                                         mlp1_w, f1H, f1L, mlpp1_w, f2H, f2L,
                                         mlp2_w, f3H, f3L, res_w, fRH, fRL);
  moments_kernel<<<256, 64, 0, stream>>>(coords, knn_i, knn_d, mom);
  setup_kernel<<<1, 128, 0, stream>>>(mom, lse1_w, lse1_b, lse1_g, lse1_t,
                                      lse2_w, lse2_b, lse2_g, lse2_t, w1f8, w2f8);
  gemm_mfma_kernel<32, 64, false><<<256, 256, 0, stream>>>(features, f1H, f1L, mlp1_b, y1, sacc_mlp1);
  pool_kernel<64, 64><<<B_ * N_ / 4, 256, 0, stream>>>(
      coords, knn_i, knn_d, w1f8, y1, sacc_mlp1, mlp1_g, mlp1_t, 0.2f, wB1, pool1_b, pooled1);
  gemm_mfma_kernel<128, 32, true><<<256, 256, 0, stream>>>(pooled1, f2H, f2L, mlpp1_b, y2, sacc_mlpp1);
  pool_kernel<32, 32><<<B_ * N_ / 4, 256, 0, stream>>>(
      coords, knn_i, knn_d, w2f8, y2, sacc_mlpp1, mlpp1_g, mlpp1_t, 0.0f, wB2, pool2_b, pooled2);
  gemm_mfma_kernel<64, 128, true><<<256, 256, 0, stream>>>(pooled2, f3H, f3L, mlp2_b, y3, sacc_mlp2);
  gemm_mfma_kernel<32, 128, false><<<256, 256, 0, stream>>>(features, fRH, fRL, res_b, yr, sacc_res);
  final_kernel<<<B_ * 512, 256, 0, stream>>>(y3, yr, sacc_mlp2, mlp2_g, mlp2_t,
                                             sacc_res, res_g, res_t, (float*)d_out);
}